// Round 2
// baseline (1448.578 us; speedup 1.0000x reference)
//
#include <hip/hip_runtime.h>
#include <math.h>

// Problem constants
#define BB 4
#define DD 256
#define LL 2048
#define EE 512
#define NN 16
#define KK 7
#define RR 16
#define NC 8               // scan chunks
#define CLEN (LL / NC)     // 256 steps per chunk

// ---------------------------------------------------------------------------
// Pre-transpose ff_w (D_out, D_in, K) -> wt[(di*K+k)*D + do]  (coalesced writes)
// ---------------------------------------------------------------------------
__global__ __launch_bounds__(256) void k_prep_wt(const float* __restrict__ w,
                                                 float* __restrict__ wt) {
    int i = blockIdx.x * 256 + threadIdx.x;      // over D*D*K = 458752
    int doo = i & 255;
    int t = i >> 8;
    int k = t % KK, di = t / KK;
    wt[i] = w[((size_t)doo * DD + di) * KK + k];
}

// ---------------------------------------------------------------------------
// conv_ff v2: implicit GEMM, tile 128l x 64do, per-thread 8l x 4do.
// x window kept in 16 registers, reused across all 7 taps.
// grid (L/128, D/64, B), block 256.
// ---------------------------------------------------------------------------
__global__ __launch_bounds__(256) void k_conv_ff2(const float* __restrict__ x,
                                                  const float* __restrict__ wt,
                                                  const float* __restrict__ bias,
                                                  float* __restrict__ out) {
    __shared__ float xs[8][136];     // 8 di x window [l0-4, l0+131]
    __shared__ float ws[8][7][64];   // di x k x do
    const int tid = threadIdx.x;
    const int tx = tid & 15, ty = tid >> 4;
    const int l0 = blockIdx.x * 128;
    const int do0 = blockIdx.y * 64;
    const int b = blockIdx.z;
    float acc[4][8] = {};
    for (int di0 = 0; di0 < DD; di0 += 8) {
        __syncthreads();
        for (int i = tid; i < 272; i += 256) {           // 8 rows x 34 float4
            int r = i / 34, c4 = i - r * 34;
            int gl = l0 - 4 + c4 * 4;
            float4 v = make_float4(0.f, 0.f, 0.f, 0.f);
            if (gl >= 0 && gl + 3 < LL)
                v = *(const float4*)&x[((size_t)(b * DD + di0 + r)) * LL + gl];
            *(float4*)&xs[r][c4 * 4] = v;
        }
        for (int i = tid; i < 896; i += 256) {           // 8*7*16 float4
            int di = i / 112, rem = i - di * 112;
            int k = rem >> 4, d4 = rem & 15;
            *(float4*)&ws[di][k][d4 * 4] =
                *(const float4*)&wt[((size_t)((di0 + di) * KK + k)) * DD + do0 + d4 * 4];
        }
        __syncthreads();
#pragma unroll
        for (int di = 0; di < 8; ++di) {
            float xr[16];
            *(float4*)&xr[0]  = *(float4*)&xs[di][tx * 8];
            *(float4*)&xr[4]  = *(float4*)&xs[di][tx * 8 + 4];
            *(float4*)&xr[8]  = *(float4*)&xs[di][tx * 8 + 8];
            *(float4*)&xr[12] = *(float4*)&xs[di][tx * 8 + 12];
            float4 wv[7];
#pragma unroll
            for (int k = 0; k < KK; ++k) wv[k] = *(float4*)&ws[di][k][ty * 4];
#pragma unroll
            for (int k = 0; k < KK; ++k) {
#pragma unroll
                for (int j = 0; j < 8; ++j) {
                    float xv = xr[j + k + 1];            // x[l + k - 3]
                    acc[0][j] = fmaf(xv, wv[k].x, acc[0][j]);
                    acc[1][j] = fmaf(xv, wv[k].y, acc[1][j]);
                    acc[2][j] = fmaf(xv, wv[k].z, acc[2][j]);
                    acc[3][j] = fmaf(xv, wv[k].w, acc[3][j]);
                }
            }
        }
    }
#pragma unroll
    for (int o = 0; o < 4; ++o) {
        float bv = bias[do0 + ty * 4 + o];
        float r8[8];
#pragma unroll
        for (int j = 0; j < 8; ++j) {
            float v = acc[o][j] + bv;
            r8[j] = v > 0.f ? v : 0.f;
        }
        float* op = out + (size_t)(b * DD + do0 + ty * 4 + o) * LL + l0 + tx * 8;
        *(float4*)op = *(float4*)&r8[0];
        *(float4*)(op + 4) = *(float4*)&r8[4];
    }
}

// ---------------------------------------------------------------------------
// instance norm over L per (b,d), fused * mask.  grid B*D blocks, 256 thr.
// ---------------------------------------------------------------------------
__global__ __launch_bounds__(256) void k_instnorm(const float* __restrict__ x,
                                                  const float* __restrict__ mask,
                                                  float* __restrict__ out) {
    const int bd = blockIdx.x;
    const int b = bd >> 8;
    const int tid = threadIdx.x;
    const float* row = x + (size_t)bd * LL;
    float v[8];
    float s = 0.f, s2 = 0.f;
#pragma unroll
    for (int i = 0; i < 8; ++i) {
        v[i] = row[i * 256 + tid];
        s += v[i];
        s2 = fmaf(v[i], v[i], s2);
    }
#pragma unroll
    for (int off = 32; off > 0; off >>= 1) {
        s  += __shfl_down(s, off);
        s2 += __shfl_down(s2, off);
    }
    __shared__ float red[2][4];
    if ((tid & 63) == 0) { red[0][tid >> 6] = s; red[1][tid >> 6] = s2; }
    __syncthreads();
    s  = red[0][0] + red[0][1] + red[0][2] + red[0][3];
    s2 = red[1][0] + red[1][1] + red[1][2] + red[1][3];
    const float mu  = s * (1.f / LL);
    const float var = s2 * (1.f / LL) - mu * mu;
    const float inv = rsqrtf(var + 1e-5f);
    const float* mrow = mask + (size_t)b * LL;
    float* orow = out + (size_t)bd * LL;
#pragma unroll
    for (int i = 0; i < 8; ++i)
        orow[i * 256 + tid] = (v[i] - mu) * inv * mrow[i * 256 + tid];
}

// ---------------------------------------------------------------------------
// Big GEMM: tile 128m x 128l, microtile 8x8. W staged in LDS (transposed,
// conflict-free), X read directly from global (L1-resident tile).
// out[b][m][l] = sum_c W[m*C+c] * X[b*sXb + c*L + l].  M%128==0, C%16==0.
// grid (L/128, M/128, B), block 256.
// ---------------------------------------------------------------------------
__global__ __launch_bounds__(256) void k_gemm_big(const float* __restrict__ X,
                                                  const float* __restrict__ W,
                                                  float* __restrict__ out,
                                                  int C, long sXb, long sOb) {
    __shared__ float Ws[16][132];
    const int tid = threadIdx.x;
    const int tx = tid & 15, ty = tid >> 4;
    const int l0 = blockIdx.x * 128, m0 = blockIdx.y * 128, b = blockIdx.z;
    const float* Xb = X + (size_t)b * sXb + l0 + tx * 8;
    float acc[8][8] = {};
    for (int c0 = 0; c0 < C; c0 += 16) {
        __syncthreads();
#pragma unroll
        for (int it = 0; it < 2; ++it) {
            int f = tid + 256 * it;
            int mm = f >> 2, c4 = f & 3;
            float4 v = *(const float4*)&W[(size_t)(m0 + mm) * C + c0 + c4 * 4];
            Ws[c4 * 4 + 0][mm] = v.x;
            Ws[c4 * 4 + 1][mm] = v.y;
            Ws[c4 * 4 + 2][mm] = v.z;
            Ws[c4 * 4 + 3][mm] = v.w;
        }
        __syncthreads();
#pragma unroll
        for (int c = 0; c < 16; ++c) {
            float4 a0 = *(float4*)&Ws[c][ty * 8];
            float4 a1 = *(float4*)&Ws[c][ty * 8 + 4];
            const float* xp = Xb + (size_t)(c0 + c) * LL;
            float4 x0 = *(const float4*)xp;
            float4 x1 = *(const float4*)(xp + 4);
            float av[8] = {a0.x, a0.y, a0.z, a0.w, a1.x, a1.y, a1.z, a1.w};
            float xv[8] = {x0.x, x0.y, x0.z, x0.w, x1.x, x1.y, x1.z, x1.w};
#pragma unroll
            for (int r = 0; r < 8; ++r)
#pragma unroll
                for (int j = 0; j < 8; ++j)
                    acc[r][j] = fmaf(av[r], xv[j], acc[r][j]);
        }
    }
#pragma unroll
    for (int r = 0; r < 8; ++r) {
        float* op = out + (size_t)b * sOb + (size_t)(m0 + ty * 8 + r) * LL + l0 + tx * 8;
        *(float4*)op = *(float4*)&acc[r][0];
        *(float4*)(op + 4) = *(float4*)&acc[r][4];
    }
}

// ---------------------------------------------------------------------------
// Small GEMM: tile 64m x 128l, microtile 4x8.  ACT: 0 none, 1 softplus.
// ATOMIC: 1 -> atomicAdd into pre-zeroed out (split-K).
// blockIdx.y = mTile + mTiles * kSlice; c range [kSlice*cLen, ...).
// ---------------------------------------------------------------------------
template <int ACT, int ATOMIC>
__global__ __launch_bounds__(256) void k_gemm_small(const float* __restrict__ X,
                                                    const float* __restrict__ W,
                                                    const float* __restrict__ bias,
                                                    float* __restrict__ out,
                                                    int M, int C, int cLen, int mTiles,
                                                    long sXb, long sOb) {
    __shared__ float Ws[16][68];
    const int tid = threadIdx.x;
    const int tx = tid & 15, ty = tid >> 4;
    const int l0 = blockIdx.x * 128;
    const int m0 = (blockIdx.y % mTiles) * 64;
    const int cs = (blockIdx.y / mTiles) * cLen;
    const int b = blockIdx.z;
    const float* Xb = X + (size_t)b * sXb + l0 + tx * 8;
    float acc[4][8] = {};
    for (int c0 = cs; c0 < cs + cLen; c0 += 16) {
        __syncthreads();
        {
            int mm = tid >> 2, c4 = tid & 3;
            int gm = m0 + mm;
            float4 v = make_float4(0.f, 0.f, 0.f, 0.f);
            if (gm < M) v = *(const float4*)&W[(size_t)gm * C + c0 + c4 * 4];
            Ws[c4 * 4 + 0][mm] = v.x;
            Ws[c4 * 4 + 1][mm] = v.y;
            Ws[c4 * 4 + 2][mm] = v.z;
            Ws[c4 * 4 + 3][mm] = v.w;
        }
        __syncthreads();
#pragma unroll
        for (int c = 0; c < 16; ++c) {
            float4 a = *(float4*)&Ws[c][ty * 4];
            const float* xp = Xb + (size_t)(c0 + c) * LL;
            float4 x0 = *(const float4*)xp;
            float4 x1 = *(const float4*)(xp + 4);
            float av[4] = {a.x, a.y, a.z, a.w};
            float xv[8] = {x0.x, x0.y, x0.z, x0.w, x1.x, x1.y, x1.z, x1.w};
#pragma unroll
            for (int r = 0; r < 4; ++r)
#pragma unroll
                for (int j = 0; j < 8; ++j)
                    acc[r][j] = fmaf(av[r], xv[j], acc[r][j]);
        }
    }
#pragma unroll
    for (int r = 0; r < 4; ++r) {
        int m = m0 + ty * 4 + r;
        if (m >= M) continue;
        float bv = bias ? bias[m] : 0.f;
        float r8[8];
#pragma unroll
        for (int j = 0; j < 8; ++j) {
            float v = acc[r][j] + bv;
            if (ACT == 1) v = fmaxf(v, 0.f) + log1pf(expf(-fabsf(v)));  // softplus
            r8[j] = v;
        }
        float* op = out + (size_t)b * sOb + (size_t)m * LL + l0 + tx * 8;
        if (ATOMIC) {
#pragma unroll
            for (int j = 0; j < 8; ++j) atomicAdd(op + j, r8[j]);
        } else {
            *(float4*)op = *(float4*)&r8[0];
            *(float4*)(op + 4) = *(float4*)&r8[4];
        }
    }
}

// ---------------------------------------------------------------------------
// Depthwise causal conv (K=7, pad 6 left) + silu.  xp = rows [0,E) of xz.
// ---------------------------------------------------------------------------
__global__ __launch_bounds__(256) void k_dwconv(const float* __restrict__ xz,
                                                const float* __restrict__ cw,
                                                const float* __restrict__ cb,
                                                float* __restrict__ xc) {
    const int l = blockIdx.x * 256 + threadIdx.x;
    const int e = blockIdx.y;
    const int b = blockIdx.z;
    const float* row = xz + ((size_t)b * (2 * EE) + e) * LL;
    float wv[KK];
#pragma unroll
    for (int k = 0; k < KK; ++k) wv[k] = cw[e * KK + k];
    float acc = cb[e];
#pragma unroll
    for (int k = 0; k < KK; ++k) {
        int ll = l + k - (KK - 1);
        if (ll >= 0) acc = fmaf(row[ll], wv[k], acc);
    }
    float sig = 1.f / (1.f + expf(-acc));
    xc[((size_t)b * EE + e) * LL + l] = acc * sig;
}

// ---------------------------------------------------------------------------
// Selective scan, chunked linear recurrence.  t = ch*32768 + b*8192 + e*16 + n.
// ---------------------------------------------------------------------------
__global__ __launch_bounds__(256) void k_scanA(const float* __restrict__ dt,
                                               const float* __restrict__ u,
                                               const float* __restrict__ xdbl,
                                               const float* __restrict__ A_log,
                                               float* __restrict__ aprod,
                                               float* __restrict__ hend) {
    const int t = blockIdx.x * 256 + threadIdx.x;
    const int n = t & 15;
    const int e = (t >> 4) & (EE - 1);
    const int b = (t >> 13) & (BB - 1);
    const int ch = t >> 15;
    const float Ae = -expf(A_log[e * NN + n]);
    const size_t rbe = (size_t)(b * EE + e) * LL + ch * CLEN;
    const float* dtp = dt + rbe;
    const float* up  = u + rbe;
    const float* Bp  = xdbl + ((size_t)(b * 48 + RR + n)) * LL + ch * CLEN;
    float h = 0.f, ap = 1.f;
    for (int i = 0; i < CLEN; i += 4) {
        float4 d4 = *(const float4*)(dtp + i);
        float4 u4 = *(const float4*)(up + i);
        float4 b4 = *(const float4*)(Bp + i);
        float dv[4] = {d4.x, d4.y, d4.z, d4.w};
        float uv[4] = {u4.x, u4.y, u4.z, u4.w};
        float bv[4] = {b4.x, b4.y, b4.z, b4.w};
#pragma unroll
        for (int j = 0; j < 4; ++j) {
            float dA = __expf(dv[j] * Ae);
            h = fmaf(dA, h, dv[j] * uv[j] * bv[j]);
            ap *= dA;
        }
    }
    aprod[t] = ap;
    hend[t] = h;
}

__global__ __launch_bounds__(256) void k_scanB(const float* __restrict__ aprod,
                                               const float* __restrict__ hend,
                                               float* __restrict__ carry) {
    const int t = blockIdx.x * 256 + threadIdx.x;
    float c = 0.f;
#pragma unroll
    for (int ch = 0; ch < NC; ++ch) {
        size_t idx = (size_t)ch * 32768 + t;
        carry[idx] = c;
        c = fmaf(aprod[idx], c, hend[idx]);
    }
}

__global__ __launch_bounds__(256) void k_scanC(const float* __restrict__ dt,
                                               const float* __restrict__ u,
                                               const float* __restrict__ xdbl,
                                               const float* __restrict__ A_log,
                                               const float* __restrict__ Dp,
                                               const float* __restrict__ xz,
                                               const float* __restrict__ carry,
                                               float* __restrict__ y) {
    const int t = blockIdx.x * 256 + threadIdx.x;
    const int n = t & 15;
    const int e = (t >> 4) & (EE - 1);
    const int b = (t >> 13) & (BB - 1);
    const int ch = t >> 15;
    const float Ae = -expf(A_log[e * NN + n]);
    const size_t rbe = (size_t)(b * EE + e) * LL + ch * CLEN;
    const float* dtp = dt + rbe;
    const float* up  = u + rbe;
    const float* Bp  = xdbl + ((size_t)(b * 48 + RR + n)) * LL + ch * CLEN;
    const float* Cp  = xdbl + ((size_t)(b * 48 + RR + NN + n)) * LL + ch * CLEN;
    const float* zp  = xz + ((size_t)b * (2 * EE) + EE + e) * LL + ch * CLEN;
    const float Dpe = Dp[e];
    float* yp = y + rbe;
    float h = carry[t];
    for (int i = 0; i < CLEN; i += 4) {
        float4 d4 = *(const float4*)(dtp + i);
        float4 u4 = *(const float4*)(up + i);
        float4 b4 = *(const float4*)(Bp + i);
        float4 c4 = *(const float4*)(Cp + i);
        float4 z4 = *(const float4*)(zp + i);
        float dv[4] = {d4.x, d4.y, d4.z, d4.w};
        float uv[4] = {u4.x, u4.y, u4.z, u4.w};
        float bv[4] = {b4.x, b4.y, b4.z, b4.w};
        float cv[4] = {c4.x, c4.y, c4.z, c4.w};
        float zv[4] = {z4.x, z4.y, z4.z, z4.w};
#pragma unroll
        for (int j = 0; j < 4; ++j) {
            float dA = __expf(dv[j] * Ae);
            h = fmaf(dA, h, dv[j] * uv[j] * bv[j]);
            float p = h * cv[j];
            p += __shfl_xor(p, 1);
            p += __shfl_xor(p, 2);
            p += __shfl_xor(p, 4);
            p += __shfl_xor(p, 8);
            if (n == 0) {
                float zz = zv[j];
                float sig = 1.f / (1.f + __expf(-zz));
                yp[i + j] = (p + uv[j] * Dpe) * (zz * sig);
            }
        }
    }
}

// ---------------------------------------------------------------------------
// final: out = (x + out0 + (s + c) * mask) * mask
// ---------------------------------------------------------------------------
__global__ __launch_bounds__(256) void k_final(const float* __restrict__ x,
                                               const float* __restrict__ out0,
                                               const float* __restrict__ sout,
                                               const float* __restrict__ cout,
                                               const float* __restrict__ mask,
                                               float* __restrict__ out) {
    const size_t idx = ((size_t)blockIdx.x * 256 + threadIdx.x) * 4;
    const size_t row = idx >> 11;
    const int b = (int)(row >> 8);
    const int l = (int)(idx & (LL - 1));
    float4 xv = *(const float4*)(x + idx);
    float4 o0 = *(const float4*)(out0 + idx);
    float4 sv = *(const float4*)(sout + idx);
    float4 cv = *(const float4*)(cout + idx);
    float4 mv = *(const float4*)(mask + (size_t)b * LL + l);
    float4 r;
    r.x = (xv.x + o0.x + (sv.x + cv.x) * mv.x) * mv.x;
    r.y = (xv.y + o0.y + (sv.y + cv.y) * mv.y) * mv.y;
    r.z = (xv.z + o0.z + (sv.z + cv.z) * mv.z) * mv.z;
    r.w = (xv.w + o0.w + (sv.w + cv.w) * mv.w) * mv.w;
    *(float4*)(out + idx) = r;
}

// ---------------------------------------------------------------------------
extern "C" void kernel_launch(void* const* d_in, const int* in_sizes, int n_in,
                              void* d_out, int out_size, void* d_ws, size_t ws_size,
                              hipStream_t stream) {
    const float* x    = (const float*)d_in[0];
    const float* enc  = (const float*)d_in[1];
    const float* mask = (const float*)d_in[2];
    const float* ff_w = (const float*)d_in[3];
    const float* ff_b = (const float*)d_in[4];
    const float* sp[9];
    const float* cp[9];
    for (int i = 0; i < 9; ++i) {
        sp[i] = (const float*)d_in[5 + i];
        cp[i] = (const float*)d_in[14 + i];
    }

    // workspace carve-up (floats)
    float* ws = (float*)d_ws;
    float* out0  = ws;  ws += (size_t)BB * DD * LL;
    float* nrm   = ws;  ws += (size_t)BB * DD * LL;
    float* xz    = ws;  ws += (size_t)BB * 2 * EE * LL;
    float* xc    = ws;  ws += (size_t)BB * EE * LL;
    float* xdbl  = ws;  ws += (size_t)BB * 48 * LL;
    float* dtb   = ws;  ws += (size_t)BB * EE * LL;
    float* yb    = ws;  ws += (size_t)BB * EE * LL;
    float* soutb = ws;  ws += (size_t)BB * DD * LL;
    float* coutb = ws;  ws += (size_t)BB * DD * LL;
    float* aprod = ws;  ws += (size_t)NC * BB * EE * NN;
    float* hendb = ws;  ws += (size_t)NC * BB * EE * NN;
    float* carry = ws;  ws += (size_t)NC * BB * EE * NN;
    float* wt    = ws;  ws += (size_t)DD * DD * KK;      // transposed ff_w

    // conv_ff
    k_prep_wt<<<dim3(DD * DD * KK / 256), 256, 0, stream>>>(ff_w, wt);
    k_conv_ff2<<<dim3(LL / 128, DD / 64, BB), 256, 0, stream>>>(x, wt, ff_b, out0);

    auto mamba = [&](const float* src, const float* const* P, float* outbuf) {
        // instance_norm(src) * mask -> nrm
        k_instnorm<<<dim3(BB * DD), 256, 0, stream>>>(src, mask, nrm);
        // in_proj: xz (B, 2E, L), M=1024, C=256
        k_gemm_big<<<dim3(LL / 128, 2 * EE / 128, BB), 256, 0, stream>>>(
            nrm, P[0], xz, DD, (long)DD * LL, (long)2 * EE * LL);
        // depthwise causal conv + silu -> xc (B, E, L)
        k_dwconv<<<dim3(LL / 256, EE, BB), 256, 0, stream>>>(xz, P[1], P[2], xc);
        // x_proj: xdbl (B, 48, L), M=48, C=512, split-K=8, atomic
        hipMemsetAsync(xdbl, 0, (size_t)BB * 48 * LL * sizeof(float), stream);
        k_gemm_small<0, 1><<<dim3(LL / 128, 8, BB), 256, 0, stream>>>(
            xc, P[3], nullptr, xdbl, RR + 2 * NN, EE, 64, 1, (long)EE * LL, (long)48 * LL);
        // dt_proj + softplus: dtb (B, E, L), M=512, C=16
        k_gemm_small<1, 0><<<dim3(LL / 128, EE / 64, BB), 256, 0, stream>>>(
            xdbl, P[4], P[5], dtb, EE, RR, RR, EE / 64, (long)48 * LL, (long)EE * LL);
        // selective scan (chunked), fused +u*D and *silu(z)
        k_scanA<<<dim3(NC * BB * EE * NN / 256), 256, 0, stream>>>(dtb, xc, xdbl, P[6], aprod, hendb);
        k_scanB<<<dim3(BB * EE * NN / 256), 256, 0, stream>>>(aprod, hendb, carry);
        k_scanC<<<dim3(NC * BB * EE * NN / 256), 256, 0, stream>>>(dtb, xc, xdbl, P[6], P[7], xz, carry, yb);
        // out_proj: outbuf (B, D, L), M=256, C=512
        k_gemm_small<0, 0><<<dim3(LL / 128, DD / 64, BB), 256, 0, stream>>>(
            yb, P[8], nullptr, outbuf, DD, EE, EE, DD / 64, (long)EE * LL, (long)DD * LL);
    };

    mamba(out0, sp, soutb);
    mamba(enc, cp, coutb);

    k_final<<<dim3((size_t)BB * DD * LL / 4 / 256), 256, 0, stream>>>(
        x, out0, soutb, coutb, mask, (float*)d_out);
}

// Round 3
// 823.059 us; speedup vs baseline: 1.7600x; 1.7600x over previous
//
#include <hip/hip_runtime.h>
#include <hip/hip_bf16.h>
#include <math.h>

// Problem constants
#define BB 4
#define DD 256
#define LL 2048
#define EE 512
#define NN 16
#define KK 7
#define RR 16
#define NC 8               // scan chunks
#define CLEN (LL / NC)     // 256 steps per chunk
#define LPAD 2064          // padded L for conv input (8 zeros each side)

typedef __attribute__((ext_vector_type(8))) short short8;   // 8 bf16 (4 VGPRs)
typedef __attribute__((ext_vector_type(4))) float floatx4;  // MFMA accumulator

static __device__ __forceinline__ unsigned short bfbits(float f) {
    __hip_bfloat16 h = __float2bfloat16(f);
    return *(unsigned short*)&h;
}

// ---------------------------------------------------------------------------
// Pack a weight matrix W[M][C] fp32 -> Wp[co][Mp][8] bf16 (zero-padded to Mp, Cp).
// ---------------------------------------------------------------------------
__global__ __launch_bounds__(256) void k_pack_w(const float* __restrict__ W,
                                                unsigned short* __restrict__ Wp,
                                                int M, int C, int Mp, int Coct) {
    int cell = blockIdx.x * 256 + threadIdx.x;
    if (cell >= Coct * Mp) return;
    int co = cell / Mp, m = cell - co * Mp;
    unsigned short v[8];
#pragma unroll
    for (int j = 0; j < 8; ++j) {
        int c = co * 8 + j;
        float f = (m < M && c < C) ? W[(size_t)m * C + c] : 0.f;
        v[j] = bfbits(f);
    }
    *(uint4*)&Wp[(size_t)cell * 8] = *(uint4*)v;
}

// ff_w (Do, Di, K) -> Wffp[k][co][do][8] with di = co*8+j
__global__ __launch_bounds__(256) void k_pack_ffw(const float* __restrict__ w,
                                                  unsigned short* __restrict__ Wp) {
    int cell = blockIdx.x * 256 + threadIdx.x;   // 7*32*256
    if (cell >= KK * 32 * DD) return;
    int doo = cell % DD;
    int rest = cell / DD;
    int co = rest % 32, k = rest / 32;
    unsigned short v[8];
#pragma unroll
    for (int j = 0; j < 8; ++j)
        v[j] = bfbits(w[((size_t)doo * DD + co * 8 + j) * KK + k]);
    *(uint4*)&Wp[(size_t)cell * 8] = *(uint4*)v;
}

// x (B, D, L) fp32 -> xp[b][co][l+8][8] bf16 with 8-column zero pad both sides
__global__ __launch_bounds__(256) void k_pack_x(const float* __restrict__ x,
                                                unsigned short* __restrict__ xp) {
    int l = blockIdx.x * 256 + threadIdx.x;
    int co = blockIdx.y, b = blockIdx.z;
    if (l >= LPAD) return;
    int sl = l - 8;
    unsigned short v[8];
#pragma unroll
    for (int j = 0; j < 8; ++j) {
        float f = (sl >= 0 && sl < LL) ? x[((size_t)(b * DD) + co * 8 + j) * LL + sl] : 0.f;
        v[j] = bfbits(f);
    }
    *(uint4*)&xp[(((size_t)(b * 32) + co) * LPAD + l) * 8] = *(uint4*)v;
}

// ---------------------------------------------------------------------------
// instance norm over L per (b,d), fused * mask, writes packed bf16 [b][d/8][l][8].
// ---------------------------------------------------------------------------
__global__ __launch_bounds__(256) void k_instnorm(const float* __restrict__ x,
                                                  const float* __restrict__ mask,
                                                  unsigned short* __restrict__ outp) {
    const int bd = blockIdx.x;
    const int b = bd >> 8, d = bd & 255;
    const int tid = threadIdx.x;
    const float* row = x + (size_t)bd * LL;
    float v[8];
    float s = 0.f, s2 = 0.f;
#pragma unroll
    for (int i = 0; i < 8; ++i) {
        v[i] = row[i * 256 + tid];
        s += v[i];
        s2 = fmaf(v[i], v[i], s2);
    }
#pragma unroll
    for (int off = 32; off > 0; off >>= 1) {
        s  += __shfl_down(s, off);
        s2 += __shfl_down(s2, off);
    }
    __shared__ float red[2][4];
    if ((tid & 63) == 0) { red[0][tid >> 6] = s; red[1][tid >> 6] = s2; }
    __syncthreads();
    s  = red[0][0] + red[0][1] + red[0][2] + red[0][3];
    s2 = red[1][0] + red[1][1] + red[1][2] + red[1][3];
    const float mu  = s * (1.f / LL);
    const float var = s2 * (1.f / LL) - mu * mu;
    const float inv = rsqrtf(var + 1e-5f);
    const float* mrow = mask + (size_t)b * LL;
    unsigned short* op = outp + ((size_t)(b * 32) + (d >> 3)) * LL * 8 + (d & 7);
#pragma unroll
    for (int i = 0; i < 8; ++i) {
        int l = i * 256 + tid;
        op[(size_t)l * 8] = bfbits((v[i] - mu) * inv * mrow[l]);
    }
}

// ---------------------------------------------------------------------------
// MFMA GEMM: out[b][m][l] = act(bias[m] + sum_c A[m][c] * B[b][c][l])
// A packed [co][Ms][8] bf16, B packed [b][BoctPhys ~ co][L][8] bf16.
// Block 256 thr = 4 waves (2x2), tile (RM*32) m x 128 l, BK=32.
// grid (L/128, Ms/(RM*32), B).
// ---------------------------------------------------------------------------
template <int RM, int ACT, int PACKOUT>
__global__ __launch_bounds__(256) void k_mfma_gemm(
        const unsigned short* __restrict__ Ap,
        const unsigned short* __restrict__ Bp,
        float* __restrict__ out,
        const float* __restrict__ bias,
        unsigned short* __restrict__ pout,
        int Ms, int Coct, int BoctPhys) {
    constexpr int TM = RM * 32;
    constexpr int APITCH = TM * 8 + 8;       // shorts per c-octet slab (+16B pad)
    constexpr int BPITCH = 128 * 8 + 8;
    constexpr int ACELLS = (4 * TM) / 256;
    __shared__ unsigned short As[4 * APITCH];
    __shared__ unsigned short Bs[4 * BPITCH];
    const int tid = threadIdx.x;
    const int w = tid >> 6, lane = tid & 63;
    const int quad = lane >> 4, t = lane & 15;
    const int wm = (w >> 1) * (RM * 16), wl = (w & 1) * 64;
    const int l0 = blockIdx.x * 128;
    const int m0 = blockIdx.y * TM;
    const int b  = blockIdx.z;
    const size_t Bbase = (size_t)b * BoctPhys * LL * 8;

    floatx4 acc[RM][4];
#pragma unroll
    for (int r = 0; r < RM; ++r)
#pragma unroll
        for (int j = 0; j < 4; ++j) acc[r][j] = (floatx4){0.f, 0.f, 0.f, 0.f};

    for (int c0 = 0; c0 < Coct; c0 += 4) {
        uint4 areg[ACELLS], breg[2];
#pragma unroll
        for (int i = 0; i < ACELLS; ++i) {
            int cell = tid + i * 256;
            int q = cell / TM, mm = cell % TM;
            areg[i] = *(const uint4*)&Ap[((size_t)(c0 + q) * Ms + m0 + mm) * 8];
        }
#pragma unroll
        for (int i = 0; i < 2; ++i) {
            int cell = tid + i * 256;
            int q = cell >> 7, ll = cell & 127;
            breg[i] = *(const uint4*)&Bp[Bbase + ((size_t)(c0 + q) * LL + l0 + ll) * 8];
        }
        __syncthreads();
#pragma unroll
        for (int i = 0; i < ACELLS; ++i) {
            int cell = tid + i * 256;
            int q = cell / TM, mm = cell % TM;
            *(uint4*)&As[q * APITCH + mm * 8] = areg[i];
        }
#pragma unroll
        for (int i = 0; i < 2; ++i) {
            int cell = tid + i * 256;
            int q = cell >> 7, ll = cell & 127;
            *(uint4*)&Bs[q * BPITCH + ll * 8] = breg[i];
        }
        __syncthreads();
        short8 af[RM], bfv[4];
#pragma unroll
        for (int r = 0; r < RM; ++r)
            af[r] = *(short8*)&As[quad * APITCH + (wm + r * 16 + t) * 8];
#pragma unroll
        for (int j = 0; j < 4; ++j)
            bfv[j] = *(short8*)&Bs[quad * BPITCH + (wl + j * 16 + t) * 8];
#pragma unroll
        for (int r = 0; r < RM; ++r)
#pragma unroll
            for (int j = 0; j < 4; ++j)
                acc[r][j] = __builtin_amdgcn_mfma_f32_16x16x32_bf16(af[r], bfv[j], acc[r][j], 0, 0, 0);
    }
    // epilogue: C/D layout col = lane&15 (l), row = quad*4 + reg (m)
#pragma unroll
    for (int r = 0; r < RM; ++r) {
        int mb = m0 + wm + r * 16 + quad * 4;
#pragma unroll
        for (int i = 0; i < 4; ++i) {
            int m = mb + i;
            float bv = bias ? bias[m] : 0.f;
#pragma unroll
            for (int j = 0; j < 4; ++j) {
                int l = l0 + wl + j * 16 + t;
                float v = acc[r][j][i] + bv;
                if (ACT == 1) v = fmaxf(v, 0.f) + log1pf(expf(-fabsf(v)));  // softplus
                out[((size_t)b * Ms + m) * LL + l] = v;
                if (PACKOUT)
                    pout[(((size_t)b * (Ms / 8) + (m >> 3)) * LL + l) * 8 + (m & 7)] = bfbits(v);
            }
        }
    }
}

// ---------------------------------------------------------------------------
// conv_ff as 7 shifted MFMA GEMM sweeps over padded packed x.
// A = Wffp[k][co][256][8], B = xp[b][co][LPAD][8].  grid (16, 2, 4).
// ---------------------------------------------------------------------------
__global__ __launch_bounds__(256) void k_conv_mfma(
        const unsigned short* __restrict__ Wp,
        const unsigned short* __restrict__ Xp,
        const float* __restrict__ bias,
        float* __restrict__ out) {
    constexpr int APITCH = 128 * 8 + 8, BPITCH = 128 * 8 + 8;
    __shared__ unsigned short As[4 * APITCH];
    __shared__ unsigned short Bs[4 * BPITCH];
    const int tid = threadIdx.x;
    const int w = tid >> 6, lane = tid & 63;
    const int quad = lane >> 4, t = lane & 15;
    const int wm = (w >> 1) * 64, wl = (w & 1) * 64;
    const int l0 = blockIdx.x * 128;
    const int m0 = blockIdx.y * 128;
    const int b  = blockIdx.z;

    floatx4 acc[4][4];
#pragma unroll
    for (int r = 0; r < 4; ++r)
#pragma unroll
        for (int j = 0; j < 4; ++j) acc[r][j] = (floatx4){0.f, 0.f, 0.f, 0.f};

    for (int it = 0; it < KK * 8; ++it) {
        int k = it >> 3, dc = it & 7;        // tap, di-chunk (4 octets each)
        uint4 areg[2], breg[2];
#pragma unroll
        for (int i = 0; i < 2; ++i) {
            int cell = tid + i * 256;
            int q = cell >> 7, mm = cell & 127;
            areg[i] = *(const uint4*)&Wp[(((size_t)k * 32 + dc * 4 + q) * DD + m0 + mm) * 8];
            // l index = l0 + ll + 8 + (k - 3)
            breg[i] = *(const uint4*)&Xp[(((size_t)b * 32 + dc * 4 + q) * LPAD + l0 + mm + 5 + k) * 8];
        }
        __syncthreads();
#pragma unroll
        for (int i = 0; i < 2; ++i) {
            int cell = tid + i * 256;
            int q = cell >> 7, mm = cell & 127;
            *(uint4*)&As[q * APITCH + mm * 8] = areg[i];
            *(uint4*)&Bs[q * BPITCH + mm * 8] = breg[i];
        }
        __syncthreads();
        short8 af[4], bfv[4];
#pragma unroll
        for (int r = 0; r < 4; ++r)
            af[r] = *(short8*)&As[quad * APITCH + (wm + r * 16 + t) * 8];
#pragma unroll
        for (int j = 0; j < 4; ++j)
            bfv[j] = *(short8*)&Bs[quad * BPITCH + (wl + j * 16 + t) * 8];
#pragma unroll
        for (int r = 0; r < 4; ++r)
#pragma unroll
            for (int j = 0; j < 4; ++j)
                acc[r][j] = __builtin_amdgcn_mfma_f32_16x16x32_bf16(af[r], bfv[j], acc[r][j], 0, 0, 0);
    }
#pragma unroll
    for (int r = 0; r < 4; ++r) {
        int mb = m0 + wm + r * 16 + quad * 4;
#pragma unroll
        for (int i = 0; i < 4; ++i) {
            int m = mb + i;
            float bv = bias[m];
#pragma unroll
            for (int j = 0; j < 4; ++j) {
                int l = l0 + wl + j * 16 + t;
                float v = acc[r][j][i] + bv;
                out[((size_t)b * DD + m) * LL + l] = v > 0.f ? v : 0.f;
            }
        }
    }
}

// ---------------------------------------------------------------------------
// Depthwise causal conv (K=7) + silu.  Writes fp32 xc and packed bf16 xcp.
// ---------------------------------------------------------------------------
__global__ __launch_bounds__(256) void k_dwconv(const float* __restrict__ xz,
                                                const float* __restrict__ cw,
                                                const float* __restrict__ cb,
                                                float* __restrict__ xc,
                                                unsigned short* __restrict__ xcp) {
    const int l = blockIdx.x * 256 + threadIdx.x;
    const int e = blockIdx.y;
    const int b = blockIdx.z;
    const float* row = xz + ((size_t)b * (2 * EE) + e) * LL;
    float wv[KK];
#pragma unroll
    for (int k = 0; k < KK; ++k) wv[k] = cw[e * KK + k];
    float acc = cb[e];
#pragma unroll
    for (int k = 0; k < KK; ++k) {
        int ll = l + k - (KK - 1);
        if (ll >= 0) acc = fmaf(row[ll], wv[k], acc);
    }
    float sig = 1.f / (1.f + expf(-acc));
    float v = acc * sig;
    xc[((size_t)b * EE + e) * LL + l] = v;
    xcp[(((size_t)(b * 64) + (e >> 3)) * LL + l) * 8 + (e & 7)] = bfbits(v);
}

// ---------------------------------------------------------------------------
// Selective scan, chunked linear recurrence.  t = ch*32768 + b*8192 + e*16 + n.
// xdbl has 64 rows per batch: rows 0..15 dt-in, 16..31 Bm, 32..47 Cm.
// ---------------------------------------------------------------------------
__global__ __launch_bounds__(256) void k_scanA(const float* __restrict__ dt,
                                               const float* __restrict__ u,
                                               const float* __restrict__ xdbl,
                                               const float* __restrict__ A_log,
                                               float* __restrict__ aprod,
                                               float* __restrict__ hend) {
    const int t = blockIdx.x * 256 + threadIdx.x;
    const int n = t & 15;
    const int e = (t >> 4) & (EE - 1);
    const int b = (t >> 13) & (BB - 1);
    const int ch = t >> 15;
    const float Ae = -expf(A_log[e * NN + n]);
    const size_t rbe = (size_t)(b * EE + e) * LL + ch * CLEN;
    const float* dtp = dt + rbe;
    const float* up  = u + rbe;
    const float* Bp  = xdbl + ((size_t)(b * 64 + RR + n)) * LL + ch * CLEN;
    float h = 0.f, ap = 1.f;
    for (int i = 0; i < CLEN; i += 4) {
        float4 d4 = *(const float4*)(dtp + i);
        float4 u4 = *(const float4*)(up + i);
        float4 b4 = *(const float4*)(Bp + i);
        float dv[4] = {d4.x, d4.y, d4.z, d4.w};
        float uv[4] = {u4.x, u4.y, u4.z, u4.w};
        float bv[4] = {b4.x, b4.y, b4.z, b4.w};
#pragma unroll
        for (int j = 0; j < 4; ++j) {
            float dA = __expf(dv[j] * Ae);
            h = fmaf(dA, h, dv[j] * uv[j] * bv[j]);
            ap *= dA;
        }
    }
    aprod[t] = ap;
    hend[t] = h;
}

__global__ __launch_bounds__(256) void k_scanB(const float* __restrict__ aprod,
                                               const float* __restrict__ hend,
                                               float* __restrict__ carry) {
    const int t = blockIdx.x * 256 + threadIdx.x;
    float c = 0.f;
#pragma unroll
    for (int ch = 0; ch < NC; ++ch) {
        size_t idx = (size_t)ch * 32768 + t;
        carry[idx] = c;
        c = fmaf(aprod[idx], c, hend[idx]);
    }
}

__global__ __launch_bounds__(256) void k_scanC(const float* __restrict__ dt,
                                               const float* __restrict__ u,
                                               const float* __restrict__ xdbl,
                                               const float* __restrict__ A_log,
                                               const float* __restrict__ Dp,
                                               const float* __restrict__ xz,
                                               const float* __restrict__ carry,
                                               unsigned short* __restrict__ ybp) {
    const int t = blockIdx.x * 256 + threadIdx.x;
    const int n = t & 15;
    const int e = (t >> 4) & (EE - 1);
    const int b = (t >> 13) & (BB - 1);
    const int ch = t >> 15;
    const float Ae = -expf(A_log[e * NN + n]);
    const size_t rbe = (size_t)(b * EE + e) * LL + ch * CLEN;
    const float* dtp = dt + rbe;
    const float* up  = u + rbe;
    const float* Bp  = xdbl + ((size_t)(b * 64 + RR + n)) * LL + ch * CLEN;
    const float* Cp  = xdbl + ((size_t)(b * 64 + RR + NN + n)) * LL + ch * CLEN;
    const float* zp  = xz + ((size_t)b * (2 * EE) + EE + e) * LL + ch * CLEN;
    const float Dpe = Dp[e];
    unsigned short* yp = ybp + ((size_t)(b * 64) + (e >> 3)) * LL * 8 + (e & 7)
                         + (size_t)(ch * CLEN) * 8;
    float h = carry[t];
    for (int i = 0; i < CLEN; i += 4) {
        float4 d4 = *(const float4*)(dtp + i);
        float4 u4 = *(const float4*)(up + i);
        float4 b4 = *(const float4*)(Bp + i);
        float4 c4 = *(const float4*)(Cp + i);
        float4 z4 = *(const float4*)(zp + i);
        float dv[4] = {d4.x, d4.y, d4.z, d4.w};
        float uv[4] = {u4.x, u4.y, u4.z, u4.w};
        float bv[4] = {b4.x, b4.y, b4.z, b4.w};
        float cv[4] = {c4.x, c4.y, c4.z, c4.w};
        float zv[4] = {z4.x, z4.y, z4.z, z4.w};
#pragma unroll
        for (int j = 0; j < 4; ++j) {
            float dA = __expf(dv[j] * Ae);
            h = fmaf(dA, h, dv[j] * uv[j] * bv[j]);
            float p = h * cv[j];
            p += __shfl_xor(p, 1);
            p += __shfl_xor(p, 2);
            p += __shfl_xor(p, 4);
            p += __shfl_xor(p, 8);
            if (n == 0) {
                float zz = zv[j];
                float sig = 1.f / (1.f + __expf(-zz));
                yp[(size_t)(i + j) * 8] = bfbits((p + uv[j] * Dpe) * (zz * sig));
            }
        }
    }
}

// ---------------------------------------------------------------------------
// final: out = (x + out0 + (s + c) * mask) * mask
// ---------------------------------------------------------------------------
__global__ __launch_bounds__(256) void k_final(const float* __restrict__ x,
                                               const float* __restrict__ out0,
                                               const float* __restrict__ sout,
                                               const float* __restrict__ cout,
                                               const float* __restrict__ mask,
                                               float* __restrict__ out) {
    const size_t idx = ((size_t)blockIdx.x * 256 + threadIdx.x) * 4;
    const size_t row = idx >> 11;
    const int b = (int)(row >> 8);
    const int l = (int)(idx & (LL - 1));
    float4 xv = *(const float4*)(x + idx);
    float4 o0 = *(const float4*)(out0 + idx);
    float4 sv = *(const float4*)(sout + idx);
    float4 cv = *(const float4*)(cout + idx);
    float4 mv = *(const float4*)(mask + (size_t)b * LL + l);
    float4 r;
    r.x = (xv.x + o0.x + (sv.x + cv.x) * mv.x) * mv.x;
    r.y = (xv.y + o0.y + (sv.y + cv.y) * mv.y) * mv.y;
    r.z = (xv.z + o0.z + (sv.z + cv.z) * mv.z) * mv.z;
    r.w = (xv.w + o0.w + (sv.w + cv.w) * mv.w) * mv.w;
    *(float4*)(out + idx) = r;
}

// ---------------------------------------------------------------------------
extern "C" void kernel_launch(void* const* d_in, const int* in_sizes, int n_in,
                              void* d_out, int out_size, void* d_ws, size_t ws_size,
                              hipStream_t stream) {
    const float* x    = (const float*)d_in[0];
    const float* enc  = (const float*)d_in[1];
    const float* mask = (const float*)d_in[2];
    const float* ff_w = (const float*)d_in[3];
    const float* ff_b = (const float*)d_in[4];
    const float* sp[9];
    const float* cp[9];
    for (int i = 0; i < 9; ++i) {
        sp[i] = (const float*)d_in[5 + i];
        cp[i] = (const float*)d_in[14 + i];
    }

    // workspace carve-up
    float* ws = (float*)d_ws;
    auto fcarve = [&](size_t n) { float* p = ws; ws += (n + 3) & ~3ul; return p; };
    float* out0  = fcarve((size_t)BB * DD * LL);
    float* xz    = fcarve((size_t)BB * 2 * EE * LL);
    float* xc    = fcarve((size_t)BB * EE * LL);
    float* xdbl  = fcarve((size_t)BB * 64 * LL);
    float* dtb   = fcarve((size_t)BB * EE * LL);
    float* soutb = fcarve((size_t)BB * DD * LL);
    float* coutb = fcarve((size_t)BB * DD * LL);
    float* aprod = fcarve((size_t)NC * BB * EE * NN);
    float* hendb = fcarve((size_t)NC * BB * EE * NN);
    float* carry = fcarve((size_t)NC * BB * EE * NN);
    auto scarve = [&](size_t n) { unsigned short* p = (unsigned short*)ws; ws += (n + 7) / 2 / 4 * 4 + 4; return p; };
    unsigned short* nrmp  = scarve((size_t)BB * 32 * LL * 8);
    unsigned short* xcp   = scarve((size_t)BB * 64 * LL * 8);
    unsigned short* xdblp = scarve((size_t)BB * 8 * LL * 8);
    unsigned short* ybp   = scarve((size_t)BB * 64 * LL * 8);
    unsigned short* xp    = scarve((size_t)BB * 32 * LPAD * 8);
    unsigned short* ffWp  = scarve((size_t)KK * 32 * DD * 8);
    unsigned short* inWp[2]  = { scarve(32 * 1024 * 8), scarve(32 * 1024 * 8) };
    unsigned short* outWp[2] = { scarve(64 * 256 * 8),  scarve(64 * 256 * 8) };
    unsigned short* xWp[2]   = { scarve(64 * 64 * 8),   scarve(64 * 64 * 8) };
    unsigned short* dtWp[2]  = { scarve(4 * 512 * 8),   scarve(4 * 512 * 8) };

    // ---- weight / input packing ----
    k_pack_ffw<<<dim3((KK * 32 * DD + 255) / 256), 256, 0, stream>>>(ff_w, ffWp);
    k_pack_x<<<dim3((LPAD + 255) / 256, 32, BB), 256, 0, stream>>>(x, xp);
    for (int s = 0; s < 2; ++s) {
        const float* const* P = s ? cp : sp;
        k_pack_w<<<dim3(32 * 1024 / 256), 256, 0, stream>>>(P[0], inWp[s], 1024, 256, 1024, 32);
        k_pack_w<<<dim3(64 * 256 / 256), 256, 0, stream>>>(P[8], outWp[s], 256, 512, 256, 64);
        k_pack_w<<<dim3(64 * 64 / 256), 256, 0, stream>>>(P[3], xWp[s], 48, 512, 64, 64);
        k_pack_w<<<dim3(4 * 512 / 256), 256, 0, stream>>>(P[4], dtWp[s], 512, 16, 512, 4);
    }

    // ---- conv_ff (MFMA) ----
    k_conv_mfma<<<dim3(LL / 128, DD / 128, BB), 256, 0, stream>>>(ffWp, xp, ff_b, out0);

    auto mamba = [&](const float* src, const float* const* P, int s, float* outbuf) {
        k_instnorm<<<dim3(BB * DD), 256, 0, stream>>>(src, mask, nrmp);
        // in_proj: xz (B, 2E, L) fp32.  M=1024, Coct=32
        k_mfma_gemm<4, 0, 0><<<dim3(LL / 128, 1024 / 128, BB), 256, 0, stream>>>(
            inWp[s], nrmp, xz, nullptr, nullptr, 1024, 32, 32);
        // depthwise conv + silu -> xc fp32 + xcp bf16
        k_dwconv<<<dim3(LL / 256, EE, BB), 256, 0, stream>>>(xz, P[1], P[2], xc, xcp);
        // x_proj: xdbl (B, 64, L) fp32 + xdblp bf16.  M=64 (48 padded), Coct=64
        k_mfma_gemm<2, 0, 1><<<dim3(LL / 128, 1, BB), 256, 0, stream>>>(
            xWp[s], xcp, xdbl, nullptr, xdblp, 64, 64, 64);
        // dt_proj + softplus: dtb fp32.  M=512, Coct=4 (K=16 zero-padded to 32)
        k_mfma_gemm<4, 1, 0><<<dim3(LL / 128, 512 / 128, BB), 256, 0, stream>>>(
            dtWp[s], xdblp, dtb, P[5], nullptr, 512, 4, 8);
        // selective scan (chunked), fused +u*D and *silu(z) -> ybp bf16
        k_scanA<<<dim3(NC * BB * EE * NN / 256), 256, 0, stream>>>(dtb, xc, xdbl, P[6], aprod, hendb);
        k_scanB<<<dim3(BB * EE * NN / 256), 256, 0, stream>>>(aprod, hendb, carry);
        k_scanC<<<dim3(NC * BB * EE * NN / 256), 256, 0, stream>>>(dtb, xc, xdbl, P[6], P[7], xz, carry, ybp);
        // out_proj: outbuf (B, D, L) fp32.  M=256, Coct=64
        k_mfma_gemm<4, 0, 0><<<dim3(LL / 128, 256 / 128, BB), 256, 0, stream>>>(
            outWp[s], ybp, outbuf, nullptr, nullptr, 256, 64, 64);
    };

    mamba(out0, sp, 0, soutb);
    mamba(enc, cp, 1, coutb);

    k_final<<<dim3((size_t)BB * DD * LL / 4 / 256), 256, 0, stream>>>(
        x, out0, soutb, coutb, mask, (float*)d_out);
}

// Round 4
// 704.013 us; speedup vs baseline: 2.0576x; 1.1691x over previous
//
#include <hip/hip_runtime.h>
#include <hip/hip_bf16.h>
#include <math.h>

// Problem constants
#define BB 4
#define DD 256
#define LL 2048
#define EE 512
#define NN 16
#define KK 7
#define RR 16
#define NC 64              // scan chunks
#define CLEN (LL / NC)     // 32 steps per chunk
#define LPAD 2064          // padded L for conv input (8 zeros each side)

typedef __attribute__((ext_vector_type(8))) short short8;   // 8 bf16 (4 VGPRs)
typedef __attribute__((ext_vector_type(4))) float floatx4;  // MFMA accumulator

static __device__ __forceinline__ unsigned short bfbits(float f) {
    __hip_bfloat16 h = __float2bfloat16(f);
    return *(unsigned short*)&h;
}

// ---------------------------------------------------------------------------
// Pack a weight matrix W[M][C] fp32 -> Wp[co][Mp][8] bf16 (zero-padded).
// ---------------------------------------------------------------------------
__global__ __launch_bounds__(256) void k_pack_w(const float* __restrict__ W,
                                                unsigned short* __restrict__ Wp,
                                                int M, int C, int Mp, int Coct) {
    int cell = blockIdx.x * 256 + threadIdx.x;
    if (cell >= Coct * Mp) return;
    int co = cell / Mp, m = cell - co * Mp;
    unsigned short v[8];
#pragma unroll
    for (int j = 0; j < 8; ++j) {
        int c = co * 8 + j;
        float f = (m < M && c < C) ? W[(size_t)m * C + c] : 0.f;
        v[j] = bfbits(f);
    }
    *(uint4*)&Wp[(size_t)cell * 8] = *(uint4*)v;
}

// ff_w (Do, Di, K) -> Wffp[k][co][do][8] with di = co*8+j
__global__ __launch_bounds__(256) void k_pack_ffw(const float* __restrict__ w,
                                                  unsigned short* __restrict__ Wp) {
    int cell = blockIdx.x * 256 + threadIdx.x;   // 7*32*256
    if (cell >= KK * 32 * DD) return;
    int doo = cell % DD;
    int rest = cell / DD;
    int co = rest % 32, k = rest / 32;
    unsigned short v[8];
#pragma unroll
    for (int j = 0; j < 8; ++j)
        v[j] = bfbits(w[((size_t)doo * DD + co * 8 + j) * KK + k]);
    *(uint4*)&Wp[(size_t)cell * 8] = *(uint4*)v;
}

// x (B, D, L) fp32 -> xp[b][co][l+8][8] bf16 with 8-column zero pad both sides
__global__ __launch_bounds__(256) void k_pack_x(const float* __restrict__ x,
                                                unsigned short* __restrict__ xp) {
    int l = blockIdx.x * 256 + threadIdx.x;
    int co = blockIdx.y, b = blockIdx.z;
    if (l >= LPAD) return;
    int sl = l - 8;
    unsigned short v[8];
#pragma unroll
    for (int j = 0; j < 8; ++j) {
        float f = (sl >= 0 && sl < LL) ? x[((size_t)(b * DD) + co * 8 + j) * LL + sl] : 0.f;
        v[j] = bfbits(f);
    }
    *(uint4*)&xp[(((size_t)(b * 32) + co) * LPAD + l) * 8] = *(uint4*)v;
}

// A = -exp(A_log), precomputed once per mamba block (E*N = 8192)
__global__ __launch_bounds__(256) void k_aexp(const float* __restrict__ A_log,
                                              float* __restrict__ aexp) {
    int i = blockIdx.x * 256 + threadIdx.x;
    if (i < EE * NN) aexp[i] = -expf(A_log[i]);
}

// ---------------------------------------------------------------------------
// instance norm over L per (b,d), fused * mask, writes packed bf16 [b][d/8][l][8].
// ---------------------------------------------------------------------------
__global__ __launch_bounds__(256) void k_instnorm(const float* __restrict__ x,
                                                  const float* __restrict__ mask,
                                                  unsigned short* __restrict__ outp) {
    const int bd = blockIdx.x;
    const int b = bd >> 8, d = bd & 255;
    const int tid = threadIdx.x;
    const float* row = x + (size_t)bd * LL;
    float v[8];
    float s = 0.f, s2 = 0.f;
#pragma unroll
    for (int i = 0; i < 8; ++i) {
        v[i] = row[i * 256 + tid];
        s += v[i];
        s2 = fmaf(v[i], v[i], s2);
    }
#pragma unroll
    for (int off = 32; off > 0; off >>= 1) {
        s  += __shfl_down(s, off);
        s2 += __shfl_down(s2, off);
    }
    __shared__ float red[2][4];
    if ((tid & 63) == 0) { red[0][tid >> 6] = s; red[1][tid >> 6] = s2; }
    __syncthreads();
    s  = red[0][0] + red[0][1] + red[0][2] + red[0][3];
    s2 = red[1][0] + red[1][1] + red[1][2] + red[1][3];
    const float mu  = s * (1.f / LL);
    const float var = s2 * (1.f / LL) - mu * mu;
    const float inv = rsqrtf(var + 1e-5f);
    const float* mrow = mask + (size_t)b * LL;
    unsigned short* op = outp + ((size_t)(b * 32) + (d >> 3)) * LL * 8 + (d & 7);
#pragma unroll
    for (int i = 0; i < 8; ++i) {
        int l = i * 256 + tid;
        op[(size_t)l * 8] = bfbits((v[i] - mu) * inv * mrow[l]);
    }
}

// ---------------------------------------------------------------------------
// MFMA GEMM: out[b][m][l] = act(bias[m] + sum_c A[m][c] * B[b][c][l])
// A packed [co][Ms][8] bf16, B packed [b][co][L][8] bf16.
// Block 256 thr = 4 waves (2x2), tile (RM*32) m x 128 l, BK=32.
// BCT: rows [16,48) additionally written transposed to bct[b][l][32] fp32.
// ---------------------------------------------------------------------------
template <int RM, int ACT, int PACKOUT, int BCT>
__global__ __launch_bounds__(256) void k_mfma_gemm(
        const unsigned short* __restrict__ Ap,
        const unsigned short* __restrict__ Bp,
        float* __restrict__ out,
        const float* __restrict__ bias,
        unsigned short* __restrict__ pout,
        float* __restrict__ bct,
        int Ms, int Coct, int BoctPhys) {
    constexpr int TM = RM * 32;
    constexpr int APITCH = TM * 8 + 8;       // shorts per c-octet slab (+16B pad)
    constexpr int BPITCH = 128 * 8 + 8;
    constexpr int ACELLS = (4 * TM) / 256;
    __shared__ unsigned short As[4 * APITCH];
    __shared__ unsigned short Bs[4 * BPITCH];
    const int tid = threadIdx.x;
    const int w = tid >> 6, lane = tid & 63;
    const int quad = lane >> 4, t = lane & 15;
    const int wm = (w >> 1) * (RM * 16), wl = (w & 1) * 64;
    const int l0 = blockIdx.x * 128;
    const int m0 = blockIdx.y * TM;
    const int b  = blockIdx.z;
    const size_t Bbase = (size_t)b * BoctPhys * LL * 8;

    floatx4 acc[RM][4];
#pragma unroll
    for (int r = 0; r < RM; ++r)
#pragma unroll
        for (int j = 0; j < 4; ++j) acc[r][j] = (floatx4){0.f, 0.f, 0.f, 0.f};

    for (int c0 = 0; c0 < Coct; c0 += 4) {
        uint4 areg[ACELLS], breg[2];
#pragma unroll
        for (int i = 0; i < ACELLS; ++i) {
            int cell = tid + i * 256;
            int q = cell / TM, mm = cell % TM;
            areg[i] = *(const uint4*)&Ap[((size_t)(c0 + q) * Ms + m0 + mm) * 8];
        }
#pragma unroll
        for (int i = 0; i < 2; ++i) {
            int cell = tid + i * 256;
            int q = cell >> 7, ll = cell & 127;
            breg[i] = *(const uint4*)&Bp[Bbase + ((size_t)(c0 + q) * LL + l0 + ll) * 8];
        }
        __syncthreads();
#pragma unroll
        for (int i = 0; i < ACELLS; ++i) {
            int cell = tid + i * 256;
            int q = cell / TM, mm = cell % TM;
            *(uint4*)&As[q * APITCH + mm * 8] = areg[i];
        }
#pragma unroll
        for (int i = 0; i < 2; ++i) {
            int cell = tid + i * 256;
            int q = cell >> 7, ll = cell & 127;
            *(uint4*)&Bs[q * BPITCH + ll * 8] = breg[i];
        }
        __syncthreads();
        short8 af[RM], bfv[4];
#pragma unroll
        for (int r = 0; r < RM; ++r)
            af[r] = *(short8*)&As[quad * APITCH + (wm + r * 16 + t) * 8];
#pragma unroll
        for (int j = 0; j < 4; ++j)
            bfv[j] = *(short8*)&Bs[quad * BPITCH + (wl + j * 16 + t) * 8];
#pragma unroll
        for (int r = 0; r < RM; ++r)
#pragma unroll
            for (int j = 0; j < 4; ++j)
                acc[r][j] = __builtin_amdgcn_mfma_f32_16x16x32_bf16(af[r], bfv[j], acc[r][j], 0, 0, 0);
    }
    // epilogue: C/D layout col = lane&15 (l), row = quad*4 + reg (m)
#pragma unroll
    for (int r = 0; r < RM; ++r) {
        int mb = m0 + wm + r * 16 + quad * 4;
#pragma unroll
        for (int i = 0; i < 4; ++i) {
            int m = mb + i;
            float bv = bias ? bias[m] : 0.f;
#pragma unroll
            for (int j = 0; j < 4; ++j) {
                int l = l0 + wl + j * 16 + t;
                float v = acc[r][j][i] + bv;
                if (ACT == 1) v = fmaxf(v, 0.f) + log1pf(expf(-fabsf(v)));  // softplus
                out[((size_t)b * Ms + m) * LL + l] = v;
                if (PACKOUT)
                    pout[(((size_t)b * (Ms / 8) + (m >> 3)) * LL + l) * 8 + (m & 7)] = bfbits(v);
                if (BCT) {
                    if (m >= 16 && m < 48)
                        bct[((size_t)b * LL + l) * 32 + (m - 16)] = v;
                }
            }
        }
    }
}

// ---------------------------------------------------------------------------
// conv_ff as 7 shifted MFMA GEMM sweeps over padded packed x.
// ---------------------------------------------------------------------------
__global__ __launch_bounds__(256) void k_conv_mfma(
        const unsigned short* __restrict__ Wp,
        const unsigned short* __restrict__ Xp,
        const float* __restrict__ bias,
        float* __restrict__ out) {
    constexpr int APITCH = 128 * 8 + 8, BPITCH = 128 * 8 + 8;
    __shared__ unsigned short As[4 * APITCH];
    __shared__ unsigned short Bs[4 * BPITCH];
    const int tid = threadIdx.x;
    const int w = tid >> 6, lane = tid & 63;
    const int quad = lane >> 4, t = lane & 15;
    const int wm = (w >> 1) * 64, wl = (w & 1) * 64;
    const int l0 = blockIdx.x * 128;
    const int m0 = blockIdx.y * 128;
    const int b  = blockIdx.z;

    floatx4 acc[4][4];
#pragma unroll
    for (int r = 0; r < 4; ++r)
#pragma unroll
        for (int j = 0; j < 4; ++j) acc[r][j] = (floatx4){0.f, 0.f, 0.f, 0.f};

    for (int it = 0; it < KK * 8; ++it) {
        int k = it >> 3, dc = it & 7;        // tap, di-chunk (4 octets each)
        uint4 areg[2], breg[2];
#pragma unroll
        for (int i = 0; i < 2; ++i) {
            int cell = tid + i * 256;
            int q = cell >> 7, mm = cell & 127;
            areg[i] = *(const uint4*)&Wp[(((size_t)k * 32 + dc * 4 + q) * DD + m0 + mm) * 8];
            breg[i] = *(const uint4*)&Xp[(((size_t)b * 32 + dc * 4 + q) * LPAD + l0 + mm + 5 + k) * 8];
        }
        __syncthreads();
#pragma unroll
        for (int i = 0; i < 2; ++i) {
            int cell = tid + i * 256;
            int q = cell >> 7, mm = cell & 127;
            *(uint4*)&As[q * APITCH + mm * 8] = areg[i];
            *(uint4*)&Bs[q * BPITCH + mm * 8] = breg[i];
        }
        __syncthreads();
        short8 af[4], bfv[4];
#pragma unroll
        for (int r = 0; r < 4; ++r)
            af[r] = *(short8*)&As[quad * APITCH + (wm + r * 16 + t) * 8];
#pragma unroll
        for (int j = 0; j < 4; ++j)
            bfv[j] = *(short8*)&Bs[quad * BPITCH + (wl + j * 16 + t) * 8];
#pragma unroll
        for (int r = 0; r < 4; ++r)
#pragma unroll
            for (int j = 0; j < 4; ++j)
                acc[r][j] = __builtin_amdgcn_mfma_f32_16x16x32_bf16(af[r], bfv[j], acc[r][j], 0, 0, 0);
    }
#pragma unroll
    for (int r = 0; r < 4; ++r) {
        int mb = m0 + wm + r * 16 + quad * 4;
#pragma unroll
        for (int i = 0; i < 4; ++i) {
            int m = mb + i;
            float bv = bias[m];
#pragma unroll
            for (int j = 0; j < 4; ++j) {
                int l = l0 + wl + j * 16 + t;
                float v = acc[r][j][i] + bv;
                out[((size_t)b * DD + m) * LL + l] = v > 0.f ? v : 0.f;
            }
        }
    }
}

// ---------------------------------------------------------------------------
// Depthwise causal conv (K=7) + silu.  Writes fp32 xc and packed bf16 xcp.
// ---------------------------------------------------------------------------
__global__ __launch_bounds__(256) void k_dwconv(const float* __restrict__ xz,
                                                const float* __restrict__ cw,
                                                const float* __restrict__ cb,
                                                float* __restrict__ xc,
                                                unsigned short* __restrict__ xcp) {
    const int l = blockIdx.x * 256 + threadIdx.x;
    const int e = blockIdx.y;
    const int b = blockIdx.z;
    const float* row = xz + ((size_t)b * (2 * EE) + e) * LL;
    float wv[KK];
#pragma unroll
    for (int k = 0; k < KK; ++k) wv[k] = cw[e * KK + k];
    float acc = cb[e];
#pragma unroll
    for (int k = 0; k < KK; ++k) {
        int ll = l + k - (KK - 1);
        if (ll >= 0) acc = fmaf(row[ll], wv[k], acc);
    }
    float sig = 1.f / (1.f + expf(-acc));
    float v = acc * sig;
    xc[((size_t)b * EE + e) * LL + l] = v;
    xcp[(((size_t)(b * 64) + (e >> 3)) * LL + l) * 8 + (e & 7)] = bfbits(v);
}

// ---------------------------------------------------------------------------
// Selective scan v2: one thread owns all 16 n-states of one (b,e) chunk.
// t = ch*2048 + b*512 + e  (lanes = consecutive e -> B/C loads broadcast).
// B/C from bct[b][l][32] fp32 (B rows 0-15, C rows 16-31).
// aprod/hend/carry layout: [ch][b][e][n] = t*16+n.
// ---------------------------------------------------------------------------
__global__ __launch_bounds__(256) void k_scanA(const float* __restrict__ dtb,
                                               const float* __restrict__ u,
                                               const float* __restrict__ bct,
                                               const float* __restrict__ aexp,
                                               float* __restrict__ aprod,
                                               float* __restrict__ hend) {
    const int t = blockIdx.x * 256 + threadIdx.x;
    const int e = t & (EE - 1);
    const int b = (t >> 9) & (BB - 1);
    const int ch = t >> 11;
    float A[16], h[16], ap[16];
    *(float4*)&A[0]  = *(const float4*)&aexp[e * 16 + 0];
    *(float4*)&A[4]  = *(const float4*)&aexp[e * 16 + 4];
    *(float4*)&A[8]  = *(const float4*)&aexp[e * 16 + 8];
    *(float4*)&A[12] = *(const float4*)&aexp[e * 16 + 12];
#pragma unroll
    for (int n = 0; n < 16; ++n) { h[n] = 0.f; ap[n] = 1.f; }
    const size_t rbe = (size_t)(b * EE + e) * LL + ch * CLEN;
    const float* dtp = dtb + rbe;
    const float* up  = u + rbe;
    const float* bc  = bct + ((size_t)(b * LL) + ch * CLEN) * 32;
    for (int i = 0; i < CLEN; i += 4) {
        float4 d4 = *(const float4*)(dtp + i);
        float4 u4 = *(const float4*)(up + i);
        float dv4[4] = {d4.x, d4.y, d4.z, d4.w};
        float uv4[4] = {u4.x, u4.y, u4.z, u4.w};
#pragma unroll
        for (int j = 0; j < 4; ++j) {
            float dv = dv4[j], du = dv * uv4[j];
            const float* bcl = bc + (size_t)(i + j) * 32;
            float Bv[16];
            *(float4*)&Bv[0]  = *(const float4*)(bcl + 0);
            *(float4*)&Bv[4]  = *(const float4*)(bcl + 4);
            *(float4*)&Bv[8]  = *(const float4*)(bcl + 8);
            *(float4*)&Bv[12] = *(const float4*)(bcl + 12);
#pragma unroll
            for (int n = 0; n < 16; ++n) {
                float dA = __expf(dv * A[n]);
                h[n] = fmaf(dA, h[n], du * Bv[n]);
                ap[n] *= dA;
            }
        }
    }
    float* app = aprod + (size_t)t * 16;
    float* hp  = hend + (size_t)t * 16;
    *(float4*)&app[0] = *(float4*)&ap[0];   *(float4*)&app[4] = *(float4*)&ap[4];
    *(float4*)&app[8] = *(float4*)&ap[8];   *(float4*)&app[12] = *(float4*)&ap[12];
    *(float4*)&hp[0] = *(float4*)&h[0];     *(float4*)&hp[4] = *(float4*)&h[4];
    *(float4*)&hp[8] = *(float4*)&h[8];     *(float4*)&hp[12] = *(float4*)&h[12];
}

// Pass B (in place): aprod[idx] <- carry into chunk ch for each (b,e,n).
__global__ __launch_bounds__(256) void k_scanB(float* __restrict__ aprod,
                                               const float* __restrict__ hend) {
    const int s = blockIdx.x * 256 + threadIdx.x;   // (b,e,n) = 32768
    float c = 0.f;
#pragma unroll
    for (int ch = 0; ch < NC; ++ch) {
        size_t idx = (size_t)ch * (BB * EE * NN) + s;
        float a = aprod[idx];
        float hh = hend[idx];
        aprod[idx] = c;
        c = fmaf(a, c, hh);
    }
}

// Pass C: re-scan with carry-in; y = (sum_n h*C + u*Dp) * silu(z) -> packed bf16.
__global__ __launch_bounds__(256) void k_scanC(const float* __restrict__ dtb,
                                               const float* __restrict__ u,
                                               const float* __restrict__ bct,
                                               const float* __restrict__ aexp,
                                               const float* __restrict__ Dp,
                                               const float* __restrict__ xz,
                                               const float* __restrict__ carry,
                                               unsigned short* __restrict__ ybp) {
    const int t = blockIdx.x * 256 + threadIdx.x;
    const int e = t & (EE - 1);
    const int b = (t >> 9) & (BB - 1);
    const int ch = t >> 11;
    float A[16], h[16];
    *(float4*)&A[0]  = *(const float4*)&aexp[e * 16 + 0];
    *(float4*)&A[4]  = *(const float4*)&aexp[e * 16 + 4];
    *(float4*)&A[8]  = *(const float4*)&aexp[e * 16 + 8];
    *(float4*)&A[12] = *(const float4*)&aexp[e * 16 + 12];
    const float* cp0 = carry + (size_t)t * 16;
    *(float4*)&h[0]  = *(const float4*)&cp0[0];
    *(float4*)&h[4]  = *(const float4*)&cp0[4];
    *(float4*)&h[8]  = *(const float4*)&cp0[8];
    *(float4*)&h[12] = *(const float4*)&cp0[12];
    const float Dpe = Dp[e];
    const size_t rbe = (size_t)(b * EE + e) * LL + ch * CLEN;
    const float* dtp = dtb + rbe;
    const float* up  = u + rbe;
    const float* zp  = xz + ((size_t)(b * 2 * EE) + EE + e) * LL + ch * CLEN;
    const float* bc  = bct + ((size_t)(b * LL) + ch * CLEN) * 32;
    unsigned short* yp = ybp + (((size_t)(b * 64) + (e >> 3)) * LL + ch * CLEN) * 8 + (e & 7);
    for (int i = 0; i < CLEN; i += 4) {
        float4 d4 = *(const float4*)(dtp + i);
        float4 u4 = *(const float4*)(up + i);
        float4 z4 = *(const float4*)(zp + i);
        float dv4[4] = {d4.x, d4.y, d4.z, d4.w};
        float uv4[4] = {u4.x, u4.y, u4.z, u4.w};
        float zv4[4] = {z4.x, z4.y, z4.z, z4.w};
#pragma unroll
        for (int j = 0; j < 4; ++j) {
            float dv = dv4[j], du = dv * uv4[j];
            const float* bcl = bc + (size_t)(i + j) * 32;
            float Bv[16], Cv[16];
            *(float4*)&Bv[0]  = *(const float4*)(bcl + 0);
            *(float4*)&Bv[4]  = *(const float4*)(bcl + 4);
            *(float4*)&Bv[8]  = *(const float4*)(bcl + 8);
            *(float4*)&Bv[12] = *(const float4*)(bcl + 12);
            *(float4*)&Cv[0]  = *(const float4*)(bcl + 16);
            *(float4*)&Cv[4]  = *(const float4*)(bcl + 20);
            *(float4*)&Cv[8]  = *(const float4*)(bcl + 24);
            *(float4*)&Cv[12] = *(const float4*)(bcl + 28);
            float p0 = 0.f, p1 = 0.f, p2 = 0.f, p3 = 0.f;
#pragma unroll
            for (int n = 0; n < 4; ++n) {
                float dA = __expf(dv * A[n]);
                h[n] = fmaf(dA, h[n], du * Bv[n]);
                p0 = fmaf(h[n], Cv[n], p0);
            }
#pragma unroll
            for (int n = 4; n < 8; ++n) {
                float dA = __expf(dv * A[n]);
                h[n] = fmaf(dA, h[n], du * Bv[n]);
                p1 = fmaf(h[n], Cv[n], p1);
            }
#pragma unroll
            for (int n = 8; n < 12; ++n) {
                float dA = __expf(dv * A[n]);
                h[n] = fmaf(dA, h[n], du * Bv[n]);
                p2 = fmaf(h[n], Cv[n], p2);
            }
#pragma unroll
            for (int n = 12; n < 16; ++n) {
                float dA = __expf(dv * A[n]);
                h[n] = fmaf(dA, h[n], du * Bv[n]);
                p3 = fmaf(h[n], Cv[n], p3);
            }
            float p = (p0 + p1) + (p2 + p3) + uv4[j] * Dpe;
            float zz = zv4[j];
            float sig = 1.f / (1.f + __expf(-zz));
            yp[(size_t)(i + j) * 8] = bfbits(p * (zz * sig));
        }
    }
}

// ---------------------------------------------------------------------------
// final: out = (x + out0 + (s + c) * mask) * mask
// ---------------------------------------------------------------------------
__global__ __launch_bounds__(256) void k_final(const float* __restrict__ x,
                                               const float* __restrict__ out0,
                                               const float* __restrict__ sout,
                                               const float* __restrict__ cout,
                                               const float* __restrict__ mask,
                                               float* __restrict__ out) {
    const size_t idx = ((size_t)blockIdx.x * 256 + threadIdx.x) * 4;
    const size_t row = idx >> 11;
    const int b = (int)(row >> 8);
    const int l = (int)(idx & (LL - 1));
    float4 xv = *(const float4*)(x + idx);
    float4 o0 = *(const float4*)(out0 + idx);
    float4 sv = *(const float4*)(sout + idx);
    float4 cv = *(const float4*)(cout + idx);
    float4 mv = *(const float4*)(mask + (size_t)b * LL + l);
    float4 r;
    r.x = (xv.x + o0.x + (sv.x + cv.x) * mv.x) * mv.x;
    r.y = (xv.y + o0.y + (sv.y + cv.y) * mv.y) * mv.y;
    r.z = (xv.z + o0.z + (sv.z + cv.z) * mv.z) * mv.z;
    r.w = (xv.w + o0.w + (sv.w + cv.w) * mv.w) * mv.w;
    *(float4*)(out + idx) = r;
}

// ---------------------------------------------------------------------------
extern "C" void kernel_launch(void* const* d_in, const int* in_sizes, int n_in,
                              void* d_out, int out_size, void* d_ws, size_t ws_size,
                              hipStream_t stream) {
    const float* x    = (const float*)d_in[0];
    const float* enc  = (const float*)d_in[1];
    const float* mask = (const float*)d_in[2];
    const float* ff_w = (const float*)d_in[3];
    const float* ff_b = (const float*)d_in[4];
    const float* sp[9];
    const float* cp[9];
    for (int i = 0; i < 9; ++i) {
        sp[i] = (const float*)d_in[5 + i];
        cp[i] = (const float*)d_in[14 + i];
    }

    // workspace carve-up
    float* ws = (float*)d_ws;
    auto fcarve = [&](size_t n) { float* p = ws; ws += (n + 3) & ~3ul; return p; };
    float* out0  = fcarve((size_t)BB * DD * LL);
    float* xz    = fcarve((size_t)BB * 2 * EE * LL);
    float* xc    = fcarve((size_t)BB * EE * LL);
    float* dtb   = fcarve((size_t)BB * EE * LL);
    float* soutb = fcarve((size_t)BB * DD * LL);
    float* coutb = fcarve((size_t)BB * DD * LL);
    float* aprod = fcarve((size_t)NC * BB * EE * NN);   // doubles as carry (pass B in place)
    float* hendb = fcarve((size_t)NC * BB * EE * NN);
    float* BCt   = fcarve((size_t)BB * LL * 32);
    float* aexp  = fcarve((size_t)EE * NN);
    float* xdbl  = dtb;   // x_proj fp32 out: write-only, dead after; alias dtb (dt GEMM writes later)
    auto scarve = [&](size_t n) { unsigned short* p = (unsigned short*)ws; ws += (n + 7) / 2 / 4 * 4 + 4; return p; };
    unsigned short* nrmp  = scarve((size_t)BB * 32 * LL * 8);
    unsigned short* xcp   = scarve((size_t)BB * 64 * LL * 8);
    unsigned short* xdblp = scarve((size_t)BB * 8 * LL * 8);
    unsigned short* ybp   = scarve((size_t)BB * 64 * LL * 8);
    unsigned short* xp    = scarve((size_t)BB * 32 * LPAD * 8);
    unsigned short* ffWp  = scarve((size_t)KK * 32 * DD * 8);
    unsigned short* inWp[2]  = { scarve(32 * 1024 * 8), scarve(32 * 1024 * 8) };
    unsigned short* outWp[2] = { scarve(64 * 256 * 8),  scarve(64 * 256 * 8) };
    unsigned short* xWp[2]   = { scarve(64 * 64 * 8),   scarve(64 * 64 * 8) };
    unsigned short* dtWp[2]  = { scarve(4 * 512 * 8),   scarve(4 * 512 * 8) };

    // ---- weight / input packing ----
    k_pack_ffw<<<dim3((KK * 32 * DD + 255) / 256), 256, 0, stream>>>(ff_w, ffWp);
    k_pack_x<<<dim3((LPAD + 255) / 256, 32, BB), 256, 0, stream>>>(x, xp);
    for (int s = 0; s < 2; ++s) {
        const float* const* P = s ? cp : sp;
        k_pack_w<<<dim3(32 * 1024 / 256), 256, 0, stream>>>(P[0], inWp[s], 1024, 256, 1024, 32);
        k_pack_w<<<dim3(64 * 256 / 256), 256, 0, stream>>>(P[8], outWp[s], 256, 512, 256, 64);
        k_pack_w<<<dim3(64 * 64 / 256), 256, 0, stream>>>(P[3], xWp[s], 48, 512, 64, 64);
        k_pack_w<<<dim3(4 * 512 / 256), 256, 0, stream>>>(P[4], dtWp[s], 512, 16, 512, 4);
    }

    // ---- conv_ff (MFMA) ----
    k_conv_mfma<<<dim3(LL / 128, DD / 128, BB), 256, 0, stream>>>(ffWp, xp, ff_b, out0);

    auto mamba = [&](const float* src, const float* const* P, int s, float* outbuf) {
        k_instnorm<<<dim3(BB * DD), 256, 0, stream>>>(src, mask, nrmp);
        k_aexp<<<dim3(EE * NN / 256), 256, 0, stream>>>(P[6], aexp);
        // in_proj: xz (B, 2E, L) fp32.  M=1024, Coct=32
        k_mfma_gemm<4, 0, 0, 0><<<dim3(LL / 128, 1024 / 128, BB), 256, 0, stream>>>(
            inWp[s], nrmp, xz, nullptr, nullptr, nullptr, 1024, 32, 32);
        // depthwise conv + silu -> xc fp32 + xcp bf16
        k_dwconv<<<dim3(LL / 256, EE, BB), 256, 0, stream>>>(xz, P[1], P[2], xc, xcp);
        // x_proj: M=64 (48 padded), Coct=64; writes xdblp bf16 + BCt transposed fp32
        k_mfma_gemm<2, 0, 1, 1><<<dim3(LL / 128, 1, BB), 256, 0, stream>>>(
            xWp[s], xcp, xdbl, nullptr, xdblp, BCt, 64, 64, 64);
        // dt_proj + softplus: dtb fp32.  M=512, Coct=4 (K=16 zero-padded to 32)
        k_mfma_gemm<4, 1, 0, 0><<<dim3(LL / 128, 512 / 128, BB), 256, 0, stream>>>(
            dtWp[s], xdblp, dtb, P[5], nullptr, nullptr, 512, 4, 8);
        // selective scan (chunked linear recurrence), fused +u*D and *silu(z) -> ybp bf16
        k_scanA<<<dim3(NC * BB * EE / 256), 256, 0, stream>>>(dtb, xc, BCt, aexp, aprod, hendb);
        k_scanB<<<dim3(BB * EE * NN / 256), 256, 0, stream>>>(aprod, hendb);
        k_scanC<<<dim3(NC * BB * EE / 256), 256, 0, stream>>>(dtb, xc, BCt, aexp, P[7], xz, aprod, ybp);
        // out_proj: outbuf (B, D, L) fp32.  M=256, Coct=64
        k_mfma_gemm<4, 0, 0, 0><<<dim3(LL / 128, 256 / 128, BB), 256, 0, stream>>>(
            outWp[s], ybp, outbuf, nullptr, nullptr, nullptr, 256, 64, 64);
    };

    mamba(out0, sp, 0, soutb);
    mamba(enc, cp, 1, coutb);

    k_final<<<dim3((size_t)BB * DD * LL / 4 / 256), 256, 0, stream>>>(
        x, out0, soutb, coutb, mask, (float*)d_out);
}

// Round 5
// 661.654 us; speedup vs baseline: 2.1893x; 1.0640x over previous
//
#include <hip/hip_runtime.h>
#include <hip/hip_bf16.h>
#include <math.h>

// Problem constants
#define BB 4
#define DD 256
#define LL 2048
#define EE 512
#define NN 16
#define KK 7
#define RR 16
#define NC 64              // scan chunks
#define CLEN (LL / NC)     // 32 steps per chunk
#define LPAD 2064          // padded L for conv input (8 zeros each side)

typedef __attribute__((ext_vector_type(8))) short short8;   // 8 bf16 (4 VGPRs)
typedef __attribute__((ext_vector_type(4))) float floatx4;  // MFMA accumulator

static __device__ __forceinline__ unsigned short bfbits(float f) {
    __hip_bfloat16 h = __float2bfloat16(f);
    return *(unsigned short*)&h;
}

// ---------------------------------------------------------------------------
// Fused packing: all weights + aexp in ONE dispatch. grid (224, 11).
// ---------------------------------------------------------------------------
static __device__ __forceinline__ void pack_w_seg(const float* __restrict__ W,
                                                  unsigned short* __restrict__ Wp,
                                                  int M, int C, int Mp, int Coct,
                                                  int cell) {
    if (cell >= Coct * Mp) return;
    int co = cell / Mp, m = cell - co * Mp;
    unsigned short v[8];
#pragma unroll
    for (int j = 0; j < 8; ++j) {
        int c = co * 8 + j;
        float f = (m < M && c < C) ? W[(size_t)m * C + c] : 0.f;
        v[j] = bfbits(f);
    }
    *(uint4*)&Wp[(size_t)cell * 8] = *(uint4*)v;
}

__global__ __launch_bounds__(256) void k_pack_fused(
        const float* __restrict__ ffw, unsigned short* __restrict__ ffWp,
        const float* __restrict__ sW0, unsigned short* __restrict__ inW0,
        const float* __restrict__ cW0, unsigned short* __restrict__ inW1,
        const float* __restrict__ sW8, unsigned short* __restrict__ outW0,
        const float* __restrict__ cW8, unsigned short* __restrict__ outW1,
        const float* __restrict__ sW3, unsigned short* __restrict__ xW0,
        const float* __restrict__ cW3, unsigned short* __restrict__ xW1,
        const float* __restrict__ sW4, unsigned short* __restrict__ dtW0,
        const float* __restrict__ cW4, unsigned short* __restrict__ dtW1,
        const float* __restrict__ sAl, float* __restrict__ aexp0,
        const float* __restrict__ cAl, float* __restrict__ aexp1) {
    int cell = blockIdx.x * 256 + threadIdx.x;
    switch (blockIdx.y) {
    case 0: {  // ff_w (Do,Di,K) -> [k][co][do][8]
        if (cell >= KK * 32 * DD) return;
        int doo = cell % DD;
        int rest = cell / DD;
        int co = rest % 32, k = rest / 32;
        unsigned short v[8];
#pragma unroll
        for (int j = 0; j < 8; ++j)
            v[j] = bfbits(ffw[((size_t)doo * DD + co * 8 + j) * KK + k]);
        *(uint4*)&ffWp[(size_t)cell * 8] = *(uint4*)v;
    } break;
    case 1: pack_w_seg(sW0, inW0, 1024, 256, 1024, 32, cell); break;
    case 2: pack_w_seg(cW0, inW1, 1024, 256, 1024, 32, cell); break;
    case 3: pack_w_seg(sW8, outW0, 256, 512, 256, 64, cell); break;
    case 4: pack_w_seg(cW8, outW1, 256, 512, 256, 64, cell); break;
    case 5: pack_w_seg(sW3, xW0, 48, 512, 64, 64, cell); break;
    case 6: pack_w_seg(cW3, xW1, 48, 512, 64, 64, cell); break;
    case 7: pack_w_seg(sW4, dtW0, 512, 16, 512, 4, cell); break;
    case 8: pack_w_seg(cW4, dtW1, 512, 16, 512, 4, cell); break;
    case 9:  if (cell < EE * NN) aexp0[cell] = -expf(sAl[cell]); break;
    case 10: if (cell < EE * NN) aexp1[cell] = -expf(cAl[cell]); break;
    }
}

// x (B, D, L) fp32 -> xp[b][co][l+8][8] bf16 with 8-column zero pad both sides
__global__ __launch_bounds__(256) void k_pack_x(const float* __restrict__ x,
                                                unsigned short* __restrict__ xp) {
    int l = blockIdx.x * 256 + threadIdx.x;
    int co = blockIdx.y, b = blockIdx.z;
    if (l >= LPAD) return;
    int sl = l - 8;
    unsigned short v[8];
#pragma unroll
    for (int j = 0; j < 8; ++j) {
        float f = (sl >= 0 && sl < LL) ? x[((size_t)(b * DD) + co * 8 + j) * LL + sl] : 0.f;
        v[j] = bfbits(f);
    }
    *(uint4*)&xp[(((size_t)(b * 32) + co) * LPAD + l) * 8] = *(uint4*)v;
}

// ---------------------------------------------------------------------------
// instance norm over L per (b,d), fused * mask, writes packed bf16 [b][d/8][l][8].
// ---------------------------------------------------------------------------
__global__ __launch_bounds__(256) void k_instnorm(const float* __restrict__ x,
                                                  const float* __restrict__ mask,
                                                  unsigned short* __restrict__ outp) {
    const int bd = blockIdx.x;
    const int b = bd >> 8, d = bd & 255;
    const int tid = threadIdx.x;
    const float* row = x + (size_t)bd * LL;
    float v[8];
    float s = 0.f, s2 = 0.f;
#pragma unroll
    for (int i = 0; i < 8; ++i) {
        v[i] = row[i * 256 + tid];
        s += v[i];
        s2 = fmaf(v[i], v[i], s2);
    }
#pragma unroll
    for (int off = 32; off > 0; off >>= 1) {
        s  += __shfl_down(s, off);
        s2 += __shfl_down(s2, off);
    }
    __shared__ float red[2][4];
    if ((tid & 63) == 0) { red[0][tid >> 6] = s; red[1][tid >> 6] = s2; }
    __syncthreads();
    s  = red[0][0] + red[0][1] + red[0][2] + red[0][3];
    s2 = red[1][0] + red[1][1] + red[1][2] + red[1][3];
    const float mu  = s * (1.f / LL);
    const float var = s2 * (1.f / LL) - mu * mu;
    const float inv = rsqrtf(var + 1e-5f);
    const float* mrow = mask + (size_t)b * LL;
    unsigned short* op = outp + ((size_t)(b * 32) + (d >> 3)) * LL * 8 + (d & 7);
#pragma unroll
    for (int i = 0; i < 8; ++i) {
        int l = i * 256 + tid;
        op[(size_t)l * 8] = bfbits((v[i] - mu) * inv * mrow[l]);
    }
}

// ---------------------------------------------------------------------------
// MFMA GEMM, double-buffered LDS, one barrier per K-chunk (BK=32).
// out[b][m][l] = act(bias[m] + sum_c A[m][c] * B[b][c][l])
// A packed [co][Ms][8] bf16, B packed [b][co][L][8] bf16.
// Block 256 thr = 4 waves (2x2), tile (RM*32)m x (NLT*32)l.
// ---------------------------------------------------------------------------
template <int RM, int NLT, int ACT, int PACKOUT, int BCT>
__global__ __launch_bounds__(256) void k_mfma_gemm(
        const unsigned short* __restrict__ Ap,
        const unsigned short* __restrict__ Bp,
        float* __restrict__ out,
        const float* __restrict__ bias,
        unsigned short* __restrict__ pout,
        float* __restrict__ bct,
        int Ms, int Coct, int BoctPhys) {
    constexpr int TM = RM * 32;
    constexpr int TL = NLT * 32;
    constexpr int APITCH = TM * 8 + 8;
    constexpr int BPITCH = TL * 8 + 8;
    constexpr int ACELLS = (4 * TM) / 256;
    constexpr int BCELLS = (4 * TL) / 256;
    __shared__ unsigned short As[2][4 * APITCH];
    __shared__ unsigned short Bs[2][4 * BPITCH];
    const int tid = threadIdx.x;
    const int w = tid >> 6, lane = tid & 63;
    const int quad = lane >> 4, t = lane & 15;
    const int wm = (w >> 1) * (RM * 16), wl = (w & 1) * (NLT * 16);
    const int l0 = blockIdx.x * TL;
    const int m0 = blockIdx.y * TM;
    const int b  = blockIdx.z;
    const size_t Bbase = (size_t)b * BoctPhys * LL * 8;

    floatx4 acc[RM][NLT];
#pragma unroll
    for (int r = 0; r < RM; ++r)
#pragma unroll
        for (int j = 0; j < NLT; ++j) acc[r][j] = (floatx4){0.f, 0.f, 0.f, 0.f};

    uint4 areg[ACELLS], breg[BCELLS];
    auto loadRegs = [&](int c0) {
#pragma unroll
        for (int i = 0; i < ACELLS; ++i) {
            int cell = tid + i * 256;
            int q = cell / TM, mm = cell % TM;
            areg[i] = *(const uint4*)&Ap[((size_t)(c0 + q) * Ms + m0 + mm) * 8];
        }
#pragma unroll
        for (int i = 0; i < BCELLS; ++i) {
            int cell = tid + i * 256;
            int q = cell / TL, ll = cell % TL;
            breg[i] = *(const uint4*)&Bp[Bbase + ((size_t)(c0 + q) * LL + l0 + ll) * 8];
        }
    };
    auto storeRegs = [&](int p) {
#pragma unroll
        for (int i = 0; i < ACELLS; ++i) {
            int cell = tid + i * 256;
            int q = cell / TM, mm = cell % TM;
            *(uint4*)&As[p][q * APITCH + mm * 8] = areg[i];
        }
#pragma unroll
        for (int i = 0; i < BCELLS; ++i) {
            int cell = tid + i * 256;
            int q = cell / TL, ll = cell % TL;
            *(uint4*)&Bs[p][q * BPITCH + ll * 8] = breg[i];
        }
    };

    loadRegs(0);
    storeRegs(0);
    __syncthreads();
    int p = 0;
    for (int c0 = 4; c0 <= Coct; c0 += 4) {
        const bool has_next = (c0 < Coct);
        if (has_next) loadRegs(c0);
        short8 af[RM], bfv[NLT];
#pragma unroll
        for (int r = 0; r < RM; ++r)
            af[r] = *(short8*)&As[p][quad * APITCH + (wm + r * 16 + t) * 8];
#pragma unroll
        for (int j = 0; j < NLT; ++j)
            bfv[j] = *(short8*)&Bs[p][quad * BPITCH + (wl + j * 16 + t) * 8];
#pragma unroll
        for (int r = 0; r < RM; ++r)
#pragma unroll
            for (int j = 0; j < NLT; ++j)
                acc[r][j] = __builtin_amdgcn_mfma_f32_16x16x32_bf16(af[r], bfv[j], acc[r][j], 0, 0, 0);
        if (has_next) {
            storeRegs(p ^ 1);
            __syncthreads();
            p ^= 1;
        }
    }
    // epilogue: C/D layout col = lane&15 (l), row = quad*4 + reg (m)
#pragma unroll
    for (int r = 0; r < RM; ++r) {
        int mb = m0 + wm + r * 16 + quad * 4;
#pragma unroll
        for (int i = 0; i < 4; ++i) {
            int m = mb + i;
            float bv = bias ? bias[m] : 0.f;
#pragma unroll
            for (int j = 0; j < NLT; ++j) {
                int l = l0 + wl + j * 16 + t;
                float v = acc[r][j][i] + bv;
                if (ACT == 1) v = fmaxf(v, 0.f) + log1pf(expf(-fabsf(v)));  // softplus
                out[((size_t)b * Ms + m) * LL + l] = v;
                if (PACKOUT)
                    pout[(((size_t)b * (Ms / 8) + (m >> 3)) * LL + l) * 8 + (m & 7)] = bfbits(v);
                if (BCT) {
                    if (m >= 16 && m < 48)
                        bct[((size_t)b * LL + l) * 32 + (m - 16)] = v;
                }
            }
        }
    }
}

// ---------------------------------------------------------------------------
// conv_ff v3: tap-reuse. Per di-chunk (32 di): stage x window ONCE (4 oct x 71
// cols) + all 7 taps' weights; 56 MFMA/wave between barriers; 8 iterations.
// Block tile 128m x 64l, grid (32, 2, 4) = 256 blocks.
// ---------------------------------------------------------------------------
__global__ __launch_bounds__(256) void k_conv_mfma(
        const unsigned short* __restrict__ Wp,
        const unsigned short* __restrict__ Xp,
        const float* __restrict__ bias,
        float* __restrict__ out) {
    __shared__ unsigned short As[7 * 4 * 128 * 8];   // [k][q][m][8]  (57 KB)
    __shared__ unsigned short Bs[4 * 72 * 8];        // [q][c][8]     (4.6 KB)
    const int tid = threadIdx.x;
    const int w = tid >> 6, lane = tid & 63;
    const int quad = lane >> 4, t = lane & 15;
    const int wm = (w >> 1) * 64, wl = (w & 1) * 32;
    const int l0 = blockIdx.x * 64;
    const int m0 = blockIdx.y * 128;
    const int b  = blockIdx.z;

    floatx4 acc[4][2];
#pragma unroll
    for (int r = 0; r < 4; ++r)
#pragma unroll
        for (int j = 0; j < 2; ++j) acc[r][j] = (floatx4){0.f, 0.f, 0.f, 0.f};

    uint4 areg[14], breg[2];
    auto loadRegs = [&](int dc) {
#pragma unroll
        for (int i = 0; i < 14; ++i) {
            int cell = tid + i * 256;            // < 3584
            int mm = cell & 127;
            int rest = cell >> 7;                // 0..27
            int q = rest & 3, k = rest >> 2;     // k < 7
            areg[i] = *(const uint4*)&Wp[(((size_t)k * 32 + dc * 4 + q) * DD + m0 + mm) * 8];
        }
#pragma unroll
        for (int i = 0; i < 2; ++i) {
            int cell = tid + i * 256;
            if (cell < 288) {
                int q = cell / 72, c = cell - q * 72;
                breg[i] = *(const uint4*)&Xp[(((size_t)b * 32 + dc * 4 + q) * LPAD + l0 + 5 + c) * 8];
            }
        }
    };

    loadRegs(0);
    for (int dc = 0; dc < 8; ++dc) {
        if (dc) __syncthreads();
#pragma unroll
        for (int i = 0; i < 14; ++i)
            *(uint4*)&As[(size_t)(tid + i * 256) * 8] = areg[i];
#pragma unroll
        for (int i = 0; i < 2; ++i) {
            int cell = tid + i * 256;
            if (cell < 288) *(uint4*)&Bs[(size_t)cell * 8] = breg[i];
        }
        __syncthreads();
        if (dc < 7) loadRegs(dc + 1);
#pragma unroll
        for (int k = 0; k < KK; ++k) {
            short8 af[4], bfv[2];
#pragma unroll
            for (int r = 0; r < 4; ++r)
                af[r] = *(short8*)&As[(((k * 4 + quad) * 128) + wm + r * 16 + t) * 8];
#pragma unroll
            for (int j = 0; j < 2; ++j)
                bfv[j] = *(short8*)&Bs[(quad * 72 + wl + j * 16 + t + k) * 8];
#pragma unroll
            for (int r = 0; r < 4; ++r)
#pragma unroll
                for (int j = 0; j < 2; ++j)
                    acc[r][j] = __builtin_amdgcn_mfma_f32_16x16x32_bf16(af[r], bfv[j], acc[r][j], 0, 0, 0);
        }
    }
#pragma unroll
    for (int r = 0; r < 4; ++r) {
        int mb = m0 + wm + r * 16 + quad * 4;
#pragma unroll
        for (int i = 0; i < 4; ++i) {
            int m = mb + i;
            float bv = bias[m];
#pragma unroll
            for (int j = 0; j < 2; ++j) {
                int l = l0 + wl + j * 16 + t;
                float v = acc[r][j][i] + bv;
                out[((size_t)b * DD + m) * LL + l] = v > 0.f ? v : 0.f;
            }
        }
    }
}

// ---------------------------------------------------------------------------
// Depthwise causal conv (K=7) + silu.  Writes fp32 xc and packed bf16 xcp.
// ---------------------------------------------------------------------------
__global__ __launch_bounds__(256) void k_dwconv(const float* __restrict__ xz,
                                                const float* __restrict__ cw,
                                                const float* __restrict__ cb,
                                                float* __restrict__ xc,
                                                unsigned short* __restrict__ xcp) {
    const int l = blockIdx.x * 256 + threadIdx.x;
    const int e = blockIdx.y;
    const int b = blockIdx.z;
    const float* row = xz + ((size_t)b * (2 * EE) + e) * LL;
    float wv[KK];
#pragma unroll
    for (int k = 0; k < KK; ++k) wv[k] = cw[e * KK + k];
    float acc = cb[e];
#pragma unroll
    for (int k = 0; k < KK; ++k) {
        int ll = l + k - (KK - 1);
        if (ll >= 0) acc = fmaf(row[ll], wv[k], acc);
    }
    float sig = 1.f / (1.f + expf(-acc));
    float v = acc * sig;
    xc[((size_t)b * EE + e) * LL + l] = v;
    xcp[(((size_t)(b * 64) + (e >> 3)) * LL + l) * 8 + (e & 7)] = bfbits(v);
}

// ---------------------------------------------------------------------------
// Selective scan: one thread owns all 16 n-states of one (b,e) chunk.
// t = ch*2048 + b*512 + e.  B/C from bct[b][l][32] fp32 (broadcast loads).
// ---------------------------------------------------------------------------
__global__ __launch_bounds__(256) void k_scanA(const float* __restrict__ dtb,
                                               const float* __restrict__ u,
                                               const float* __restrict__ bct,
                                               const float* __restrict__ aexp,
                                               float* __restrict__ aprod,
                                               float* __restrict__ hend) {
    const int t = blockIdx.x * 256 + threadIdx.x;
    const int e = t & (EE - 1);
    const int b = (t >> 9) & (BB - 1);
    const int ch = t >> 11;
    float A[16], h[16], ap[16];
    *(float4*)&A[0]  = *(const float4*)&aexp[e * 16 + 0];
    *(float4*)&A[4]  = *(const float4*)&aexp[e * 16 + 4];
    *(float4*)&A[8]  = *(const float4*)&aexp[e * 16 + 8];
    *(float4*)&A[12] = *(const float4*)&aexp[e * 16 + 12];
#pragma unroll
    for (int n = 0; n < 16; ++n) { h[n] = 0.f; ap[n] = 1.f; }
    const size_t rbe = (size_t)(b * EE + e) * LL + ch * CLEN;
    const float* dtp = dtb + rbe;
    const float* up  = u + rbe;
    const float* bc  = bct + ((size_t)(b * LL) + ch * CLEN) * 32;
    for (int i = 0; i < CLEN; i += 4) {
        float4 d4 = *(const float4*)(dtp + i);
        float4 u4 = *(const float4*)(up + i);
        float dv4[4] = {d4.x, d4.y, d4.z, d4.w};
        float uv4[4] = {u4.x, u4.y, u4.z, u4.w};
#pragma unroll
        for (int j = 0; j < 4; ++j) {
            float dv = dv4[j], du = dv * uv4[j];
            const float* bcl = bc + (size_t)(i + j) * 32;
            float Bv[16];
            *(float4*)&Bv[0]  = *(const float4*)(bcl + 0);
            *(float4*)&Bv[4]  = *(const float4*)(bcl + 4);
            *(float4*)&Bv[8]  = *(const float4*)(bcl + 8);
            *(float4*)&Bv[12] = *(const float4*)(bcl + 12);
#pragma unroll
            for (int n = 0; n < 16; ++n) {
                float dA = __expf(dv * A[n]);
                h[n] = fmaf(dA, h[n], du * Bv[n]);
                ap[n] *= dA;
            }
        }
    }
    float* app = aprod + (size_t)t * 16;
    float* hp  = hend + (size_t)t * 16;
    *(float4*)&app[0] = *(float4*)&ap[0];   *(float4*)&app[4] = *(float4*)&ap[4];
    *(float4*)&app[8] = *(float4*)&ap[8];   *(float4*)&app[12] = *(float4*)&ap[12];
    *(float4*)&hp[0] = *(float4*)&h[0];     *(float4*)&hp[4] = *(float4*)&h[4];
    *(float4*)&hp[8] = *(float4*)&h[8];     *(float4*)&hp[12] = *(float4*)&h[12];
}

// Pass B (in place): aprod[idx] <- carry into chunk ch for each (b,e,n).
__global__ __launch_bounds__(256) void k_scanB(float* __restrict__ aprod,
                                               const float* __restrict__ hend) {
    const int s = blockIdx.x * 256 + threadIdx.x;   // (b,e,n) = 32768
    float c = 0.f;
#pragma unroll
    for (int ch = 0; ch < NC; ++ch) {
        size_t idx = (size_t)ch * (BB * EE * NN) + s;
        float a = aprod[idx];
        float hh = hend[idx];
        aprod[idx] = c;
        c = fmaf(a, c, hh);
    }
}

// Pass C: re-scan with carry-in; y = (sum_n h*C + u*Dp) * silu(z) -> packed bf16.
__global__ __launch_bounds__(256) void k_scanC(const float* __restrict__ dtb,
                                               const float* __restrict__ u,
                                               const float* __restrict__ bct,
                                               const float* __restrict__ aexp,
                                               const float* __restrict__ Dp,
                                               const float* __restrict__ xz,
                                               const float* __restrict__ carry,
                                               unsigned short* __restrict__ ybp) {
    const int t = blockIdx.x * 256 + threadIdx.x;
    const int e = t & (EE - 1);
    const int b = (t >> 9) & (BB - 1);
    const int ch = t >> 11;
    float A[16], h[16];
    *(float4*)&A[0]  = *(const float4*)&aexp[e * 16 + 0];
    *(float4*)&A[4]  = *(const float4*)&aexp[e * 16 + 4];
    *(float4*)&A[8]  = *(const float4*)&aexp[e * 16 + 8];
    *(float4*)&A[12] = *(const float4*)&aexp[e * 16 + 12];
    const float* cp0 = carry + (size_t)t * 16;
    *(float4*)&h[0]  = *(const float4*)&cp0[0];
    *(float4*)&h[4]  = *(const float4*)&cp0[4];
    *(float4*)&h[8]  = *(const float4*)&cp0[8];
    *(float4*)&h[12] = *(const float4*)&cp0[12];
    const float Dpe = Dp[e];
    const size_t rbe = (size_t)(b * EE + e) * LL + ch * CLEN;
    const float* dtp = dtb + rbe;
    const float* up  = u + rbe;
    const float* zp  = xz + ((size_t)(b * 2 * EE) + EE + e) * LL + ch * CLEN;
    const float* bc  = bct + ((size_t)(b * LL) + ch * CLEN) * 32;
    unsigned short* yp = ybp + (((size_t)(b * 64) + (e >> 3)) * LL + ch * CLEN) * 8 + (e & 7);
    for (int i = 0; i < CLEN; i += 4) {
        float4 d4 = *(const float4*)(dtp + i);
        float4 u4 = *(const float4*)(up + i);
        float4 z4 = *(const float4*)(zp + i);
        float dv4[4] = {d4.x, d4.y, d4.z, d4.w};
        float uv4[4] = {u4.x, u4.y, u4.z, u4.w};
        float zv4[4] = {z4.x, z4.y, z4.z, z4.w};
#pragma unroll
        for (int j = 0; j < 4; ++j) {
            float dv = dv4[j], du = dv * uv4[j];
            const float* bcl = bc + (size_t)(i + j) * 32;
            float Bv[16], Cv[16];
            *(float4*)&Bv[0]  = *(const float4*)(bcl + 0);
            *(float4*)&Bv[4]  = *(const float4*)(bcl + 4);
            *(float4*)&Bv[8]  = *(const float4*)(bcl + 8);
            *(float4*)&Bv[12] = *(const float4*)(bcl + 12);
            *(float4*)&Cv[0]  = *(const float4*)(bcl + 16);
            *(float4*)&Cv[4]  = *(const float4*)(bcl + 20);
            *(float4*)&Cv[8]  = *(const float4*)(bcl + 24);
            *(float4*)&Cv[12] = *(const float4*)(bcl + 28);
            float p0 = 0.f, p1 = 0.f, p2 = 0.f, p3 = 0.f;
#pragma unroll
            for (int n = 0; n < 4; ++n) {
                float dA = __expf(dv * A[n]);
                h[n] = fmaf(dA, h[n], du * Bv[n]);
                p0 = fmaf(h[n], Cv[n], p0);
            }
#pragma unroll
            for (int n = 4; n < 8; ++n) {
                float dA = __expf(dv * A[n]);
                h[n] = fmaf(dA, h[n], du * Bv[n]);
                p1 = fmaf(h[n], Cv[n], p1);
            }
#pragma unroll
            for (int n = 8; n < 12; ++n) {
                float dA = __expf(dv * A[n]);
                h[n] = fmaf(dA, h[n], du * Bv[n]);
                p2 = fmaf(h[n], Cv[n], p2);
            }
#pragma unroll
            for (int n = 12; n < 16; ++n) {
                float dA = __expf(dv * A[n]);
                h[n] = fmaf(dA, h[n], du * Bv[n]);
                p3 = fmaf(h[n], Cv[n], p3);
            }
            float p = (p0 + p1) + (p2 + p3) + uv4[j] * Dpe;
            float zz = zv4[j];
            float sig = 1.f / (1.f + __expf(-zz));
            yp[(size_t)(i + j) * 8] = bfbits(p * (zz * sig));
        }
    }
}

// ---------------------------------------------------------------------------
// final: out = (x + out0 + (s + c) * mask) * mask
// ---------------------------------------------------------------------------
__global__ __launch_bounds__(256) void k_final(const float* __restrict__ x,
                                               const float* __restrict__ out0,
                                               const float* __restrict__ sout,
                                               const float* __restrict__ cout,
                                               const float* __restrict__ mask,
                                               float* __restrict__ out) {
    const size_t idx = ((size_t)blockIdx.x * 256 + threadIdx.x) * 4;
    const size_t row = idx >> 11;
    const int b = (int)(row >> 8);
    const int l = (int)(idx & (LL - 1));
    float4 xv = *(const float4*)(x + idx);
    float4 o0 = *(const float4*)(out0 + idx);
    float4 sv = *(const float4*)(sout + idx);
    float4 cv = *(const float4*)(cout + idx);
    float4 mv = *(const float4*)(mask + (size_t)b * LL + l);
    float4 r;
    r.x = (xv.x + o0.x + (sv.x + cv.x) * mv.x) * mv.x;
    r.y = (xv.y + o0.y + (sv.y + cv.y) * mv.y) * mv.y;
    r.z = (xv.z + o0.z + (sv.z + cv.z) * mv.z) * mv.z;
    r.w = (xv.w + o0.w + (sv.w + cv.w) * mv.w) * mv.w;
    *(float4*)(out + idx) = r;
}

// ---------------------------------------------------------------------------
extern "C" void kernel_launch(void* const* d_in, const int* in_sizes, int n_in,
                              void* d_out, int out_size, void* d_ws, size_t ws_size,
                              hipStream_t stream) {
    const float* x    = (const float*)d_in[0];
    const float* enc  = (const float*)d_in[1];
    const float* mask = (const float*)d_in[2];
    const float* ff_w = (const float*)d_in[3];
    const float* ff_b = (const float*)d_in[4];
    const float* sp[9];
    const float* cp[9];
    for (int i = 0; i < 9; ++i) {
        sp[i] = (const float*)d_in[5 + i];
        cp[i] = (const float*)d_in[14 + i];
    }

    // workspace carve-up
    float* ws = (float*)d_ws;
    auto fcarve = [&](size_t n) { float* p = ws; ws += (n + 3) & ~3ul; return p; };
    float* out0  = fcarve((size_t)BB * DD * LL);
    float* xz    = fcarve((size_t)BB * 2 * EE * LL);
    float* xc    = fcarve((size_t)BB * EE * LL);
    float* dtb   = fcarve((size_t)BB * EE * LL);
    float* soutb = fcarve((size_t)BB * DD * LL);
    float* coutb = fcarve((size_t)BB * DD * LL);
    float* aprod = fcarve((size_t)NC * BB * EE * NN);   // doubles as carry (pass B in place)
    float* hendb = fcarve((size_t)NC * BB * EE * NN);
    float* BCt   = fcarve((size_t)BB * LL * 32);
    float* aexp2 = fcarve((size_t)2 * EE * NN);
    float* xdbl  = dtb;   // x_proj fp32 out: dead after; alias dtb (dt GEMM overwrites)
    auto scarve = [&](size_t n) { unsigned short* p = (unsigned short*)ws; ws += (n + 7) / 2 / 4 * 4 + 4; return p; };
    unsigned short* nrmp  = scarve((size_t)BB * 32 * LL * 8);
    unsigned short* xcp   = scarve((size_t)BB * 64 * LL * 8);
    unsigned short* xdblp = scarve((size_t)BB * 8 * LL * 8);
    unsigned short* ybp   = scarve((size_t)BB * 64 * LL * 8);
    unsigned short* xp    = scarve((size_t)BB * 32 * LPAD * 8);
    unsigned short* ffWp  = scarve((size_t)KK * 32 * DD * 8);
    unsigned short* inWp[2]  = { scarve(32 * 1024 * 8), scarve(32 * 1024 * 8) };
    unsigned short* outWp[2] = { scarve(64 * 256 * 8),  scarve(64 * 256 * 8) };
    unsigned short* xWp[2]   = { scarve(64 * 64 * 8),   scarve(64 * 64 * 8) };
    unsigned short* dtWp[2]  = { scarve(4 * 512 * 8),   scarve(4 * 512 * 8) };

    // ---- fused packing (weights + aexp) + input packing ----
    k_pack_fused<<<dim3(224, 11), 256, 0, stream>>>(
        ff_w, ffWp, sp[0], inWp[0], cp[0], inWp[1], sp[8], outWp[0], cp[8], outWp[1],
        sp[3], xWp[0], cp[3], xWp[1], sp[4], dtWp[0], cp[4], dtWp[1],
        sp[6], aexp2, cp[6], aexp2 + EE * NN);
    k_pack_x<<<dim3((LPAD + 255) / 256, 32, BB), 256, 0, stream>>>(x, xp);

    // ---- conv_ff (MFMA, tap-reuse) ----
    k_conv_mfma<<<dim3(LL / 64, DD / 128, BB), 256, 0, stream>>>(ffWp, xp, ff_b, out0);

    auto mamba = [&](const float* src, const float* const* P, int s, float* outbuf) {
        const float* aexp = aexp2 + s * EE * NN;
        k_instnorm<<<dim3(BB * DD), 256, 0, stream>>>(src, mask, nrmp);
        // in_proj: xz (B, 2E, L) fp32.  M=1024, Coct=32; 128x128 tiles, 512 blocks
        k_mfma_gemm<4, 4, 0, 0, 0><<<dim3(LL / 128, 1024 / 128, BB), 256, 0, stream>>>(
            inWp[s], nrmp, xz, nullptr, nullptr, nullptr, 1024, 32, 32);
        // depthwise conv + silu -> xc fp32 + xcp bf16
        k_dwconv<<<dim3(LL / 256, EE, BB), 256, 0, stream>>>(xz, P[1], P[2], xc, xcp);
        // x_proj: M=64 (48 padded), Coct=64; 64x64 tiles, 128 blocks; + xdblp, BCt
        k_mfma_gemm<2, 2, 0, 1, 1><<<dim3(LL / 64, 1, BB), 256, 0, stream>>>(
            xWp[s], xcp, xdbl, nullptr, xdblp, BCt, 64, 64, 64);
        // dt_proj + softplus: dtb fp32.  M=512, Coct=4 (K=16 padded to 32)
        k_mfma_gemm<4, 4, 1, 0, 0><<<dim3(LL / 128, 512 / 128, BB), 256, 0, stream>>>(
            dtWp[s], xdblp, dtb, P[5], nullptr, nullptr, 512, 4, 8);
        // selective scan (chunked linear recurrence) -> ybp bf16
        k_scanA<<<dim3(NC * BB * EE / 256), 256, 0, stream>>>(dtb, xc, BCt, aexp, aprod, hendb);
        k_scanB<<<dim3(BB * EE * NN / 256), 256, 0, stream>>>(aprod, hendb);
        k_scanC<<<dim3(NC * BB * EE / 256), 256, 0, stream>>>(dtb, xc, BCt, aexp, P[7], xz, aprod, ybp);
        // out_proj: outbuf (B, D, L) fp32.  M=256, Coct=64; 64x128 tiles, 256 blocks
        k_mfma_gemm<2, 4, 0, 0, 0><<<dim3(LL / 128, 256 / 64, BB), 256, 0, stream>>>(
            outWp[s], ybp, outbuf, nullptr, nullptr, nullptr, 256, 64, 64);
    };

    mamba(out0, sp, 0, soutb);
    mamba(enc, cp, 1, coutb);

    k_final<<<dim3((size_t)BB * DD * LL / 4 / 256), 256, 0, stream>>>(
        x, out0, soutb, coutb, mask, (float*)d_out);
}

// Round 6
// 547.594 us; speedup vs baseline: 2.6454x; 1.2083x over previous
//
#include <hip/hip_runtime.h>
#include <hip/hip_bf16.h>
#include <math.h>

// Problem constants
#define BB 4
#define DD 256
#define LL 2048
#define EE 512
#define NN 16
#define KK 7
#define RR 16
#define NC 64              // scan chunks
#define CLEN (LL / NC)     // 32 steps per chunk
#define LPAD 2064          // padded L for conv input (8 zeros each side)

typedef __attribute__((ext_vector_type(8))) short short8;   // 8 bf16 (4 VGPRs)
typedef __attribute__((ext_vector_type(4))) float floatx4;  // MFMA accumulator

static __device__ __forceinline__ unsigned short bfbits(float f) {
    __hip_bfloat16 h = __float2bfloat16(f);
    return *(unsigned short*)&h;
}

static __device__ __forceinline__ float softplus_fast(float v) {
    // max(v,0) + log1p(exp(-|v|)) via fast intrinsics; abs err <= ~1.2e-7
    return fmaxf(v, 0.f) + __logf(1.f + __expf(-fabsf(v)));
}

// ---------------------------------------------------------------------------
// Fused packing: all weights + aexp in ONE dispatch. grid (224, 9).
// ---------------------------------------------------------------------------
static __device__ __forceinline__ void pack_w_seg(const float* __restrict__ W,
                                                  unsigned short* __restrict__ Wp,
                                                  int M, int C, int Mp, int Coct,
                                                  int cell) {
    if (cell >= Coct * Mp) return;
    int co = cell / Mp, m = cell - co * Mp;
    unsigned short v[8];
#pragma unroll
    for (int j = 0; j < 8; ++j) {
        int c = co * 8 + j;
        float f = (m < M && c < C) ? W[(size_t)m * C + c] : 0.f;
        v[j] = bfbits(f);
    }
    *(uint4*)&Wp[(size_t)cell * 8] = *(uint4*)v;
}

__global__ __launch_bounds__(256) void k_pack_fused(
        const float* __restrict__ ffw, unsigned short* __restrict__ ffWp,
        const float* __restrict__ sW0, unsigned short* __restrict__ inW0,
        const float* __restrict__ cW0, unsigned short* __restrict__ inW1,
        const float* __restrict__ sW8, unsigned short* __restrict__ outW0,
        const float* __restrict__ cW8, unsigned short* __restrict__ outW1,
        const float* __restrict__ sW3, unsigned short* __restrict__ xW0,
        const float* __restrict__ cW3, unsigned short* __restrict__ xW1,
        const float* __restrict__ sAl, float* __restrict__ aexp0,
        const float* __restrict__ cAl, float* __restrict__ aexp1) {
    int cell = blockIdx.x * 256 + threadIdx.x;
    switch (blockIdx.y) {
    case 0: {  // ff_w (Do,Di,K) -> [k][co][do][8]
        if (cell >= KK * 32 * DD) return;
        int doo = cell % DD;
        int rest = cell / DD;
        int co = rest % 32, k = rest / 32;
        unsigned short v[8];
#pragma unroll
        for (int j = 0; j < 8; ++j)
            v[j] = bfbits(ffw[((size_t)doo * DD + co * 8 + j) * KK + k]);
        *(uint4*)&ffWp[(size_t)cell * 8] = *(uint4*)v;
    } break;
    case 1: pack_w_seg(sW0, inW0, 1024, 256, 1024, 32, cell); break;
    case 2: pack_w_seg(cW0, inW1, 1024, 256, 1024, 32, cell); break;
    case 3: pack_w_seg(sW8, outW0, 256, 512, 256, 64, cell); break;
    case 4: pack_w_seg(cW8, outW1, 256, 512, 256, 64, cell); break;
    case 5: pack_w_seg(sW3, xW0, 48, 512, 64, 64, cell); break;
    case 6: pack_w_seg(cW3, xW1, 48, 512, 64, 64, cell); break;
    case 7: if (cell < EE * NN) aexp0[cell] = -expf(sAl[cell]); break;
    case 8: if (cell < EE * NN) aexp1[cell] = -expf(cAl[cell]); break;
    }
}

// x (B, D, L) fp32 -> xp[b][co][l+8][8] bf16 with 8-column zero pad both sides
__global__ __launch_bounds__(256) void k_pack_x(const float* __restrict__ x,
                                                unsigned short* __restrict__ xp) {
    int l = blockIdx.x * 256 + threadIdx.x;
    int co = blockIdx.y, b = blockIdx.z;
    if (l >= LPAD) return;
    int sl = l - 8;
    unsigned short v[8];
#pragma unroll
    for (int j = 0; j < 8; ++j) {
        float f = (sl >= 0 && sl < LL) ? x[((size_t)(b * DD) + co * 8 + j) * LL + sl] : 0.f;
        v[j] = bfbits(f);
    }
    *(uint4*)&xp[(((size_t)(b * 32) + co) * LPAD + l) * 8] = *(uint4*)v;
}

// ---------------------------------------------------------------------------
// instance norm over L per (b,d), fused * mask, writes packed bf16 [b][d/8][l][8].
// ---------------------------------------------------------------------------
__global__ __launch_bounds__(256) void k_instnorm(const float* __restrict__ x,
                                                  const float* __restrict__ mask,
                                                  unsigned short* __restrict__ outp) {
    const int bd = blockIdx.x;
    const int b = bd >> 8, d = bd & 255;
    const int tid = threadIdx.x;
    const float* row = x + (size_t)bd * LL;
    float v[8];
    float s = 0.f, s2 = 0.f;
#pragma unroll
    for (int i = 0; i < 8; ++i) {
        v[i] = row[i * 256 + tid];
        s += v[i];
        s2 = fmaf(v[i], v[i], s2);
    }
#pragma unroll
    for (int off = 32; off > 0; off >>= 1) {
        s  += __shfl_down(s, off);
        s2 += __shfl_down(s2, off);
    }
    __shared__ float red[2][4];
    if ((tid & 63) == 0) { red[0][tid >> 6] = s; red[1][tid >> 6] = s2; }
    __syncthreads();
    s  = red[0][0] + red[0][1] + red[0][2] + red[0][3];
    s2 = red[1][0] + red[1][1] + red[1][2] + red[1][3];
    const float mu  = s * (1.f / LL);
    const float var = s2 * (1.f / LL) - mu * mu;
    const float inv = rsqrtf(var + 1e-5f);
    const float* mrow = mask + (size_t)b * LL;
    unsigned short* op = outp + ((size_t)(b * 32) + (d >> 3)) * LL * 8 + (d & 7);
#pragma unroll
    for (int i = 0; i < 8; ++i) {
        int l = i * 256 + tid;
        op[(size_t)l * 8] = bfbits((v[i] - mu) * inv * mrow[l]);
    }
}

// ---------------------------------------------------------------------------
// MFMA GEMM, double-buffered LDS, one barrier per K-chunk (BK=32).
// out[b][m][l] = sum_c A[m][c] * B[b][c][l]
// A packed [co][Ms][8] bf16, B packed [b][co][L][8] bf16.
// Block 256 thr = 4 waves (2x2), tile (RM*32)m x (NLT*32)l.
// STOREOUT: write fp32 planar out.  BCT48: write rows m<48 to bct[b][l][48].
// ---------------------------------------------------------------------------
template <int RM, int NLT, int STOREOUT, int BCT48>
__global__ __launch_bounds__(256) void k_mfma_gemm(
        const unsigned short* __restrict__ Ap,
        const unsigned short* __restrict__ Bp,
        float* __restrict__ out,
        float* __restrict__ bct,
        int Ms, int Coct, int BoctPhys) {
    constexpr int TM = RM * 32;
    constexpr int TL = NLT * 32;
    constexpr int APITCH = TM * 8 + 8;
    constexpr int BPITCH = TL * 8 + 8;
    constexpr int ACELLS = (4 * TM) / 256;
    constexpr int BCELLS = (4 * TL) / 256;
    __shared__ unsigned short As[2][4 * APITCH];
    __shared__ unsigned short Bs[2][4 * BPITCH];
    const int tid = threadIdx.x;
    const int w = tid >> 6, lane = tid & 63;
    const int quad = lane >> 4, t = lane & 15;
    const int wm = (w >> 1) * (RM * 16), wl = (w & 1) * (NLT * 16);
    const int l0 = blockIdx.x * TL;
    const int m0 = blockIdx.y * TM;
    const int b  = blockIdx.z;
    const size_t Bbase = (size_t)b * BoctPhys * LL * 8;

    floatx4 acc[RM][NLT];
#pragma unroll
    for (int r = 0; r < RM; ++r)
#pragma unroll
        for (int j = 0; j < NLT; ++j) acc[r][j] = (floatx4){0.f, 0.f, 0.f, 0.f};

    uint4 areg[ACELLS], breg[BCELLS];
    auto loadRegs = [&](int c0) {
#pragma unroll
        for (int i = 0; i < ACELLS; ++i) {
            int cell = tid + i * 256;
            int q = cell / TM, mm = cell % TM;
            areg[i] = *(const uint4*)&Ap[((size_t)(c0 + q) * Ms + m0 + mm) * 8];
        }
#pragma unroll
        for (int i = 0; i < BCELLS; ++i) {
            int cell = tid + i * 256;
            int q = cell / TL, ll = cell % TL;
            breg[i] = *(const uint4*)&Bp[Bbase + ((size_t)(c0 + q) * LL + l0 + ll) * 8];
        }
    };
    auto storeRegs = [&](int p) {
#pragma unroll
        for (int i = 0; i < ACELLS; ++i) {
            int cell = tid + i * 256;
            int q = cell / TM, mm = cell % TM;
            *(uint4*)&As[p][q * APITCH + mm * 8] = areg[i];
        }
#pragma unroll
        for (int i = 0; i < BCELLS; ++i) {
            int cell = tid + i * 256;
            int q = cell / TL, ll = cell % TL;
            *(uint4*)&Bs[p][q * BPITCH + ll * 8] = breg[i];
        }
    };

    loadRegs(0);
    storeRegs(0);
    __syncthreads();
    int p = 0;
    for (int c0 = 4; c0 <= Coct; c0 += 4) {
        const bool has_next = (c0 < Coct);
        if (has_next) loadRegs(c0);
        short8 af[RM], bfv[NLT];
#pragma unroll
        for (int r = 0; r < RM; ++r)
            af[r] = *(short8*)&As[p][quad * APITCH + (wm + r * 16 + t) * 8];
#pragma unroll
        for (int j = 0; j < NLT; ++j)
            bfv[j] = *(short8*)&Bs[p][quad * BPITCH + (wl + j * 16 + t) * 8];
#pragma unroll
        for (int r = 0; r < RM; ++r)
#pragma unroll
            for (int j = 0; j < NLT; ++j)
                acc[r][j] = __builtin_amdgcn_mfma_f32_16x16x32_bf16(af[r], bfv[j], acc[r][j], 0, 0, 0);
        if (has_next) {
            storeRegs(p ^ 1);
            __syncthreads();
            p ^= 1;
        }
    }
    // epilogue: C/D layout col = lane&15 (l), row = quad*4 + reg (m)
#pragma unroll
    for (int r = 0; r < RM; ++r) {
        int mb = m0 + wm + r * 16 + quad * 4;
#pragma unroll
        for (int i = 0; i < 4; ++i) {
            int m = mb + i;
#pragma unroll
            for (int j = 0; j < NLT; ++j) {
                int l = l0 + wl + j * 16 + t;
                float v = acc[r][j][i];
                if (STOREOUT) out[((size_t)b * Ms + m) * LL + l] = v;
                if (BCT48) {
                    if (m < 48) bct[((size_t)b * LL + l) * 48 + m] = v;
                }
            }
        }
    }
}

// ---------------------------------------------------------------------------
// conv_ff: tap-reuse. Per di-chunk (32 di): stage x window ONCE + all 7 taps'
// weights; 56 MFMA/wave between barriers; 8 iterations. 128m x 64l tiles.
// ---------------------------------------------------------------------------
__global__ __launch_bounds__(256) void k_conv_mfma(
        const unsigned short* __restrict__ Wp,
        const unsigned short* __restrict__ Xp,
        const float* __restrict__ bias,
        float* __restrict__ out) {
    __shared__ unsigned short As[7 * 4 * 128 * 8];   // [k][q][m][8]  (57 KB)
    __shared__ unsigned short Bs[4 * 72 * 8];        // [q][c][8]     (4.6 KB)
    const int tid = threadIdx.x;
    const int w = tid >> 6, lane = tid & 63;
    const int quad = lane >> 4, t = lane & 15;
    const int wm = (w >> 1) * 64, wl = (w & 1) * 32;
    const int l0 = blockIdx.x * 64;
    const int m0 = blockIdx.y * 128;
    const int b  = blockIdx.z;

    floatx4 acc[4][2];
#pragma unroll
    for (int r = 0; r < 4; ++r)
#pragma unroll
        for (int j = 0; j < 2; ++j) acc[r][j] = (floatx4){0.f, 0.f, 0.f, 0.f};

    uint4 areg[14], breg[2];
    auto loadRegs = [&](int dc) {
#pragma unroll
        for (int i = 0; i < 14; ++i) {
            int cell = tid + i * 256;            // < 3584
            int mm = cell & 127;
            int rest = cell >> 7;                // 0..27
            int q = rest & 3, k = rest >> 2;     // k < 7
            areg[i] = *(const uint4*)&Wp[(((size_t)k * 32 + dc * 4 + q) * DD + m0 + mm) * 8];
        }
#pragma unroll
        for (int i = 0; i < 2; ++i) {
            int cell = tid + i * 256;
            if (cell < 288) {
                int q = cell / 72, c = cell - q * 72;
                breg[i] = *(const uint4*)&Xp[(((size_t)b * 32 + dc * 4 + q) * LPAD + l0 + 5 + c) * 8];
            }
        }
    };

    loadRegs(0);
    for (int dc = 0; dc < 8; ++dc) {
        if (dc) __syncthreads();
#pragma unroll
        for (int i = 0; i < 14; ++i)
            *(uint4*)&As[(size_t)(tid + i * 256) * 8] = areg[i];
#pragma unroll
        for (int i = 0; i < 2; ++i) {
            int cell = tid + i * 256;
            if (cell < 288) *(uint4*)&Bs[(size_t)cell * 8] = breg[i];
        }
        __syncthreads();
        if (dc < 7) loadRegs(dc + 1);
#pragma unroll
        for (int k = 0; k < KK; ++k) {
            short8 af[4], bfv[2];
#pragma unroll
            for (int r = 0; r < 4; ++r)
                af[r] = *(short8*)&As[(((k * 4 + quad) * 128) + wm + r * 16 + t) * 8];
#pragma unroll
            for (int j = 0; j < 2; ++j)
                bfv[j] = *(short8*)&Bs[(quad * 72 + wl + j * 16 + t + k) * 8];
#pragma unroll
            for (int r = 0; r < 4; ++r)
#pragma unroll
                for (int j = 0; j < 2; ++j)
                    acc[r][j] = __builtin_amdgcn_mfma_f32_16x16x32_bf16(af[r], bfv[j], acc[r][j], 0, 0, 0);
        }
    }
#pragma unroll
    for (int r = 0; r < 4; ++r) {
        int mb = m0 + wm + r * 16 + quad * 4;
#pragma unroll
        for (int i = 0; i < 4; ++i) {
            int m = mb + i;
            float bv = bias[m];
#pragma unroll
            for (int j = 0; j < 2; ++j) {
                int l = l0 + wl + j * 16 + t;
                float v = acc[r][j][i] + bv;
                out[((size_t)b * DD + m) * LL + l] = v > 0.f ? v : 0.f;
            }
        }
    }
}

// ---------------------------------------------------------------------------
// Depthwise causal conv (K=7) + silu.  Writes fp32 xc and packed bf16 xcp.
// ---------------------------------------------------------------------------
__global__ __launch_bounds__(256) void k_dwconv(const float* __restrict__ xz,
                                                const float* __restrict__ cw,
                                                const float* __restrict__ cb,
                                                float* __restrict__ xc,
                                                unsigned short* __restrict__ xcp) {
    const int l = blockIdx.x * 256 + threadIdx.x;
    const int e = blockIdx.y;
    const int b = blockIdx.z;
    const float* row = xz + ((size_t)b * (2 * EE) + e) * LL;
    float wv[KK];
#pragma unroll
    for (int k = 0; k < KK; ++k) wv[k] = cw[e * KK + k];
    float acc = cb[e];
#pragma unroll
    for (int k = 0; k < KK; ++k) {
        int ll = l + k - (KK - 1);
        if (ll >= 0) acc = fmaf(row[ll], wv[k], acc);
    }
    float sig = 1.f / (1.f + __expf(-acc));
    float v = acc * sig;
    xc[((size_t)b * EE + e) * LL + l] = v;
    xcp[(((size_t)(b * 64) + (e >> 3)) * LL + l) * 8 + (e & 7)] = bfbits(v);
}

// ---------------------------------------------------------------------------
// Selective scan: one thread owns all 16 n-states of one (b,e) chunk.
// t = ch*2048 + b*512 + e.  bct[b][l][48]: 0..15 dt-in, 16..31 B, 32..47 C
// (all loads wave-broadcast: lanes share (b,ch) hence l).
// dt computed inline: softplus(Wdt[e] . bct[l][0:16] + dt_bias[e]).
// ---------------------------------------------------------------------------
__global__ __launch_bounds__(256) void k_scanA(const float* __restrict__ u,
                                               const float* __restrict__ bct,
                                               const float* __restrict__ aexp,
                                               const float* __restrict__ Wdt,
                                               const float* __restrict__ dtbias,
                                               float* __restrict__ aprod,
                                               float* __restrict__ hend) {
    const int t = blockIdx.x * 256 + threadIdx.x;
    const int e = t & (EE - 1);
    const int b = (t >> 9) & (BB - 1);
    const int ch = t >> 11;
    float A[16], h[16], ap[16], wd[16];
#pragma unroll
    for (int q = 0; q < 4; ++q) {
        *(float4*)&A[q * 4]  = *(const float4*)&aexp[e * 16 + q * 4];
        *(float4*)&wd[q * 4] = *(const float4*)&Wdt[e * 16 + q * 4];
    }
    const float be = dtbias[e];
#pragma unroll
    for (int n = 0; n < 16; ++n) { h[n] = 0.f; ap[n] = 1.f; }
    const float* up = u + (size_t)(b * EE + e) * LL + ch * CLEN;
    const float* bc = bct + ((size_t)(b * LL) + ch * CLEN) * 48;
    for (int i = 0; i < CLEN; i += 4) {
        float4 u4 = *(const float4*)(up + i);
        float uv4[4] = {u4.x, u4.y, u4.z, u4.w};
#pragma unroll
        for (int j = 0; j < 4; ++j) {
            const float* bcl = bc + (size_t)(i + j) * 48;
            float Dv[16], Bv[16];
#pragma unroll
            for (int q = 0; q < 4; ++q) {
                *(float4*)&Dv[q * 4] = *(const float4*)(bcl + q * 4);
                *(float4*)&Bv[q * 4] = *(const float4*)(bcl + 16 + q * 4);
            }
            float d0 = be, d1 = 0.f, d2 = 0.f, d3 = 0.f;
#pragma unroll
            for (int r = 0; r < 4; ++r) {
                d0 = fmaf(wd[r], Dv[r], d0);
                d1 = fmaf(wd[r + 4], Dv[r + 4], d1);
                d2 = fmaf(wd[r + 8], Dv[r + 8], d2);
                d3 = fmaf(wd[r + 12], Dv[r + 12], d3);
            }
            float dv = softplus_fast((d0 + d1) + (d2 + d3));
            float du = dv * uv4[j];
#pragma unroll
            for (int n = 0; n < 16; ++n) {
                float dA = __expf(dv * A[n]);
                h[n] = fmaf(dA, h[n], du * Bv[n]);
                ap[n] *= dA;
            }
        }
    }
    float* app = aprod + (size_t)t * 16;
    float* hp  = hend + (size_t)t * 16;
#pragma unroll
    for (int q = 0; q < 4; ++q) {
        *(float4*)&app[q * 4] = *(float4*)&ap[q * 4];
        *(float4*)&hp[q * 4]  = *(float4*)&h[q * 4];
    }
}

// Pass B (in place): aprod[idx] <- carry into chunk ch for each (b,e,n).
__global__ __launch_bounds__(256) void k_scanB(float* __restrict__ aprod,
                                               const float* __restrict__ hend) {
    const int s = blockIdx.x * 256 + threadIdx.x;   // (b,e,n) = 32768
    float c = 0.f;
#pragma unroll
    for (int ch = 0; ch < NC; ++ch) {
        size_t idx = (size_t)ch * (BB * EE * NN) + s;
        float a = aprod[idx];
        float hh = hend[idx];
        aprod[idx] = c;
        c = fmaf(a, c, hh);
    }
}

// Pass C: re-scan with carry-in; y = (sum_n h*C + u*Dp) * silu(z) -> packed bf16.
__global__ __launch_bounds__(256) void k_scanC(const float* __restrict__ u,
                                               const float* __restrict__ bct,
                                               const float* __restrict__ aexp,
                                               const float* __restrict__ Wdt,
                                               const float* __restrict__ dtbias,
                                               const float* __restrict__ Dp,
                                               const float* __restrict__ xz,
                                               const float* __restrict__ carry,
                                               unsigned short* __restrict__ ybp) {
    const int t = blockIdx.x * 256 + threadIdx.x;
    const int e = t & (EE - 1);
    const int b = (t >> 9) & (BB - 1);
    const int ch = t >> 11;
    float A[16], h[16], wd[16];
#pragma unroll
    for (int q = 0; q < 4; ++q) {
        *(float4*)&A[q * 4]  = *(const float4*)&aexp[e * 16 + q * 4];
        *(float4*)&wd[q * 4] = *(const float4*)&Wdt[e * 16 + q * 4];
        *(float4*)&h[q * 4]  = *(const float4*)&carry[(size_t)t * 16 + q * 4];
    }
    const float be = dtbias[e];
    const float Dpe = Dp[e];
    const float* up = u + (size_t)(b * EE + e) * LL + ch * CLEN;
    const float* zp = xz + ((size_t)(b * 2 * EE) + EE + e) * LL + ch * CLEN;
    const float* bc = bct + ((size_t)(b * LL) + ch * CLEN) * 48;
    unsigned short* yp = ybp + (((size_t)(b * 64) + (e >> 3)) * LL + ch * CLEN) * 8 + (e & 7);
    for (int i = 0; i < CLEN; i += 4) {
        float4 u4 = *(const float4*)(up + i);
        float4 z4 = *(const float4*)(zp + i);
        float uv4[4] = {u4.x, u4.y, u4.z, u4.w};
        float zv4[4] = {z4.x, z4.y, z4.z, z4.w};
#pragma unroll
        for (int j = 0; j < 4; ++j) {
            const float* bcl = bc + (size_t)(i + j) * 48;
            float Dv[16], Bv[16], Cv[16];
#pragma unroll
            for (int q = 0; q < 4; ++q) {
                *(float4*)&Dv[q * 4] = *(const float4*)(bcl + q * 4);
                *(float4*)&Bv[q * 4] = *(const float4*)(bcl + 16 + q * 4);
                *(float4*)&Cv[q * 4] = *(const float4*)(bcl + 32 + q * 4);
            }
            float d0 = be, d1 = 0.f, d2 = 0.f, d3 = 0.f;
#pragma unroll
            for (int r = 0; r < 4; ++r) {
                d0 = fmaf(wd[r], Dv[r], d0);
                d1 = fmaf(wd[r + 4], Dv[r + 4], d1);
                d2 = fmaf(wd[r + 8], Dv[r + 8], d2);
                d3 = fmaf(wd[r + 12], Dv[r + 12], d3);
            }
            float dv = softplus_fast((d0 + d1) + (d2 + d3));
            float du = dv * uv4[j];
            float p0 = 0.f, p1 = 0.f, p2 = 0.f, p3 = 0.f;
#pragma unroll
            for (int n = 0; n < 4; ++n) {
                float dA = __expf(dv * A[n]);
                h[n] = fmaf(dA, h[n], du * Bv[n]);
                p0 = fmaf(h[n], Cv[n], p0);
            }
#pragma unroll
            for (int n = 4; n < 8; ++n) {
                float dA = __expf(dv * A[n]);
                h[n] = fmaf(dA, h[n], du * Bv[n]);
                p1 = fmaf(h[n], Cv[n], p1);
            }
#pragma unroll
            for (int n = 8; n < 12; ++n) {
                float dA = __expf(dv * A[n]);
                h[n] = fmaf(dA, h[n], du * Bv[n]);
                p2 = fmaf(h[n], Cv[n], p2);
            }
#pragma unroll
            for (int n = 12; n < 16; ++n) {
                float dA = __expf(dv * A[n]);
                h[n] = fmaf(dA, h[n], du * Bv[n]);
                p3 = fmaf(h[n], Cv[n], p3);
            }
            float p = (p0 + p1) + (p2 + p3) + uv4[j] * Dpe;
            float zz = zv4[j];
            float sig = 1.f / (1.f + __expf(-zz));
            yp[(size_t)(i + j) * 8] = bfbits(p * (zz * sig));
        }
    }
}

// ---------------------------------------------------------------------------
// final: out = (x + out0 + (s + c) * mask) * mask
// ---------------------------------------------------------------------------
__global__ __launch_bounds__(256) void k_final(const float* __restrict__ x,
                                               const float* __restrict__ out0,
                                               const float* __restrict__ sout,
                                               const float* __restrict__ cout,
                                               const float* __restrict__ mask,
                                               float* __restrict__ out) {
    const size_t idx = ((size_t)blockIdx.x * 256 + threadIdx.x) * 4;
    const size_t row = idx >> 11;
    const int b = (int)(row >> 8);
    const int l = (int)(idx & (LL - 1));
    float4 xv = *(const float4*)(x + idx);
    float4 o0 = *(const float4*)(out0 + idx);
    float4 sv = *(const float4*)(sout + idx);
    float4 cv = *(const float4*)(cout + idx);
    float4 mv = *(const float4*)(mask + (size_t)b * LL + l);
    float4 r;
    r.x = (xv.x + o0.x + (sv.x + cv.x) * mv.x) * mv.x;
    r.y = (xv.y + o0.y + (sv.y + cv.y) * mv.y) * mv.y;
    r.z = (xv.z + o0.z + (sv.z + cv.z) * mv.z) * mv.z;
    r.w = (xv.w + o0.w + (sv.w + cv.w) * mv.w) * mv.w;
    *(float4*)(out + idx) = r;
}

// ---------------------------------------------------------------------------
extern "C" void kernel_launch(void* const* d_in, const int* in_sizes, int n_in,
                              void* d_out, int out_size, void* d_ws, size_t ws_size,
                              hipStream_t stream) {
    const float* x    = (const float*)d_in[0];
    const float* enc  = (const float*)d_in[1];
    const float* mask = (const float*)d_in[2];
    const float* ff_w = (const float*)d_in[3];
    const float* ff_b = (const float*)d_in[4];
    const float* sp[9];
    const float* cp[9];
    for (int i = 0; i < 9; ++i) {
        sp[i] = (const float*)d_in[5 + i];
        cp[i] = (const float*)d_in[14 + i];
    }

    // workspace carve-up
    float* ws = (float*)d_ws;
    auto fcarve = [&](size_t n) { float* p = ws; ws += (n + 3) & ~3ul; return p; };
    float* out0  = fcarve((size_t)BB * DD * LL);
    float* xz    = fcarve((size_t)BB * 2 * EE * LL);
    float* xc    = fcarve((size_t)BB * EE * LL);
    float* soutb = fcarve((size_t)BB * DD * LL);
    float* coutb = fcarve((size_t)BB * DD * LL);
    float* aprod = fcarve((size_t)NC * BB * EE * NN);   // doubles as carry (pass B in place)
    float* hendb = fcarve((size_t)NC * BB * EE * NN);
    float* BCt   = fcarve((size_t)BB * LL * 48);
    float* aexp2 = fcarve((size_t)2 * EE * NN);
    auto scarve = [&](size_t n) { unsigned short* p = (unsigned short*)ws; ws += (n + 7) / 2 / 4 * 4 + 4; return p; };
    unsigned short* nrmp  = scarve((size_t)BB * 32 * LL * 8);
    unsigned short* xcp   = scarve((size_t)BB * 64 * LL * 8);
    unsigned short* ybp   = scarve((size_t)BB * 64 * LL * 8);
    unsigned short* xp    = scarve((size_t)BB * 32 * LPAD * 8);
    unsigned short* ffWp  = scarve((size_t)KK * 32 * DD * 8);
    unsigned short* inWp[2]  = { scarve(32 * 1024 * 8), scarve(32 * 1024 * 8) };
    unsigned short* outWp[2] = { scarve(64 * 256 * 8),  scarve(64 * 256 * 8) };
    unsigned short* xWp[2]   = { scarve(64 * 64 * 8),   scarve(64 * 64 * 8) };

    // ---- fused packing (weights + aexp) + input packing ----
    k_pack_fused<<<dim3(224, 9), 256, 0, stream>>>(
        ff_w, ffWp, sp[0], inWp[0], cp[0], inWp[1], sp[8], outWp[0], cp[8], outWp[1],
        sp[3], xWp[0], cp[3], xWp[1],
        sp[6], aexp2, cp[6], aexp2 + EE * NN);
    k_pack_x<<<dim3((LPAD + 255) / 256, 32, BB), 256, 0, stream>>>(x, xp);

    // ---- conv_ff (MFMA, tap-reuse) ----
    k_conv_mfma<<<dim3(LL / 64, DD / 128, BB), 256, 0, stream>>>(ffWp, xp, ff_b, out0);

    auto mamba = [&](const float* src, const float* const* P, int s, float* outbuf) {
        const float* aexp = aexp2 + s * EE * NN;
        k_instnorm<<<dim3(BB * DD), 256, 0, stream>>>(src, mask, nrmp);
        // in_proj: xz (B, 2E, L) fp32.  M=1024, Coct=32; 64m x 128l tiles, 1024 blocks
        k_mfma_gemm<2, 4, 1, 0><<<dim3(LL / 128, 1024 / 64, BB), 256, 0, stream>>>(
            inWp[s], nrmp, xz, nullptr, 1024, 32, 32);
        // depthwise conv + silu -> xc fp32 + xcp bf16
        k_dwconv<<<dim3(LL / 256, EE, BB), 256, 0, stream>>>(xz, P[1], P[2], xc, xcp);
        // x_proj: M=64 (48 live), Coct=64; writes ONLY bct[b][l][48]
        k_mfma_gemm<2, 2, 0, 1><<<dim3(LL / 64, 1, BB), 256, 0, stream>>>(
            xWp[s], xcp, nullptr, BCt, 64, 64, 64);
        // selective scan (chunked linear recurrence), dt inline -> ybp bf16
        k_scanA<<<dim3(NC * BB * EE / 256), 256, 0, stream>>>(
            xc, BCt, aexp, P[4], P[5], aprod, hendb);
        k_scanB<<<dim3(BB * EE * NN / 256), 256, 0, stream>>>(aprod, hendb);
        k_scanC<<<dim3(NC * BB * EE / 256), 256, 0, stream>>>(
            xc, BCt, aexp, P[4], P[5], P[7], xz, aprod, ybp);
        // out_proj: outbuf (B, D, L) fp32.  M=256, Coct=64; 64m x 64l tiles, 512 blocks
        k_mfma_gemm<2, 2, 1, 0><<<dim3(LL / 64, DD / 64, BB), 256, 0, stream>>>(
            outWp[s], ybp, outbuf, nullptr, 256, 64, 64);
    };

    mamba(out0, sp, 0, soutb);
    mamba(enc, cp, 1, coutb);

    k_final<<<dim3((size_t)BB * DD * LL / 4 / 256), 256, 0, stream>>>(
        x, out0, soutb, coutb, mask, (float*)d_out);
}

// Round 7
// 502.050 us; speedup vs baseline: 2.8853x; 1.0907x over previous
//
#include <hip/hip_runtime.h>
#include <hip/hip_bf16.h>
#include <math.h>

// Problem constants
#define BB 4
#define DD 256
#define LL 2048
#define EE 512
#define NN 16
#define KK 7
#define RR 16
#define NC 64              // scan chunks
#define CLEN (LL / NC)     // 32 steps per chunk
#define LPAD 2064          // padded L for conv input (8 zeros each side)

typedef __attribute__((ext_vector_type(8))) short short8;   // 8 bf16 (4 VGPRs)
typedef __attribute__((ext_vector_type(4))) float floatx4;  // MFMA accumulator

static __device__ __forceinline__ unsigned short bfbits(float f) {
    __hip_bfloat16 h = __float2bfloat16(f);
    return *(unsigned short*)&h;
}

static __device__ __forceinline__ float softplus_fast(float v) {
    return fmaxf(v, 0.f) + __logf(1.f + __expf(-fabsf(v)));
}

// ---------------------------------------------------------------------------
// Fused packing: all weights + aexp in ONE dispatch. grid (224, 9).
// ---------------------------------------------------------------------------
static __device__ __forceinline__ void pack_w_seg(const float* __restrict__ W,
                                                  unsigned short* __restrict__ Wp,
                                                  int M, int C, int Mp, int Coct,
                                                  int cell) {
    if (cell >= Coct * Mp) return;
    int co = cell / Mp, m = cell - co * Mp;
    unsigned short v[8];
#pragma unroll
    for (int j = 0; j < 8; ++j) {
        int c = co * 8 + j;
        float f = (m < M && c < C) ? W[(size_t)m * C + c] : 0.f;
        v[j] = bfbits(f);
    }
    *(uint4*)&Wp[(size_t)cell * 8] = *(uint4*)v;
}

__global__ __launch_bounds__(256) void k_pack_fused(
        const float* __restrict__ ffw, unsigned short* __restrict__ ffWp,
        const float* __restrict__ sW0, unsigned short* __restrict__ inW0,
        const float* __restrict__ cW0, unsigned short* __restrict__ inW1,
        const float* __restrict__ sW8, unsigned short* __restrict__ outW0,
        const float* __restrict__ cW8, unsigned short* __restrict__ outW1,
        const float* __restrict__ sW3, unsigned short* __restrict__ xW0,
        const float* __restrict__ cW3, unsigned short* __restrict__ xW1,
        const float* __restrict__ sAl, float* __restrict__ aexp0,
        const float* __restrict__ cAl, float* __restrict__ aexp1) {
    int cell = blockIdx.x * 256 + threadIdx.x;
    switch (blockIdx.y) {
    case 0: {  // ff_w (Do,Di,K) -> [k][co][do][8]
        if (cell >= KK * 32 * DD) return;
        int doo = cell % DD;
        int rest = cell / DD;
        int co = rest % 32, k = rest / 32;
        unsigned short v[8];
#pragma unroll
        for (int j = 0; j < 8; ++j)
            v[j] = bfbits(ffw[((size_t)doo * DD + co * 8 + j) * KK + k]);
        *(uint4*)&ffWp[(size_t)cell * 8] = *(uint4*)v;
    } break;
    case 1: pack_w_seg(sW0, inW0, 1024, 256, 1024, 32, cell); break;
    case 2: pack_w_seg(cW0, inW1, 1024, 256, 1024, 32, cell); break;
    case 3: pack_w_seg(sW8, outW0, 256, 512, 256, 64, cell); break;
    case 4: pack_w_seg(cW8, outW1, 256, 512, 256, 64, cell); break;
    case 5: pack_w_seg(sW3, xW0, 48, 512, 64, 64, cell); break;
    case 6: pack_w_seg(cW3, xW1, 48, 512, 64, 64, cell); break;
    case 7: if (cell < EE * NN) aexp0[cell] = -expf(sAl[cell]); break;
    case 8: if (cell < EE * NN) aexp1[cell] = -expf(cAl[cell]); break;
    }
}

// x (B, D, L) fp32 -> xp[b][co][l+8][8] bf16 with 8-column zero pad both sides
__global__ __launch_bounds__(256) void k_pack_x(const float* __restrict__ x,
                                                unsigned short* __restrict__ xp) {
    int l = blockIdx.x * 256 + threadIdx.x;
    int co = blockIdx.y, b = blockIdx.z;
    if (l >= LPAD) return;
    int sl = l - 8;
    unsigned short v[8];
#pragma unroll
    for (int j = 0; j < 8; ++j) {
        float f = (sl >= 0 && sl < LL) ? x[((size_t)(b * DD) + co * 8 + j) * LL + sl] : 0.f;
        v[j] = bfbits(f);
    }
    *(uint4*)&xp[(((size_t)(b * 32) + co) * LPAD + l) * 8] = *(uint4*)v;
}

// ---------------------------------------------------------------------------
// instance norm over L per (b,d), fused * mask, writes packed bf16 [b][d/8][l][8].
// ---------------------------------------------------------------------------
__global__ __launch_bounds__(256) void k_instnorm(const float* __restrict__ x,
                                                  const float* __restrict__ mask,
                                                  unsigned short* __restrict__ outp) {
    const int bd = blockIdx.x;
    const int b = bd >> 8, d = bd & 255;
    const int tid = threadIdx.x;
    const float* row = x + (size_t)bd * LL;
    float v[8];
    float s = 0.f, s2 = 0.f;
#pragma unroll
    for (int i = 0; i < 8; ++i) {
        v[i] = row[i * 256 + tid];
        s += v[i];
        s2 = fmaf(v[i], v[i], s2);
    }
#pragma unroll
    for (int off = 32; off > 0; off >>= 1) {
        s  += __shfl_down(s, off);
        s2 += __shfl_down(s2, off);
    }
    __shared__ float red[2][4];
    if ((tid & 63) == 0) { red[0][tid >> 6] = s; red[1][tid >> 6] = s2; }
    __syncthreads();
    s  = red[0][0] + red[0][1] + red[0][2] + red[0][3];
    s2 = red[1][0] + red[1][1] + red[1][2] + red[1][3];
    const float mu  = s * (1.f / LL);
    const float var = s2 * (1.f / LL) - mu * mu;
    const float inv = rsqrtf(var + 1e-5f);
    const float* mrow = mask + (size_t)b * LL;
    unsigned short* op = outp + ((size_t)(b * 32) + (d >> 3)) * LL * 8 + (d & 7);
#pragma unroll
    for (int i = 0; i < 8; ++i) {
        int l = i * 256 + tid;
        op[(size_t)l * 8] = bfbits((v[i] - mu) * inv * mrow[l]);
    }
}

// ---------------------------------------------------------------------------
// MFMA GEMM, double-buffered LDS, one barrier per K-chunk (BK=32).
// out[b][m][l] = sum_c A[m][c] * B[b][c][l]
// A packed [co][Ms][8] bf16.
// B layout: BLT=0 -> [b][co][L][8] (EphOrBoct = octet count);
//           BLT=1 -> [b][l][E]     (EphOrBoct = E, shorts per l-row).
// Block 256 thr = 4 waves (2x2), tile (RM*32)m x (NLT*32)l.
// STOREOUT: write fp32 planar out.  BCT48: write rows m<48 to bct[b][l][48].
// ---------------------------------------------------------------------------
template <int RM, int NLT, int STOREOUT, int BCT48, int BLT>
__global__ __launch_bounds__(256) void k_mfma_gemm(
        const unsigned short* __restrict__ Ap,
        const unsigned short* __restrict__ Bp,
        float* __restrict__ out,
        float* __restrict__ bct,
        int Ms, int Coct, int EphOrBoct) {
    constexpr int TM = RM * 32;
    constexpr int TL = NLT * 32;
    constexpr int APITCH = TM * 8 + 8;
    constexpr int BPITCH = TL * 8 + 8;
    constexpr int ACELLS = (4 * TM) / 256;
    constexpr int BCELLS = (4 * TL) / 256;
    __shared__ unsigned short As[2][4 * APITCH];
    __shared__ unsigned short Bs[2][4 * BPITCH];
    const int tid = threadIdx.x;
    const int w = tid >> 6, lane = tid & 63;
    const int quad = lane >> 4, t = lane & 15;
    const int wm = (w >> 1) * (RM * 16), wl = (w & 1) * (NLT * 16);
    const int l0 = blockIdx.x * TL;
    const int m0 = blockIdx.y * TM;
    const int b  = blockIdx.z;

    floatx4 acc[RM][NLT];
#pragma unroll
    for (int r = 0; r < RM; ++r)
#pragma unroll
        for (int j = 0; j < NLT; ++j) acc[r][j] = (floatx4){0.f, 0.f, 0.f, 0.f};

    uint4 areg[ACELLS], breg[BCELLS];
    auto loadRegs = [&](int c0) {
#pragma unroll
        for (int i = 0; i < ACELLS; ++i) {
            int cell = tid + i * 256;
            int q = cell / TM, mm = cell % TM;
            areg[i] = *(const uint4*)&Ap[((size_t)(c0 + q) * Ms + m0 + mm) * 8];
        }
#pragma unroll
        for (int i = 0; i < BCELLS; ++i) {
            int cell = tid + i * 256;
            if (BLT == 0) {
                int q = cell / TL, ll = cell % TL;
                breg[i] = *(const uint4*)&Bp[((size_t)b * EphOrBoct * LL +
                                              (size_t)(c0 + q) * LL + l0 + ll) * 8];
            } else {
                int ll = cell >> 2, q = cell & 3;
                breg[i] = *(const uint4*)&Bp[((size_t)b * LL + l0 + ll) * EphOrBoct +
                                             (size_t)(c0 + q) * 8];
            }
        }
    };
    auto storeRegs = [&](int p) {
#pragma unroll
        for (int i = 0; i < ACELLS; ++i) {
            int cell = tid + i * 256;
            int q = cell / TM, mm = cell % TM;
            *(uint4*)&As[p][q * APITCH + mm * 8] = areg[i];
        }
#pragma unroll
        for (int i = 0; i < BCELLS; ++i) {
            int cell = tid + i * 256;
            int q, ll;
            if (BLT == 0) { q = cell / TL; ll = cell % TL; }
            else          { ll = cell >> 2; q = cell & 3; }
            *(uint4*)&Bs[p][q * BPITCH + ll * 8] = breg[i];
        }
    };

    loadRegs(0);
    storeRegs(0);
    __syncthreads();
    int p = 0;
    for (int c0 = 4; c0 <= Coct; c0 += 4) {
        const bool has_next = (c0 < Coct);
        if (has_next) loadRegs(c0);
        short8 af[RM], bfv[NLT];
#pragma unroll
        for (int r = 0; r < RM; ++r)
            af[r] = *(short8*)&As[p][quad * APITCH + (wm + r * 16 + t) * 8];
#pragma unroll
        for (int j = 0; j < NLT; ++j)
            bfv[j] = *(short8*)&Bs[p][quad * BPITCH + (wl + j * 16 + t) * 8];
#pragma unroll
        for (int r = 0; r < RM; ++r)
#pragma unroll
            for (int j = 0; j < NLT; ++j)
                acc[r][j] = __builtin_amdgcn_mfma_f32_16x16x32_bf16(af[r], bfv[j], acc[r][j], 0, 0, 0);
        if (has_next) {
            storeRegs(p ^ 1);
            __syncthreads();
            p ^= 1;
        }
    }
    // epilogue: C/D layout col = lane&15 (l), row = quad*4 + reg (m)
#pragma unroll
    for (int r = 0; r < RM; ++r) {
        int mb = m0 + wm + r * 16 + quad * 4;
#pragma unroll
        for (int i = 0; i < 4; ++i) {
            int m = mb + i;
#pragma unroll
            for (int j = 0; j < NLT; ++j) {
                int l = l0 + wl + j * 16 + t;
                float v = acc[r][j][i];
                if (STOREOUT) out[((size_t)b * Ms + m) * LL + l] = v;
                if (BCT48) {
                    if (m < 48) bct[((size_t)b * LL + l) * 48 + m] = v;
                }
            }
        }
    }
}

// ---------------------------------------------------------------------------
// conv_ff: tap-reuse. 128m x 64l tiles, 56 MFMA/wave between barriers.
// ---------------------------------------------------------------------------
__global__ __launch_bounds__(256) void k_conv_mfma(
        const unsigned short* __restrict__ Wp,
        const unsigned short* __restrict__ Xp,
        const float* __restrict__ bias,
        float* __restrict__ out) {
    __shared__ unsigned short As[7 * 4 * 128 * 8];   // [k][q][m][8]  (57 KB)
    __shared__ unsigned short Bs[4 * 72 * 8];        // [q][c][8]     (4.6 KB)
    const int tid = threadIdx.x;
    const int w = tid >> 6, lane = tid & 63;
    const int quad = lane >> 4, t = lane & 15;
    const int wm = (w >> 1) * 64, wl = (w & 1) * 32;
    const int l0 = blockIdx.x * 64;
    const int m0 = blockIdx.y * 128;
    const int b  = blockIdx.z;

    floatx4 acc[4][2];
#pragma unroll
    for (int r = 0; r < 4; ++r)
#pragma unroll
        for (int j = 0; j < 2; ++j) acc[r][j] = (floatx4){0.f, 0.f, 0.f, 0.f};

    uint4 areg[14], breg[2];
    auto loadRegs = [&](int dc) {
#pragma unroll
        for (int i = 0; i < 14; ++i) {
            int cell = tid + i * 256;
            int mm = cell & 127;
            int rest = cell >> 7;
            int q = rest & 3, k = rest >> 2;
            areg[i] = *(const uint4*)&Wp[(((size_t)k * 32 + dc * 4 + q) * DD + m0 + mm) * 8];
        }
#pragma unroll
        for (int i = 0; i < 2; ++i) {
            int cell = tid + i * 256;
            if (cell < 288) {
                int q = cell / 72, c = cell - q * 72;
                breg[i] = *(const uint4*)&Xp[(((size_t)b * 32 + dc * 4 + q) * LPAD + l0 + 5 + c) * 8];
            }
        }
    };

    loadRegs(0);
    for (int dc = 0; dc < 8; ++dc) {
        if (dc) __syncthreads();
#pragma unroll
        for (int i = 0; i < 14; ++i)
            *(uint4*)&As[(size_t)(tid + i * 256) * 8] = areg[i];
#pragma unroll
        for (int i = 0; i < 2; ++i) {
            int cell = tid + i * 256;
            if (cell < 288) *(uint4*)&Bs[(size_t)cell * 8] = breg[i];
        }
        __syncthreads();
        if (dc < 7) loadRegs(dc + 1);
#pragma unroll
        for (int k = 0; k < KK; ++k) {
            short8 af[4], bfv[2];
#pragma unroll
            for (int r = 0; r < 4; ++r)
                af[r] = *(short8*)&As[(((k * 4 + quad) * 128) + wm + r * 16 + t) * 8];
#pragma unroll
            for (int j = 0; j < 2; ++j)
                bfv[j] = *(short8*)&Bs[(quad * 72 + wl + j * 16 + t + k) * 8];
#pragma unroll
            for (int r = 0; r < 4; ++r)
#pragma unroll
                for (int j = 0; j < 2; ++j)
                    acc[r][j] = __builtin_amdgcn_mfma_f32_16x16x32_bf16(af[r], bfv[j], acc[r][j], 0, 0, 0);
        }
    }
#pragma unroll
    for (int r = 0; r < 4; ++r) {
        int mb = m0 + wm + r * 16 + quad * 4;
#pragma unroll
        for (int i = 0; i < 4; ++i) {
            int m = mb + i;
            float bv = bias[m];
#pragma unroll
            for (int j = 0; j < 2; ++j) {
                int l = l0 + wl + j * 16 + t;
                float v = acc[r][j][i] + bv;
                out[((size_t)b * DD + m) * LL + l] = v > 0.f ? v : 0.f;
            }
        }
    }
}

// ---------------------------------------------------------------------------
// dwconv v2: tiled transpose. 64e x 64l tiles.  Reads xz planar (coalesced
// along l), writes e-contiguous: ut[b][l][e] fp32, xbf[b][l][e] bf16,
// gt[b][l][e] = silu(z) fp32.  grid (L/64, E/64, B).
// ---------------------------------------------------------------------------
__global__ __launch_bounds__(256) void k_dwconv2(const float* __restrict__ xz,
                                                 const float* __restrict__ cw,
                                                 const float* __restrict__ cb,
                                                 float* __restrict__ ut,
                                                 unsigned short* __restrict__ xbf,
                                                 float* __restrict__ gt) {
    __shared__ float xs[64][71];   // pitch 71: stride 7 mod 32 -> conflict-free
    __shared__ float zs[64][65];
    const int tid = threadIdx.x;
    const int l0 = blockIdx.x * 64;
    const int e0 = blockIdx.y * 64;
    const int b  = blockIdx.z;
    for (int idx = tid; idx < 64 * 70; idx += 256) {
        int r = idx / 70, c = idx - r * 70;
        int gl = l0 - 6 + c;
        xs[r][c] = (gl >= 0) ? xz[((size_t)(b * 2 * EE) + e0 + r) * LL + gl] : 0.f;
    }
    for (int idx = tid; idx < 64 * 64; idx += 256) {
        int r = idx >> 6, c = idx & 63;
        zs[r][c] = xz[((size_t)(b * 2 * EE) + EE + e0 + r) * LL + l0 + c];
    }
    __syncthreads();
    const int e = tid & 63, g = tid >> 6;
    float wv[KK];
#pragma unroll
    for (int k = 0; k < KK; ++k) wv[k] = cw[(e0 + e) * KK + k];
    const float cbe = cb[e0 + e];
#pragma unroll 4
    for (int i = 0; i < 16; ++i) {
        int li = g * 16 + i;
        float acc = cbe;
#pragma unroll
        for (int k = 0; k < KK; ++k) acc = fmaf(xs[e][li + k], wv[k], acc);
        float v = acc / (1.f + __expf(-acc));
        size_t o = ((size_t)(b * LL) + l0 + li) * EE + e0 + e;
        ut[o] = v;
        xbf[o] = bfbits(v);
        float zz = zs[e][li];
        gt[o] = zz / (1.f + __expf(-zz));
    }
}

// ---------------------------------------------------------------------------
// Selective scan: one thread owns all 16 n-states of one (b,e) chunk.
// t = ch*2048 + b*512 + e (lanes = consecutive e).
// u from ut[b][l][e] (lane-stride-1 coalesced); bct[b][l][48] broadcast.
// dt inline: softplus(Wdt[e] . bct[l][0:16] + dt_bias[e]).
// ---------------------------------------------------------------------------
__global__ __launch_bounds__(256) void k_scanA(const float* __restrict__ ut,
                                               const float* __restrict__ bct,
                                               const float* __restrict__ aexp,
                                               const float* __restrict__ Wdt,
                                               const float* __restrict__ dtbias,
                                               float* __restrict__ aprod,
                                               float* __restrict__ hend) {
    const int t = blockIdx.x * 256 + threadIdx.x;
    const int e = t & (EE - 1);
    const int b = (t >> 9) & (BB - 1);
    const int ch = t >> 11;
    float A[16], h[16], ap[16], wd[16];
#pragma unroll
    for (int q = 0; q < 4; ++q) {
        *(float4*)&A[q * 4]  = *(const float4*)&aexp[e * 16 + q * 4];
        *(float4*)&wd[q * 4] = *(const float4*)&Wdt[e * 16 + q * 4];
    }
    const float be = dtbias[e];
#pragma unroll
    for (int n = 0; n < 16; ++n) { h[n] = 0.f; ap[n] = 1.f; }
    const float* up = ut + ((size_t)(b * LL) + ch * CLEN) * EE + e;
    const float* bc = bct + ((size_t)(b * LL) + ch * CLEN) * 48;
#pragma unroll 4
    for (int i = 0; i < CLEN; ++i) {
        float uv = up[(size_t)i * EE];
        const float* bcl = bc + (size_t)i * 48;
        float Dv[16], Bv[16];
#pragma unroll
        for (int q = 0; q < 4; ++q) {
            *(float4*)&Dv[q * 4] = *(const float4*)(bcl + q * 4);
            *(float4*)&Bv[q * 4] = *(const float4*)(bcl + 16 + q * 4);
        }
        float d0 = be, d1 = 0.f, d2 = 0.f, d3 = 0.f;
#pragma unroll
        for (int r = 0; r < 4; ++r) {
            d0 = fmaf(wd[r], Dv[r], d0);
            d1 = fmaf(wd[r + 4], Dv[r + 4], d1);
            d2 = fmaf(wd[r + 8], Dv[r + 8], d2);
            d3 = fmaf(wd[r + 12], Dv[r + 12], d3);
        }
        float dv = softplus_fast((d0 + d1) + (d2 + d3));
        float du = dv * uv;
#pragma unroll
        for (int n = 0; n < 16; ++n) {
            float dA = __expf(dv * A[n]);
            h[n] = fmaf(dA, h[n], du * Bv[n]);
            ap[n] *= dA;
        }
    }
    float* app = aprod + (size_t)t * 16;
    float* hp  = hend + (size_t)t * 16;
#pragma unroll
    for (int q = 0; q < 4; ++q) {
        *(float4*)&app[q * 4] = *(float4*)&ap[q * 4];
        *(float4*)&hp[q * 4]  = *(float4*)&h[q * 4];
    }
}

// Pass B (in place): aprod[idx] <- carry into chunk ch for each (b,e,n).
__global__ __launch_bounds__(256) void k_scanB(float* __restrict__ aprod,
                                               const float* __restrict__ hend) {
    const int s = blockIdx.x * 256 + threadIdx.x;   // (b,e,n) = 32768
    float c = 0.f;
#pragma unroll
    for (int ch = 0; ch < NC; ++ch) {
        size_t idx = (size_t)ch * (BB * EE * NN) + s;
        float a = aprod[idx];
        float hh = hend[idx];
        aprod[idx] = c;
        c = fmaf(a, c, hh);
    }
}

// Pass C: re-scan with carry-in; y = (sum_n h*C + u*Dp) * g -> yt[b][l][e] bf16.
__global__ __launch_bounds__(256) void k_scanC(const float* __restrict__ ut,
                                               const float* __restrict__ bct,
                                               const float* __restrict__ aexp,
                                               const float* __restrict__ Wdt,
                                               const float* __restrict__ dtbias,
                                               const float* __restrict__ Dp,
                                               const float* __restrict__ gt,
                                               const float* __restrict__ carry,
                                               unsigned short* __restrict__ yt) {
    const int t = blockIdx.x * 256 + threadIdx.x;
    const int e = t & (EE - 1);
    const int b = (t >> 9) & (BB - 1);
    const int ch = t >> 11;
    float A[16], h[16], wd[16];
#pragma unroll
    for (int q = 0; q < 4; ++q) {
        *(float4*)&A[q * 4]  = *(const float4*)&aexp[e * 16 + q * 4];
        *(float4*)&wd[q * 4] = *(const float4*)&Wdt[e * 16 + q * 4];
        *(float4*)&h[q * 4]  = *(const float4*)&carry[(size_t)t * 16 + q * 4];
    }
    const float be = dtbias[e];
    const float Dpe = Dp[e];
    const size_t base = ((size_t)(b * LL) + ch * CLEN) * EE + e;
    const float* up = ut + base;
    const float* gp = gt + base;
    unsigned short* yp = yt + base;
    const float* bc = bct + ((size_t)(b * LL) + ch * CLEN) * 48;
#pragma unroll 4
    for (int i = 0; i < CLEN; ++i) {
        float uv = up[(size_t)i * EE];
        float gv = gp[(size_t)i * EE];
        const float* bcl = bc + (size_t)i * 48;
        float Dv[16], Bv[16], Cv[16];
#pragma unroll
        for (int q = 0; q < 4; ++q) {
            *(float4*)&Dv[q * 4] = *(const float4*)(bcl + q * 4);
            *(float4*)&Bv[q * 4] = *(const float4*)(bcl + 16 + q * 4);
            *(float4*)&Cv[q * 4] = *(const float4*)(bcl + 32 + q * 4);
        }
        float d0 = be, d1 = 0.f, d2 = 0.f, d3 = 0.f;
#pragma unroll
        for (int r = 0; r < 4; ++r) {
            d0 = fmaf(wd[r], Dv[r], d0);
            d1 = fmaf(wd[r + 4], Dv[r + 4], d1);
            d2 = fmaf(wd[r + 8], Dv[r + 8], d2);
            d3 = fmaf(wd[r + 12], Dv[r + 12], d3);
        }
        float dv = softplus_fast((d0 + d1) + (d2 + d3));
        float du = dv * uv;
        float p0 = 0.f, p1 = 0.f, p2 = 0.f, p3 = 0.f;
#pragma unroll
        for (int n = 0; n < 4; ++n) {
            float dA = __expf(dv * A[n]);
            h[n] = fmaf(dA, h[n], du * Bv[n]);
            p0 = fmaf(h[n], Cv[n], p0);
        }
#pragma unroll
        for (int n = 4; n < 8; ++n) {
            float dA = __expf(dv * A[n]);
            h[n] = fmaf(dA, h[n], du * Bv[n]);
            p1 = fmaf(h[n], Cv[n], p1);
        }
#pragma unroll
        for (int n = 8; n < 12; ++n) {
            float dA = __expf(dv * A[n]);
            h[n] = fmaf(dA, h[n], du * Bv[n]);
            p2 = fmaf(h[n], Cv[n], p2);
        }
#pragma unroll
        for (int n = 12; n < 16; ++n) {
            float dA = __expf(dv * A[n]);
            h[n] = fmaf(dA, h[n], du * Bv[n]);
            p3 = fmaf(h[n], Cv[n], p3);
        }
        float p = (p0 + p1) + (p2 + p3) + uv * Dpe;
        yp[(size_t)i * EE] = bfbits(p * gv);
    }
}

// ---------------------------------------------------------------------------
// final: out = (x + out0 + (s + c) * mask) * mask
// ---------------------------------------------------------------------------
__global__ __launch_bounds__(256) void k_final(const float* __restrict__ x,
                                               const float* __restrict__ out0,
                                               const float* __restrict__ sout,
                                               const float* __restrict__ cout,
                                               const float* __restrict__ mask,
                                               float* __restrict__ out) {
    const size_t idx = ((size_t)blockIdx.x * 256 + threadIdx.x) * 4;
    const size_t row = idx >> 11;
    const int b = (int)(row >> 8);
    const int l = (int)(idx & (LL - 1));
    float4 xv = *(const float4*)(x + idx);
    float4 o0 = *(const float4*)(out0 + idx);
    float4 sv = *(const float4*)(sout + idx);
    float4 cv = *(const float4*)(cout + idx);
    float4 mv = *(const float4*)(mask + (size_t)b * LL + l);
    float4 r;
    r.x = (xv.x + o0.x + (sv.x + cv.x) * mv.x) * mv.x;
    r.y = (xv.y + o0.y + (sv.y + cv.y) * mv.y) * mv.y;
    r.z = (xv.z + o0.z + (sv.z + cv.z) * mv.z) * mv.z;
    r.w = (xv.w + o0.w + (sv.w + cv.w) * mv.w) * mv.w;
    *(float4*)(out + idx) = r;
}

// ---------------------------------------------------------------------------
extern "C" void kernel_launch(void* const* d_in, const int* in_sizes, int n_in,
                              void* d_out, int out_size, void* d_ws, size_t ws_size,
                              hipStream_t stream) {
    const float* x    = (const float*)d_in[0];
    const float* enc  = (const float*)d_in[1];
    const float* mask = (const float*)d_in[2];
    const float* ff_w = (const float*)d_in[3];
    const float* ff_b = (const float*)d_in[4];
    const float* sp[9];
    const float* cp[9];
    for (int i = 0; i < 9; ++i) {
        sp[i] = (const float*)d_in[5 + i];
        cp[i] = (const float*)d_in[14 + i];
    }

    // workspace carve-up
    float* ws = (float*)d_ws;
    auto fcarve = [&](size_t n) { float* p = ws; ws += (n + 3) & ~3ul; return p; };
    float* out0  = fcarve((size_t)BB * DD * LL);
    float* xz    = fcarve((size_t)BB * 2 * EE * LL);
    float* ut    = fcarve((size_t)BB * LL * EE);
    float* gt    = fcarve((size_t)BB * LL * EE);
    float* soutb = fcarve((size_t)BB * DD * LL);
    float* coutb = fcarve((size_t)BB * DD * LL);
    float* aprod = fcarve((size_t)NC * BB * EE * NN);   // doubles as carry
    float* hendb = fcarve((size_t)NC * BB * EE * NN);
    float* BCt   = fcarve((size_t)BB * LL * 48);
    float* aexp2 = fcarve((size_t)2 * EE * NN);
    auto scarve = [&](size_t n) { unsigned short* p = (unsigned short*)ws; ws += (n + 7) / 2 / 4 * 4 + 4; return p; };
    unsigned short* nrmp = scarve((size_t)BB * 32 * LL * 8);
    unsigned short* xbf  = scarve((size_t)BB * LL * EE);
    unsigned short* yt   = scarve((size_t)BB * LL * EE);
    unsigned short* xp   = scarve((size_t)BB * 32 * LPAD * 8);
    unsigned short* ffWp = scarve((size_t)KK * 32 * DD * 8);
    unsigned short* inWp[2]  = { scarve(32 * 1024 * 8), scarve(32 * 1024 * 8) };
    unsigned short* outWp[2] = { scarve(64 * 256 * 8),  scarve(64 * 256 * 8) };
    unsigned short* xWp[2]   = { scarve(64 * 64 * 8),   scarve(64 * 64 * 8) };

    // ---- fused packing (weights + aexp) + input packing ----
    k_pack_fused<<<dim3(224, 9), 256, 0, stream>>>(
        ff_w, ffWp, sp[0], inWp[0], cp[0], inWp[1], sp[8], outWp[0], cp[8], outWp[1],
        sp[3], xWp[0], cp[3], xWp[1],
        sp[6], aexp2, cp[6], aexp2 + EE * NN);
    k_pack_x<<<dim3((LPAD + 255) / 256, 32, BB), 256, 0, stream>>>(x, xp);

    // ---- conv_ff (MFMA, tap-reuse) ----
    k_conv_mfma<<<dim3(LL / 64, DD / 128, BB), 256, 0, stream>>>(ffWp, xp, ff_b, out0);

    auto mamba = [&](const float* src, const float* const* P, int s, float* outbuf) {
        const float* aexp = aexp2 + s * EE * NN;
        k_instnorm<<<dim3(BB * DD), 256, 0, stream>>>(src, mask, nrmp);
        // in_proj: xz (B, 2E, L) fp32.  M=1024, Coct=32; 64m x 128l tiles
        k_mfma_gemm<2, 4, 1, 0, 0><<<dim3(LL / 128, 1024 / 64, BB), 256, 0, stream>>>(
            inWp[s], nrmp, xz, nullptr, 1024, 32, 32);
        // dwconv + silu + transpose -> ut/xbf/gt  [b][l][e]
        k_dwconv2<<<dim3(LL / 64, EE / 64, BB), 256, 0, stream>>>(
            xz, P[1], P[2], ut, xbf, gt);
        // x_proj: M=64 (48 live), Coct=64; B = xbf [b][l][E]; writes bct[b][l][48]
        k_mfma_gemm<2, 2, 0, 1, 1><<<dim3(LL / 64, 1, BB), 256, 0, stream>>>(
            xWp[s], xbf, nullptr, BCt, 64, 64, EE);
        // selective scan (chunked linear recurrence), dt inline -> yt bf16
        k_scanA<<<dim3(NC * BB * EE / 256), 256, 0, stream>>>(
            ut, BCt, aexp, P[4], P[5], aprod, hendb);
        k_scanB<<<dim3(BB * EE * NN / 256), 256, 0, stream>>>(aprod, hendb);
        k_scanC<<<dim3(NC * BB * EE / 256), 256, 0, stream>>>(
            ut, BCt, aexp, P[4], P[5], P[7], gt, aprod, yt);
        // out_proj: outbuf (B, D, L) fp32.  M=256, Coct=64; B = yt [b][l][E]
        k_mfma_gemm<2, 2, 1, 0, 1><<<dim3(LL / 64, DD / 64, BB), 256, 0, stream>>>(
            outWp[s], yt, outbuf, nullptr, 256, 64, EE);
    };

    mamba(out0, sp, 0, soutb);
    mamba(enc, cp, 1, coutb);

    k_final<<<dim3((size_t)BB * DD * LL / 4 / 256), 256, 0, stream>>>(
        x, out0, soutb, coutb, mask, (float*)d_out);
}

// Round 8
// 480.845 us; speedup vs baseline: 3.0126x; 1.0441x over previous
//
#include <hip/hip_runtime.h>
#include <hip/hip_bf16.h>
#include <math.h>

// Problem constants
#define BB 4
#define DD 256
#define LL 2048
#define EE 512
#define NN 16
#define KK 7
#define RR 16
#define NC 64              // scan chunks
#define CLEN (LL / NC)     // 32 steps per chunk
#define LPAD 2064          // padded L for conv input (8 zeros each side)

typedef __attribute__((ext_vector_type(8))) short short8;   // 8 bf16 (4 VGPRs)
typedef __attribute__((ext_vector_type(4))) float floatx4;  // MFMA accumulator

static __device__ __forceinline__ unsigned short bfbits(float f) {
    __hip_bfloat16 h = __float2bfloat16(f);
    return *(unsigned short*)&h;
}

static __device__ __forceinline__ float softplus_fast(float v) {
    return fmaxf(v, 0.f) + __logf(1.f + __expf(-fabsf(v)));
}

// ---------------------------------------------------------------------------
// Fused packing: all weights + aexp in ONE dispatch. grid (224, 9).
// ---------------------------------------------------------------------------
static __device__ __forceinline__ void pack_w_seg(const float* __restrict__ W,
                                                  unsigned short* __restrict__ Wp,
                                                  int M, int C, int Mp, int Coct,
                                                  int cell) {
    if (cell >= Coct * Mp) return;
    int co = cell / Mp, m = cell - co * Mp;
    unsigned short v[8];
#pragma unroll
    for (int j = 0; j < 8; ++j) {
        int c = co * 8 + j;
        float f = (m < M && c < C) ? W[(size_t)m * C + c] : 0.f;
        v[j] = bfbits(f);
    }
    *(uint4*)&Wp[(size_t)cell * 8] = *(uint4*)v;
}

__global__ __launch_bounds__(256) void k_pack_fused(
        const float* __restrict__ ffw, unsigned short* __restrict__ ffWp,
        const float* __restrict__ sW0, unsigned short* __restrict__ inW0,
        const float* __restrict__ cW0, unsigned short* __restrict__ inW1,
        const float* __restrict__ sW8, unsigned short* __restrict__ outW0,
        const float* __restrict__ cW8, unsigned short* __restrict__ outW1,
        const float* __restrict__ sW3, unsigned short* __restrict__ xW0,
        const float* __restrict__ cW3, unsigned short* __restrict__ xW1,
        const float* __restrict__ sAl, float* __restrict__ aexp0,
        const float* __restrict__ cAl, float* __restrict__ aexp1) {
    int cell = blockIdx.x * 256 + threadIdx.x;
    switch (blockIdx.y) {
    case 0: {  // ff_w (Do,Di,K) -> [k][co][do][8]
        if (cell >= KK * 32 * DD) return;
        int doo = cell % DD;
        int rest = cell / DD;
        int co = rest % 32, k = rest / 32;
        unsigned short v[8];
#pragma unroll
        for (int j = 0; j < 8; ++j)
            v[j] = bfbits(ffw[((size_t)doo * DD + co * 8 + j) * KK + k]);
        *(uint4*)&ffWp[(size_t)cell * 8] = *(uint4*)v;
    } break;
    case 1: pack_w_seg(sW0, inW0, 1024, 256, 1024, 32, cell); break;
    case 2: pack_w_seg(cW0, inW1, 1024, 256, 1024, 32, cell); break;
    case 3: pack_w_seg(sW8, outW0, 256, 512, 256, 64, cell); break;
    case 4: pack_w_seg(cW8, outW1, 256, 512, 256, 64, cell); break;
    case 5: pack_w_seg(sW3, xW0, 48, 512, 64, 64, cell); break;
    case 6: pack_w_seg(cW3, xW1, 48, 512, 64, 64, cell); break;
    case 7: if (cell < EE * NN) aexp0[cell] = -expf(sAl[cell]); break;
    case 8: if (cell < EE * NN) aexp1[cell] = -expf(cAl[cell]); break;
    }
}

// x (B, D, L) fp32 -> xp[b][co][l+8][8] bf16 with 8-column zero pad both sides
__global__ __launch_bounds__(256) void k_pack_x(const float* __restrict__ x,
                                                unsigned short* __restrict__ xp) {
    int l = blockIdx.x * 256 + threadIdx.x;
    int co = blockIdx.y, b = blockIdx.z;
    if (l >= LPAD) return;
    int sl = l - 8;
    unsigned short v[8];
#pragma unroll
    for (int j = 0; j < 8; ++j) {
        float f = (sl >= 0 && sl < LL) ? x[((size_t)(b * DD) + co * 8 + j) * LL + sl] : 0.f;
        v[j] = bfbits(f);
    }
    *(uint4*)&xp[(((size_t)(b * 32) + co) * LPAD + l) * 8] = *(uint4*)v;
}

// ---------------------------------------------------------------------------
// instance norm over L per (b,d), fused * mask, writes packed bf16 [b][d/8][l][8].
// ---------------------------------------------------------------------------
__global__ __launch_bounds__(256) void k_instnorm(const float* __restrict__ x,
                                                  const float* __restrict__ mask,
                                                  unsigned short* __restrict__ outp) {
    const int bd = blockIdx.x;
    const int b = bd >> 8, d = bd & 255;
    const int tid = threadIdx.x;
    const float* row = x + (size_t)bd * LL;
    float v[8];
    float s = 0.f, s2 = 0.f;
#pragma unroll
    for (int i = 0; i < 8; ++i) {
        v[i] = row[i * 256 + tid];
        s += v[i];
        s2 = fmaf(v[i], v[i], s2);
    }
#pragma unroll
    for (int off = 32; off > 0; off >>= 1) {
        s  += __shfl_down(s, off);
        s2 += __shfl_down(s2, off);
    }
    __shared__ float red[2][4];
    if ((tid & 63) == 0) { red[0][tid >> 6] = s; red[1][tid >> 6] = s2; }
    __syncthreads();
    s  = red[0][0] + red[0][1] + red[0][2] + red[0][3];
    s2 = red[1][0] + red[1][1] + red[1][2] + red[1][3];
    const float mu  = s * (1.f / LL);
    const float var = s2 * (1.f / LL) - mu * mu;
    const float inv = rsqrtf(var + 1e-5f);
    const float* mrow = mask + (size_t)b * LL;
    unsigned short* op = outp + ((size_t)(b * 32) + (d >> 3)) * LL * 8 + (d & 7);
#pragma unroll
    for (int i = 0; i < 8; ++i) {
        int l = i * 256 + tid;
        op[(size_t)l * 8] = bfbits((v[i] - mu) * inv * mrow[l]);
    }
}

// ---------------------------------------------------------------------------
// MFMA GEMM, double-buffered LDS, one barrier per K-chunk (BK=32).
// out[b][m][l] = sum_c A[m][c] * B[b][c][l]
// A packed [co][Ms][8] bf16.
// B layout: BLT=0 -> [b][co][L][8] (EphOrBoct = octet count);
//           BLT=1 -> [b][l][E]     (EphOrBoct = E, shorts per l-row).
// Block 256 thr = 4 waves (2x2), tile (RM*32)m x (NLT*32)l.
// STOREOUT: write fp32 planar out.  BCT48: write rows m<48 to bct[b][l][48].
// ---------------------------------------------------------------------------
template <int RM, int NLT, int STOREOUT, int BCT48, int BLT>
__global__ __launch_bounds__(256) void k_mfma_gemm(
        const unsigned short* __restrict__ Ap,
        const unsigned short* __restrict__ Bp,
        float* __restrict__ out,
        float* __restrict__ bct,
        int Ms, int Coct, int EphOrBoct) {
    constexpr int TM = RM * 32;
    constexpr int TL = NLT * 32;
    constexpr int APITCH = TM * 8 + 8;
    constexpr int BPITCH = TL * 8 + 8;
    constexpr int ACELLS = (4 * TM) / 256;
    constexpr int BCELLS = (4 * TL) / 256;
    __shared__ unsigned short As[2][4 * APITCH];
    __shared__ unsigned short Bs[2][4 * BPITCH];
    const int tid = threadIdx.x;
    const int w = tid >> 6, lane = tid & 63;
    const int quad = lane >> 4, t = lane & 15;
    const int wm = (w >> 1) * (RM * 16), wl = (w & 1) * (NLT * 16);
    const int l0 = blockIdx.x * TL;
    const int m0 = blockIdx.y * TM;
    const int b  = blockIdx.z;

    floatx4 acc[RM][NLT];
#pragma unroll
    for (int r = 0; r < RM; ++r)
#pragma unroll
        for (int j = 0; j < NLT; ++j) acc[r][j] = (floatx4){0.f, 0.f, 0.f, 0.f};

    uint4 areg[ACELLS], breg[BCELLS];
    auto loadRegs = [&](int c0) {
#pragma unroll
        for (int i = 0; i < ACELLS; ++i) {
            int cell = tid + i * 256;
            int q = cell / TM, mm = cell % TM;
            areg[i] = *(const uint4*)&Ap[((size_t)(c0 + q) * Ms + m0 + mm) * 8];
        }
#pragma unroll
        for (int i = 0; i < BCELLS; ++i) {
            int cell = tid + i * 256;
            if (BLT == 0) {
                int q = cell / TL, ll = cell % TL;
                breg[i] = *(const uint4*)&Bp[((size_t)b * EphOrBoct * LL +
                                              (size_t)(c0 + q) * LL + l0 + ll) * 8];
            } else {
                int ll = cell >> 2, q = cell & 3;
                breg[i] = *(const uint4*)&Bp[((size_t)b * LL + l0 + ll) * EphOrBoct +
                                             (size_t)(c0 + q) * 8];
            }
        }
    };
    auto storeRegs = [&](int p) {
#pragma unroll
        for (int i = 0; i < ACELLS; ++i) {
            int cell = tid + i * 256;
            int q = cell / TM, mm = cell % TM;
            *(uint4*)&As[p][q * APITCH + mm * 8] = areg[i];
        }
#pragma unroll
        for (int i = 0; i < BCELLS; ++i) {
            int cell = tid + i * 256;
            int q, ll;
            if (BLT == 0) { q = cell / TL; ll = cell % TL; }
            else          { ll = cell >> 2; q = cell & 3; }
            *(uint4*)&Bs[p][q * BPITCH + ll * 8] = breg[i];
        }
    };

    loadRegs(0);
    storeRegs(0);
    __syncthreads();
    int p = 0;
    for (int c0 = 4; c0 <= Coct; c0 += 4) {
        const bool has_next = (c0 < Coct);
        if (has_next) loadRegs(c0);
        short8 af[RM], bfv[NLT];
#pragma unroll
        for (int r = 0; r < RM; ++r)
            af[r] = *(short8*)&As[p][quad * APITCH + (wm + r * 16 + t) * 8];
#pragma unroll
        for (int j = 0; j < NLT; ++j)
            bfv[j] = *(short8*)&Bs[p][quad * BPITCH + (wl + j * 16 + t) * 8];
#pragma unroll
        for (int r = 0; r < RM; ++r)
#pragma unroll
            for (int j = 0; j < NLT; ++j)
                acc[r][j] = __builtin_amdgcn_mfma_f32_16x16x32_bf16(af[r], bfv[j], acc[r][j], 0, 0, 0);
        if (has_next) {
            storeRegs(p ^ 1);
            __syncthreads();
            p ^= 1;
        }
    }
    // epilogue: C/D layout col = lane&15 (l), row = quad*4 + reg (m)
#pragma unroll
    for (int r = 0; r < RM; ++r) {
        int mb = m0 + wm + r * 16 + quad * 4;
#pragma unroll
        for (int i = 0; i < 4; ++i) {
            int m = mb + i;
#pragma unroll
            for (int j = 0; j < NLT; ++j) {
                int l = l0 + wl + j * 16 + t;
                float v = acc[r][j][i];
                if (STOREOUT) out[((size_t)b * Ms + m) * LL + l] = v;
                if (BCT48) {
                    if (m < 48) bct[((size_t)b * LL + l) * 48 + m] = v;
                }
            }
        }
    }
}

// ---------------------------------------------------------------------------
// conv_ff v4: LDS-free. MFMA fragments loaded DIRECTLY from global:
// A-frag = 16 lanes x 16B consecutive in m (Wp[k][oct][m][8]);
// B-frag = 16 lanes x 16B consecutive in l (Xp[b][oct][l][8]).
// Weights 0.9 MB (L2-resident), x window ~40 KB/block (L1/L2).
// No barriers, no staging registers -> no spills. 128m x 64l, grid (32,2,4).
// ---------------------------------------------------------------------------
__global__ __launch_bounds__(256) void k_conv_mfma(
        const unsigned short* __restrict__ Wp,
        const unsigned short* __restrict__ Xp,
        const float* __restrict__ bias,
        float* __restrict__ out) {
    const int tid = threadIdx.x;
    const int w = tid >> 6, lane = tid & 63;
    const int quad = lane >> 4, t = lane & 15;
    const int wm = (w >> 1) * 64, wl = (w & 1) * 32;
    const int l0 = blockIdx.x * 64;
    const int m0 = blockIdx.y * 128;
    const int b  = blockIdx.z;

    floatx4 acc[4][2];
#pragma unroll
    for (int r = 0; r < 4; ++r)
#pragma unroll
        for (int j = 0; j < 2; ++j) acc[r][j] = (floatx4){0.f, 0.f, 0.f, 0.f};

    // A: ((k*32 + dc*4 + quad)*DD + m0 + wm + r*16 + t) * 8
    const unsigned short* wbase = Wp + ((size_t)quad * DD + m0 + wm + t) * 8;
    // B: ((b*32 + dc*4 + quad)*LPAD + l0 + wl + j*16 + t + 5 + k) * 8
    const unsigned short* xbase = Xp + (((size_t)(b * 32) + quad) * LPAD + l0 + wl + t + 5) * 8;

    for (int dc = 0; dc < 8; ++dc) {
#pragma unroll
        for (int k = 0; k < KK; ++k) {
            short8 af[4], bfv[2];
#pragma unroll
            for (int r = 0; r < 4; ++r)
                af[r] = *(const short8*)&wbase[((size_t)(k * 32 + dc * 4) * DD + r * 16) * 8];
#pragma unroll
            for (int j = 0; j < 2; ++j)
                bfv[j] = *(const short8*)&xbase[((size_t)(dc * 4) * LPAD + j * 16 + k) * 8];
#pragma unroll
            for (int r = 0; r < 4; ++r)
#pragma unroll
                for (int j = 0; j < 2; ++j)
                    acc[r][j] = __builtin_amdgcn_mfma_f32_16x16x32_bf16(af[r], bfv[j], acc[r][j], 0, 0, 0);
        }
    }
#pragma unroll
    for (int r = 0; r < 4; ++r) {
        int mb = m0 + wm + r * 16 + quad * 4;
#pragma unroll
        for (int i = 0; i < 4; ++i) {
            int m = mb + i;
            float bv = bias[m];
#pragma unroll
            for (int j = 0; j < 2; ++j) {
                int l = l0 + wl + j * 16 + t;
                float v = acc[r][j][i] + bv;
                out[((size_t)b * DD + m) * LL + l] = v > 0.f ? v : 0.f;
            }
        }
    }
}

// ---------------------------------------------------------------------------
// dwconv v2: tiled transpose. 64e x 64l tiles.  Reads xz planar (coalesced
// along l), writes e-contiguous: ut[b][l][e] fp32, xbf[b][l][e] bf16,
// gt[b][l][e] = silu(z) fp32.  grid (L/64, E/64, B).
// ---------------------------------------------------------------------------
__global__ __launch_bounds__(256) void k_dwconv2(const float* __restrict__ xz,
                                                 const float* __restrict__ cw,
                                                 const float* __restrict__ cb,
                                                 float* __restrict__ ut,
                                                 unsigned short* __restrict__ xbf,
                                                 float* __restrict__ gt) {
    __shared__ float xs[64][71];   // pitch 71: conflict-free
    __shared__ float zs[64][65];
    const int tid = threadIdx.x;
    const int l0 = blockIdx.x * 64;
    const int e0 = blockIdx.y * 64;
    const int b  = blockIdx.z;
    for (int idx = tid; idx < 64 * 70; idx += 256) {
        int r = idx / 70, c = idx - r * 70;
        int gl = l0 - 6 + c;
        xs[r][c] = (gl >= 0) ? xz[((size_t)(b * 2 * EE) + e0 + r) * LL + gl] : 0.f;
    }
    for (int idx = tid; idx < 64 * 64; idx += 256) {
        int r = idx >> 6, c = idx & 63;
        zs[r][c] = xz[((size_t)(b * 2 * EE) + EE + e0 + r) * LL + l0 + c];
    }
    __syncthreads();
    const int e = tid & 63, g = tid >> 6;
    float wv[KK];
#pragma unroll
    for (int k = 0; k < KK; ++k) wv[k] = cw[(e0 + e) * KK + k];
    const float cbe = cb[e0 + e];
#pragma unroll 4
    for (int i = 0; i < 16; ++i) {
        int li = g * 16 + i;
        float acc = cbe;
#pragma unroll
        for (int k = 0; k < KK; ++k) acc = fmaf(xs[e][li + k], wv[k], acc);
        float v = acc / (1.f + __expf(-acc));
        size_t o = ((size_t)(b * LL) + l0 + li) * EE + e0 + e;
        ut[o] = v;
        xbf[o] = bfbits(v);
        float zz = zs[e][li];
        gt[o] = zz / (1.f + __expf(-zz));
    }
}

// ---------------------------------------------------------------------------
// Selective scan: one thread owns all 16 n-states of one (b,e) chunk.
// t = ch*2048 + b*512 + e (lanes = consecutive e).
// u from ut[b][l][e] (lane-stride-1 coalesced); bct[b][l][48] broadcast.
// dt inline: softplus(Wdt[e] . bct[l][0:16] + dt_bias[e]).
// ---------------------------------------------------------------------------
__global__ __launch_bounds__(256) void k_scanA(const float* __restrict__ ut,
                                               const float* __restrict__ bct,
                                               const float* __restrict__ aexp,
                                               const float* __restrict__ Wdt,
                                               const float* __restrict__ dtbias,
                                               float* __restrict__ aprod,
                                               float* __restrict__ hend) {
    const int t = blockIdx.x * 256 + threadIdx.x;
    const int e = t & (EE - 1);
    const int b = (t >> 9) & (BB - 1);
    const int ch = t >> 11;
    float A[16], h[16], ap[16], wd[16];
#pragma unroll
    for (int q = 0; q < 4; ++q) {
        *(float4*)&A[q * 4]  = *(const float4*)&aexp[e * 16 + q * 4];
        *(float4*)&wd[q * 4] = *(const float4*)&Wdt[e * 16 + q * 4];
    }
    const float be = dtbias[e];
#pragma unroll
    for (int n = 0; n < 16; ++n) { h[n] = 0.f; ap[n] = 1.f; }
    const float* up = ut + ((size_t)(b * LL) + ch * CLEN) * EE + e;
    const float* bc = bct + ((size_t)(b * LL) + ch * CLEN) * 48;
#pragma unroll 4
    for (int i = 0; i < CLEN; ++i) {
        float uv = up[(size_t)i * EE];
        const float* bcl = bc + (size_t)i * 48;
        float Dv[16], Bv[16];
#pragma unroll
        for (int q = 0; q < 4; ++q) {
            *(float4*)&Dv[q * 4] = *(const float4*)(bcl + q * 4);
            *(float4*)&Bv[q * 4] = *(const float4*)(bcl + 16 + q * 4);
        }
        float d0 = be, d1 = 0.f, d2 = 0.f, d3 = 0.f;
#pragma unroll
        for (int r = 0; r < 4; ++r) {
            d0 = fmaf(wd[r], Dv[r], d0);
            d1 = fmaf(wd[r + 4], Dv[r + 4], d1);
            d2 = fmaf(wd[r + 8], Dv[r + 8], d2);
            d3 = fmaf(wd[r + 12], Dv[r + 12], d3);
        }
        float dv = softplus_fast((d0 + d1) + (d2 + d3));
        float du = dv * uv;
#pragma unroll
        for (int n = 0; n < 16; ++n) {
            float dA = __expf(dv * A[n]);
            h[n] = fmaf(dA, h[n], du * Bv[n]);
            ap[n] *= dA;
        }
    }
    float* app = aprod + (size_t)t * 16;
    float* hp  = hend + (size_t)t * 16;
#pragma unroll
    for (int q = 0; q < 4; ++q) {
        *(float4*)&app[q * 4] = *(float4*)&ap[q * 4];
        *(float4*)&hp[q * 4]  = *(float4*)&h[q * 4];
    }
}

// Pass B (in place): aprod[idx] <- carry into chunk ch for each (b,e,n).
__global__ __launch_bounds__(256) void k_scanB(float* __restrict__ aprod,
                                               const float* __restrict__ hend) {
    const int s = blockIdx.x * 256 + threadIdx.x;   // (b,e,n) = 32768
    float c = 0.f;
#pragma unroll
    for (int ch = 0; ch < NC; ++ch) {
        size_t idx = (size_t)ch * (BB * EE * NN) + s;
        float a = aprod[idx];
        float hh = hend[idx];
        aprod[idx] = c;
        c = fmaf(a, c, hh);
    }
}

// Pass C: re-scan with carry-in; y = (sum_n h*C + u*Dp) * g -> yt[b][l][e] bf16.
__global__ __launch_bounds__(256) void k_scanC(const float* __restrict__ ut,
                                               const float* __restrict__ bct,
                                               const float* __restrict__ aexp,
                                               const float* __restrict__ Wdt,
                                               const float* __restrict__ dtbias,
                                               const float* __restrict__ Dp,
                                               const float* __restrict__ gt,
                                               const float* __restrict__ carry,
                                               unsigned short* __restrict__ yt) {
    const int t = blockIdx.x * 256 + threadIdx.x;
    const int e = t & (EE - 1);
    const int b = (t >> 9) & (BB - 1);
    const int ch = t >> 11;
    float A[16], h[16], wd[16];
#pragma unroll
    for (int q = 0; q < 4; ++q) {
        *(float4*)&A[q * 4]  = *(const float4*)&aexp[e * 16 + q * 4];
        *(float4*)&wd[q * 4] = *(const float4*)&Wdt[e * 16 + q * 4];
        *(float4*)&h[q * 4]  = *(const float4*)&carry[(size_t)t * 16 + q * 4];
    }
    const float be = dtbias[e];
    const float Dpe = Dp[e];
    const size_t base = ((size_t)(b * LL) + ch * CLEN) * EE + e;
    const float* up = ut + base;
    const float* gp = gt + base;
    unsigned short* yp = yt + base;
    const float* bc = bct + ((size_t)(b * LL) + ch * CLEN) * 48;
#pragma unroll 4
    for (int i = 0; i < CLEN; ++i) {
        float uv = up[(size_t)i * EE];
        float gv = gp[(size_t)i * EE];
        const float* bcl = bc + (size_t)i * 48;
        float Dv[16], Bv[16], Cv[16];
#pragma unroll
        for (int q = 0; q < 4; ++q) {
            *(float4*)&Dv[q * 4] = *(const float4*)(bcl + q * 4);
            *(float4*)&Bv[q * 4] = *(const float4*)(bcl + 16 + q * 4);
            *(float4*)&Cv[q * 4] = *(const float4*)(bcl + 32 + q * 4);
        }
        float d0 = be, d1 = 0.f, d2 = 0.f, d3 = 0.f;
#pragma unroll
        for (int r = 0; r < 4; ++r) {
            d0 = fmaf(wd[r], Dv[r], d0);
            d1 = fmaf(wd[r + 4], Dv[r + 4], d1);
            d2 = fmaf(wd[r + 8], Dv[r + 8], d2);
            d3 = fmaf(wd[r + 12], Dv[r + 12], d3);
        }
        float dv = softplus_fast((d0 + d1) + (d2 + d3));
        float du = dv * uv;
        float p0 = 0.f, p1 = 0.f, p2 = 0.f, p3 = 0.f;
#pragma unroll
        for (int n = 0; n < 4; ++n) {
            float dA = __expf(dv * A[n]);
            h[n] = fmaf(dA, h[n], du * Bv[n]);
            p0 = fmaf(h[n], Cv[n], p0);
        }
#pragma unroll
        for (int n = 4; n < 8; ++n) {
            float dA = __expf(dv * A[n]);
            h[n] = fmaf(dA, h[n], du * Bv[n]);
            p1 = fmaf(h[n], Cv[n], p1);
        }
#pragma unroll
        for (int n = 8; n < 12; ++n) {
            float dA = __expf(dv * A[n]);
            h[n] = fmaf(dA, h[n], du * Bv[n]);
            p2 = fmaf(h[n], Cv[n], p2);
        }
#pragma unroll
        for (int n = 12; n < 16; ++n) {
            float dA = __expf(dv * A[n]);
            h[n] = fmaf(dA, h[n], du * Bv[n]);
            p3 = fmaf(h[n], Cv[n], p3);
        }
        float p = (p0 + p1) + (p2 + p3) + uv * Dpe;
        yp[(size_t)i * EE] = bfbits(p * gv);
    }
}

// ---------------------------------------------------------------------------
// final: out = (x + out0 + (s + c) * mask) * mask
// ---------------------------------------------------------------------------
__global__ __launch_bounds__(256) void k_final(const float* __restrict__ x,
                                               const float* __restrict__ out0,
                                               const float* __restrict__ sout,
                                               const float* __restrict__ cout,
                                               const float* __restrict__ mask,
                                               float* __restrict__ out) {
    const size_t idx = ((size_t)blockIdx.x * 256 + threadIdx.x) * 4;
    const size_t row = idx >> 11;
    const int b = (int)(row >> 8);
    const int l = (int)(idx & (LL - 1));
    float4 xv = *(const float4*)(x + idx);
    float4 o0 = *(const float4*)(out0 + idx);
    float4 sv = *(const float4*)(sout + idx);
    float4 cv = *(const float4*)(cout + idx);
    float4 mv = *(const float4*)(mask + (size_t)b * LL + l);
    float4 r;
    r.x = (xv.x + o0.x + (sv.x + cv.x) * mv.x) * mv.x;
    r.y = (xv.y + o0.y + (sv.y + cv.y) * mv.y) * mv.y;
    r.z = (xv.z + o0.z + (sv.z + cv.z) * mv.z) * mv.z;
    r.w = (xv.w + o0.w + (sv.w + cv.w) * mv.w) * mv.w;
    *(float4*)(out + idx) = r;
}

// ---------------------------------------------------------------------------
extern "C" void kernel_launch(void* const* d_in, const int* in_sizes, int n_in,
                              void* d_out, int out_size, void* d_ws, size_t ws_size,
                              hipStream_t stream) {
    const float* x    = (const float*)d_in[0];
    const float* enc  = (const float*)d_in[1];
    const float* mask = (const float*)d_in[2];
    const float* ff_w = (const float*)d_in[3];
    const float* ff_b = (const float*)d_in[4];
    const float* sp[9];
    const float* cp[9];
    for (int i = 0; i < 9; ++i) {
        sp[i] = (const float*)d_in[5 + i];
        cp[i] = (const float*)d_in[14 + i];
    }

    // workspace carve-up
    float* ws = (float*)d_ws;
    auto fcarve = [&](size_t n) { float* p = ws; ws += (n + 3) & ~3ul; return p; };
    float* out0  = fcarve((size_t)BB * DD * LL);
    float* xz    = fcarve((size_t)BB * 2 * EE * LL);
    float* ut    = fcarve((size_t)BB * LL * EE);
    float* gt    = fcarve((size_t)BB * LL * EE);
    float* soutb = fcarve((size_t)BB * DD * LL);
    float* coutb = fcarve((size_t)BB * DD * LL);
    float* aprod = fcarve((size_t)NC * BB * EE * NN);   // doubles as carry
    float* hendb = fcarve((size_t)NC * BB * EE * NN);
    float* BCt   = fcarve((size_t)BB * LL * 48);
    float* aexp2 = fcarve((size_t)2 * EE * NN);
    auto scarve = [&](size_t n) { unsigned short* p = (unsigned short*)ws; ws += (n + 7) / 2 / 4 * 4 + 4; return p; };
    unsigned short* nrmp = scarve((size_t)BB * 32 * LL * 8);
    unsigned short* xbf  = scarve((size_t)BB * LL * EE);
    unsigned short* yt   = scarve((size_t)BB * LL * EE);
    unsigned short* xp   = scarve((size_t)BB * 32 * LPAD * 8);
    unsigned short* ffWp = scarve((size_t)KK * 32 * DD * 8);
    unsigned short* inWp[2]  = { scarve(32 * 1024 * 8), scarve(32 * 1024 * 8) };
    unsigned short* outWp[2] = { scarve(64 * 256 * 8),  scarve(64 * 256 * 8) };
    unsigned short* xWp[2]   = { scarve(64 * 64 * 8),   scarve(64 * 64 * 8) };

    // ---- fused packing (weights + aexp) + input packing ----
    k_pack_fused<<<dim3(224, 9), 256, 0, stream>>>(
        ff_w, ffWp, sp[0], inWp[0], cp[0], inWp[1], sp[8], outWp[0], cp[8], outWp[1],
        sp[3], xWp[0], cp[3], xWp[1],
        sp[6], aexp2, cp[6], aexp2 + EE * NN);
    k_pack_x<<<dim3((LPAD + 255) / 256, 32, BB), 256, 0, stream>>>(x, xp);

    // ---- conv_ff (MFMA, LDS-free direct fragments) ----
    k_conv_mfma<<<dim3(LL / 64, DD / 128, BB), 256, 0, stream>>>(ffWp, xp, ff_b, out0);

    auto mamba = [&](const float* src, const float* const* P, int s, float* outbuf) {
        const float* aexp = aexp2 + s * EE * NN;
        k_instnorm<<<dim3(BB * DD), 256, 0, stream>>>(src, mask, nrmp);
        // in_proj: xz (B, 2E, L) fp32.  M=1024, Coct=32; 64m x 128l tiles
        k_mfma_gemm<2, 4, 1, 0, 0><<<dim3(LL / 128, 1024 / 64, BB), 256, 0, stream>>>(
            inWp[s], nrmp, xz, nullptr, 1024, 32, 32);
        // dwconv + silu + transpose -> ut/xbf/gt  [b][l][e]
        k_dwconv2<<<dim3(LL / 64, EE / 64, BB), 256, 0, stream>>>(
            xz, P[1], P[2], ut, xbf, gt);
        // x_proj: M=64 (48 live), Coct=64; B = xbf [b][l][E]; writes bct[b][l][48]
        k_mfma_gemm<2, 2, 0, 1, 1><<<dim3(LL / 64, 1, BB), 256, 0, stream>>>(
            xWp[s], xbf, nullptr, BCt, 64, 64, EE);
        // selective scan (chunked linear recurrence), dt inline -> yt bf16
        k_scanA<<<dim3(NC * BB * EE / 256), 256, 0, stream>>>(
            ut, BCt, aexp, P[4], P[5], aprod, hendb);
        k_scanB<<<dim3(BB * EE * NN / 256), 256, 0, stream>>>(aprod, hendb);
        k_scanC<<<dim3(NC * BB * EE / 256), 256, 0, stream>>>(
            ut, BCt, aexp, P[4], P[5], P[7], gt, aprod, yt);
        // out_proj: outbuf (B, D, L) fp32.  M=256, Coct=64; B = yt [b][l][E]
        k_mfma_gemm<2, 2, 1, 0, 1><<<dim3(LL / 64, DD / 64, BB), 256, 0, stream>>>(
            outWp[s], yt, outbuf, nullptr, 256, 64, EE);
    };

    mamba(out0, sp, 0, soutb);
    mamba(enc, cp, 1, coutb);

    k_final<<<dim3((size_t)BB * DD * LL / 4 / 256), 256, 0, stream>>>(
        x, out0, soutb, coutb, mask, (float*)d_out);
}

// Round 9
// 477.701 us; speedup vs baseline: 3.0324x; 1.0066x over previous
//
#include <hip/hip_runtime.h>
#include <hip/hip_bf16.h>
#include <math.h>

// Problem constants
#define BB 4
#define DD 256
#define LL 2048
#define EE 512
#define NN 16
#define KK 7
#define RR 16
#define NC 128             // scan chunks
#define CLEN (LL / NC)     // 16 steps per chunk
#define LPAD 2064          // padded L for conv input (8 zeros each side)

typedef __attribute__((ext_vector_type(8))) short short8;   // 8 bf16 (4 VGPRs)
typedef __attribute__((ext_vector_type(4))) float floatx4;  // MFMA accumulator

static __device__ __forceinline__ unsigned short bfbits(float f) {
    __hip_bfloat16 h = __float2bfloat16(f);
    return *(unsigned short*)&h;
}

static __device__ __forceinline__ float bf2f(unsigned short u) {
    unsigned v = ((unsigned)u) << 16;
    float f;
    __builtin_memcpy(&f, &v, 4);
    return f;
}

static __device__ __forceinline__ float softplus_fast(float v) {
    return fmaxf(v, 0.f) + __logf(1.f + __expf(-fabsf(v)));
}

// ---------------------------------------------------------------------------
// Fused packing: all weights + aexp in ONE dispatch. grid (224, 9).
// ---------------------------------------------------------------------------
static __device__ __forceinline__ void pack_w_seg(const float* __restrict__ W,
                                                  unsigned short* __restrict__ Wp,
                                                  int M, int C, int Mp, int Coct,
                                                  int cell) {
    if (cell >= Coct * Mp) return;
    int co = cell / Mp, m = cell - co * Mp;
    unsigned short v[8];
#pragma unroll
    for (int j = 0; j < 8; ++j) {
        int c = co * 8 + j;
        float f = (m < M && c < C) ? W[(size_t)m * C + c] : 0.f;
        v[j] = bfbits(f);
    }
    *(uint4*)&Wp[(size_t)cell * 8] = *(uint4*)v;
}

__global__ __launch_bounds__(256) void k_pack_fused(
        const float* __restrict__ ffw, unsigned short* __restrict__ ffWp,
        const float* __restrict__ sW0, unsigned short* __restrict__ inW0,
        const float* __restrict__ cW0, unsigned short* __restrict__ inW1,
        const float* __restrict__ sW8, unsigned short* __restrict__ outW0,
        const float* __restrict__ cW8, unsigned short* __restrict__ outW1,
        const float* __restrict__ sW3, unsigned short* __restrict__ xW0,
        const float* __restrict__ cW3, unsigned short* __restrict__ xW1,
        const float* __restrict__ sAl, float* __restrict__ aexp0,
        const float* __restrict__ cAl, float* __restrict__ aexp1) {
    int cell = blockIdx.x * 256 + threadIdx.x;
    switch (blockIdx.y) {
    case 0: {  // ff_w (Do,Di,K) -> [k][co][do][8]
        if (cell >= KK * 32 * DD) return;
        int doo = cell % DD;
        int rest = cell / DD;
        int co = rest % 32, k = rest / 32;
        unsigned short v[8];
#pragma unroll
        for (int j = 0; j < 8; ++j)
            v[j] = bfbits(ffw[((size_t)doo * DD + co * 8 + j) * KK + k]);
        *(uint4*)&ffWp[(size_t)cell * 8] = *(uint4*)v;
    } break;
    case 1: pack_w_seg(sW0, inW0, 1024, 256, 1024, 32, cell); break;
    case 2: pack_w_seg(cW0, inW1, 1024, 256, 1024, 32, cell); break;
    case 3: pack_w_seg(sW8, outW0, 256, 512, 256, 64, cell); break;
    case 4: pack_w_seg(cW8, outW1, 256, 512, 256, 64, cell); break;
    case 5: pack_w_seg(sW3, xW0, 48, 512, 64, 64, cell); break;
    case 6: pack_w_seg(cW3, xW1, 48, 512, 64, 64, cell); break;
    case 7: if (cell < EE * NN) aexp0[cell] = -expf(sAl[cell]); break;
    case 8: if (cell < EE * NN) aexp1[cell] = -expf(cAl[cell]); break;
    }
}

// x (B, D, L) fp32 -> xp[b][co][l+8][8] bf16 with 8-column zero pad both sides
__global__ __launch_bounds__(256) void k_pack_x(const float* __restrict__ x,
                                                unsigned short* __restrict__ xp) {
    int l = blockIdx.x * 256 + threadIdx.x;
    int co = blockIdx.y, b = blockIdx.z;
    if (l >= LPAD) return;
    int sl = l - 8;
    unsigned short v[8];
#pragma unroll
    for (int j = 0; j < 8; ++j) {
        float f = (sl >= 0 && sl < LL) ? x[((size_t)(b * DD) + co * 8 + j) * LL + sl] : 0.f;
        v[j] = bfbits(f);
    }
    *(uint4*)&xp[(((size_t)(b * 32) + co) * LPAD + l) * 8] = *(uint4*)v;
}

// ---------------------------------------------------------------------------
// instance norm over L per (b,d), fused * mask, writes packed bf16 [b][d/8][l][8].
// ---------------------------------------------------------------------------
__global__ __launch_bounds__(256) void k_instnorm(const float* __restrict__ x,
                                                  const float* __restrict__ mask,
                                                  unsigned short* __restrict__ outp) {
    const int bd = blockIdx.x;
    const int b = bd >> 8, d = bd & 255;
    const int tid = threadIdx.x;
    const float* row = x + (size_t)bd * LL;
    float v[8];
    float s = 0.f, s2 = 0.f;
#pragma unroll
    for (int i = 0; i < 8; ++i) {
        v[i] = row[i * 256 + tid];
        s += v[i];
        s2 = fmaf(v[i], v[i], s2);
    }
#pragma unroll
    for (int off = 32; off > 0; off >>= 1) {
        s  += __shfl_down(s, off);
        s2 += __shfl_down(s2, off);
    }
    __shared__ float red[2][4];
    if ((tid & 63) == 0) { red[0][tid >> 6] = s; red[1][tid >> 6] = s2; }
    __syncthreads();
    s  = red[0][0] + red[0][1] + red[0][2] + red[0][3];
    s2 = red[1][0] + red[1][1] + red[1][2] + red[1][3];
    const float mu  = s * (1.f / LL);
    const float var = s2 * (1.f / LL) - mu * mu;
    const float inv = rsqrtf(var + 1e-5f);
    const float* mrow = mask + (size_t)b * LL;
    unsigned short* op = outp + ((size_t)(b * 32) + (d >> 3)) * LL * 8 + (d & 7);
#pragma unroll
    for (int i = 0; i < 8; ++i) {
        int l = i * 256 + tid;
        op[(size_t)l * 8] = bfbits((v[i] - mu) * inv * mrow[l]);
    }
}

// ---------------------------------------------------------------------------
// MFMA GEMM, double-buffered LDS, one barrier per K-chunk (BK=32).
// out[b][m][l] = sum_c A[m][c] * B[b][c][l]
// A packed [co][Ms][8] bf16.
// B layout: BLT=0 -> [b][co][L][8]; BLT=1 -> [b][l][E] (EphOrBoct = E).
// STOREOUT: write fp32 planar out.  BCT48: rows m<48 -> bct[b][l][48].
// FINAL: out = (fx + fo0 + (fs + v)*mask)*mask -> out (d_out).
// ---------------------------------------------------------------------------
template <int RM, int NLT, int STOREOUT, int BCT48, int BLT, int FINAL>
__global__ __launch_bounds__(256) void k_mfma_gemm(
        const unsigned short* __restrict__ Ap,
        const unsigned short* __restrict__ Bp,
        float* __restrict__ out,
        float* __restrict__ bct,
        const float* __restrict__ fx,
        const float* __restrict__ fo0,
        const float* __restrict__ fs,
        const float* __restrict__ fmask,
        int Ms, int Coct, int EphOrBoct) {
    constexpr int TM = RM * 32;
    constexpr int TL = NLT * 32;
    constexpr int APITCH = TM * 8 + 8;
    constexpr int BPITCH = TL * 8 + 8;
    constexpr int ACELLS = (4 * TM) / 256;
    constexpr int BCELLS = (4 * TL) / 256;
    __shared__ unsigned short As[2][4 * APITCH];
    __shared__ unsigned short Bs[2][4 * BPITCH];
    const int tid = threadIdx.x;
    const int w = tid >> 6, lane = tid & 63;
    const int quad = lane >> 4, t = lane & 15;
    const int wm = (w >> 1) * (RM * 16), wl = (w & 1) * (NLT * 16);
    const int l0 = blockIdx.x * TL;
    const int m0 = blockIdx.y * TM;
    const int b  = blockIdx.z;

    floatx4 acc[RM][NLT];
#pragma unroll
    for (int r = 0; r < RM; ++r)
#pragma unroll
        for (int j = 0; j < NLT; ++j) acc[r][j] = (floatx4){0.f, 0.f, 0.f, 0.f};

    uint4 areg[ACELLS], breg[BCELLS];
    auto loadRegs = [&](int c0) {
#pragma unroll
        for (int i = 0; i < ACELLS; ++i) {
            int cell = tid + i * 256;
            int q = cell / TM, mm = cell % TM;
            areg[i] = *(const uint4*)&Ap[((size_t)(c0 + q) * Ms + m0 + mm) * 8];
        }
#pragma unroll
        for (int i = 0; i < BCELLS; ++i) {
            int cell = tid + i * 256;
            if (BLT == 0) {
                int q = cell / TL, ll = cell % TL;
                breg[i] = *(const uint4*)&Bp[((size_t)b * EphOrBoct * LL +
                                              (size_t)(c0 + q) * LL + l0 + ll) * 8];
            } else {
                int ll = cell >> 2, q = cell & 3;
                breg[i] = *(const uint4*)&Bp[((size_t)b * LL + l0 + ll) * EphOrBoct +
                                             (size_t)(c0 + q) * 8];
            }
        }
    };
    auto storeRegs = [&](int p) {
#pragma unroll
        for (int i = 0; i < ACELLS; ++i) {
            int cell = tid + i * 256;
            int q = cell / TM, mm = cell % TM;
            *(uint4*)&As[p][q * APITCH + mm * 8] = areg[i];
        }
#pragma unroll
        for (int i = 0; i < BCELLS; ++i) {
            int cell = tid + i * 256;
            int q, ll;
            if (BLT == 0) { q = cell / TL; ll = cell % TL; }
            else          { ll = cell >> 2; q = cell & 3; }
            *(uint4*)&Bs[p][q * BPITCH + ll * 8] = breg[i];
        }
    };

    loadRegs(0);
    storeRegs(0);
    __syncthreads();
    int p = 0;
    for (int c0 = 4; c0 <= Coct; c0 += 4) {
        const bool has_next = (c0 < Coct);
        if (has_next) loadRegs(c0);
        short8 af[RM], bfv[NLT];
#pragma unroll
        for (int r = 0; r < RM; ++r)
            af[r] = *(short8*)&As[p][quad * APITCH + (wm + r * 16 + t) * 8];
#pragma unroll
        for (int j = 0; j < NLT; ++j)
            bfv[j] = *(short8*)&Bs[p][quad * BPITCH + (wl + j * 16 + t) * 8];
#pragma unroll
        for (int r = 0; r < RM; ++r)
#pragma unroll
            for (int j = 0; j < NLT; ++j)
                acc[r][j] = __builtin_amdgcn_mfma_f32_16x16x32_bf16(af[r], bfv[j], acc[r][j], 0, 0, 0);
        if (has_next) {
            storeRegs(p ^ 1);
            __syncthreads();
            p ^= 1;
        }
    }
    // epilogue: C/D layout col = lane&15 (l), row = quad*4 + reg (m)
#pragma unroll
    for (int r = 0; r < RM; ++r) {
        int mb = m0 + wm + r * 16 + quad * 4;
#pragma unroll
        for (int i = 0; i < 4; ++i) {
            int m = mb + i;
#pragma unroll
            for (int j = 0; j < NLT; ++j) {
                int l = l0 + wl + j * 16 + t;
                float v = acc[r][j][i];
                if (STOREOUT) out[((size_t)b * Ms + m) * LL + l] = v;
                if (BCT48) {
                    if (m < 48) bct[((size_t)b * LL + l) * 48 + m] = v;
                }
                if (FINAL) {
                    size_t idx = ((size_t)b * Ms + m) * LL + l;
                    float mk = fmask[(size_t)b * LL + l];
                    out[idx] = (fx[idx] + fo0[idx] + (fs[idx] + v) * mk) * mk;
                }
            }
        }
    }
}

// ---------------------------------------------------------------------------
// conv_ff: LDS-free, MFMA fragments loaded directly from global.
// ---------------------------------------------------------------------------
__global__ __launch_bounds__(256) void k_conv_mfma(
        const unsigned short* __restrict__ Wp,
        const unsigned short* __restrict__ Xp,
        const float* __restrict__ bias,
        float* __restrict__ out) {
    const int tid = threadIdx.x;
    const int w = tid >> 6, lane = tid & 63;
    const int quad = lane >> 4, t = lane & 15;
    const int wm = (w >> 1) * 64, wl = (w & 1) * 32;
    const int l0 = blockIdx.x * 64;
    const int m0 = blockIdx.y * 128;
    const int b  = blockIdx.z;

    floatx4 acc[4][2];
#pragma unroll
    for (int r = 0; r < 4; ++r)
#pragma unroll
        for (int j = 0; j < 2; ++j) acc[r][j] = (floatx4){0.f, 0.f, 0.f, 0.f};

    const unsigned short* wbase = Wp + ((size_t)quad * DD + m0 + wm + t) * 8;
    const unsigned short* xbase = Xp + (((size_t)(b * 32) + quad) * LPAD + l0 + wl + t + 5) * 8;

    for (int dc = 0; dc < 8; ++dc) {
#pragma unroll
        for (int k = 0; k < KK; ++k) {
            short8 af[4], bfv[2];
#pragma unroll
            for (int r = 0; r < 4; ++r)
                af[r] = *(const short8*)&wbase[((size_t)(k * 32 + dc * 4) * DD + r * 16) * 8];
#pragma unroll
            for (int j = 0; j < 2; ++j)
                bfv[j] = *(const short8*)&xbase[((size_t)(dc * 4) * LPAD + j * 16 + k) * 8];
#pragma unroll
            for (int r = 0; r < 4; ++r)
#pragma unroll
                for (int j = 0; j < 2; ++j)
                    acc[r][j] = __builtin_amdgcn_mfma_f32_16x16x32_bf16(af[r], bfv[j], acc[r][j], 0, 0, 0);
        }
    }
#pragma unroll
    for (int r = 0; r < 4; ++r) {
        int mb = m0 + wm + r * 16 + quad * 4;
#pragma unroll
        for (int i = 0; i < 4; ++i) {
            int m = mb + i;
            float bv = bias[m];
#pragma unroll
            for (int j = 0; j < 2; ++j) {
                int l = l0 + wl + j * 16 + t;
                float v = acc[r][j][i] + bv;
                out[((size_t)b * DD + m) * LL + l] = v > 0.f ? v : 0.f;
            }
        }
    }
}

// ---------------------------------------------------------------------------
// dwconv: tiled transpose. Writes ONLY bf16: xbf[b][l][e] = silu(conv(x)),
// gbf[b][l][e] = silu(z).  grid (L/64, E/64, B).
// ---------------------------------------------------------------------------
__global__ __launch_bounds__(256) void k_dwconv2(const float* __restrict__ xz,
                                                 const float* __restrict__ cw,
                                                 const float* __restrict__ cb,
                                                 unsigned short* __restrict__ xbf,
                                                 unsigned short* __restrict__ gbf) {
    __shared__ float xs[64][71];   // pitch 71: conflict-free
    __shared__ float zs[64][65];
    const int tid = threadIdx.x;
    const int l0 = blockIdx.x * 64;
    const int e0 = blockIdx.y * 64;
    const int b  = blockIdx.z;
    for (int idx = tid; idx < 64 * 70; idx += 256) {
        int r = idx / 70, c = idx - r * 70;
        int gl = l0 - 6 + c;
        xs[r][c] = (gl >= 0) ? xz[((size_t)(b * 2 * EE) + e0 + r) * LL + gl] : 0.f;
    }
    for (int idx = tid; idx < 64 * 64; idx += 256) {
        int r = idx >> 6, c = idx & 63;
        zs[r][c] = xz[((size_t)(b * 2 * EE) + EE + e0 + r) * LL + l0 + c];
    }
    __syncthreads();
    const int e = tid & 63, g = tid >> 6;
    float wv[KK];
#pragma unroll
    for (int k = 0; k < KK; ++k) wv[k] = cw[(e0 + e) * KK + k];
    const float cbe = cb[e0 + e];
#pragma unroll 4
    for (int i = 0; i < 16; ++i) {
        int li = g * 16 + i;
        float acc = cbe;
#pragma unroll
        for (int k = 0; k < KK; ++k) acc = fmaf(xs[e][li + k], wv[k], acc);
        float v = acc / (1.f + __expf(-acc));
        size_t o = ((size_t)(b * LL) + l0 + li) * EE + e0 + e;
        xbf[o] = bfbits(v);
        float zz = zs[e][li];
        gbf[o] = bfbits(zz / (1.f + __expf(-zz)));
    }
}

// ---------------------------------------------------------------------------
// Selective scan: one thread owns all 16 n-states of one (b,e) chunk.
// t = ch*2048 + b*512 + e (lanes = consecutive e).
// u from xbf[b][l][e] bf16 (lane-stride-1); bct[b][l][48] broadcast.
// dt inline: softplus(Wdt[e] . bct[l][0:16] + dt_bias[e]).
// ---------------------------------------------------------------------------
__global__ __launch_bounds__(256) void k_scanA(const unsigned short* __restrict__ ubf,
                                               const float* __restrict__ bct,
                                               const float* __restrict__ aexp,
                                               const float* __restrict__ Wdt,
                                               const float* __restrict__ dtbias,
                                               float* __restrict__ aprod,
                                               float* __restrict__ hend) {
    const int t = blockIdx.x * 256 + threadIdx.x;
    const int e = t & (EE - 1);
    const int b = (t >> 9) & (BB - 1);
    const int ch = t >> 11;
    float A[16], h[16], ap[16], wd[16];
#pragma unroll
    for (int q = 0; q < 4; ++q) {
        *(float4*)&A[q * 4]  = *(const float4*)&aexp[e * 16 + q * 4];
        *(float4*)&wd[q * 4] = *(const float4*)&Wdt[e * 16 + q * 4];
    }
    const float be = dtbias[e];
#pragma unroll
    for (int n = 0; n < 16; ++n) { h[n] = 0.f; ap[n] = 1.f; }
    const unsigned short* up = ubf + ((size_t)(b * LL) + ch * CLEN) * EE + e;
    const float* bc = bct + ((size_t)(b * LL) + ch * CLEN) * 48;
#pragma unroll 4
    for (int i = 0; i < CLEN; ++i) {
        float uv = bf2f(up[(size_t)i * EE]);
        const float* bcl = bc + (size_t)i * 48;
        float Dv[16], Bv[16];
#pragma unroll
        for (int q = 0; q < 4; ++q) {
            *(float4*)&Dv[q * 4] = *(const float4*)(bcl + q * 4);
            *(float4*)&Bv[q * 4] = *(const float4*)(bcl + 16 + q * 4);
        }
        float d0 = be, d1 = 0.f, d2 = 0.f, d3 = 0.f;
#pragma unroll
        for (int r = 0; r < 4; ++r) {
            d0 = fmaf(wd[r], Dv[r], d0);
            d1 = fmaf(wd[r + 4], Dv[r + 4], d1);
            d2 = fmaf(wd[r + 8], Dv[r + 8], d2);
            d3 = fmaf(wd[r + 12], Dv[r + 12], d3);
        }
        float dv = softplus_fast((d0 + d1) + (d2 + d3));
        float du = dv * uv;
#pragma unroll
        for (int n = 0; n < 16; ++n) {
            float dA = __expf(dv * A[n]);
            h[n] = fmaf(dA, h[n], du * Bv[n]);
            ap[n] *= dA;
        }
    }
    float* app = aprod + (size_t)t * 16;
    float* hp  = hend + (size_t)t * 16;
#pragma unroll
    for (int q = 0; q < 4; ++q) {
        *(float4*)&app[q * 4] = *(float4*)&ap[q * 4];
        *(float4*)&hp[q * 4]  = *(float4*)&h[q * 4];
    }
}

// Pass B (in place): aprod[idx] <- carry into chunk ch for each (b,e,n).
__global__ __launch_bounds__(256) void k_scanB(float* __restrict__ aprod,
                                               const float* __restrict__ hend) {
    const int s = blockIdx.x * 256 + threadIdx.x;   // (b,e,n) = 32768
    float c = 0.f;
#pragma unroll 4
    for (int ch = 0; ch < NC; ++ch) {
        size_t idx = (size_t)ch * (BB * EE * NN) + s;
        float a = aprod[idx];
        float hh = hend[idx];
        aprod[idx] = c;
        c = fmaf(a, c, hh);
    }
}

// Pass C: re-scan with carry-in; y = (sum_n h*C + u*Dp) * g -> yt[b][l][e] bf16.
__global__ __launch_bounds__(256) void k_scanC(const unsigned short* __restrict__ ubf,
                                               const float* __restrict__ bct,
                                               const float* __restrict__ aexp,
                                               const float* __restrict__ Wdt,
                                               const float* __restrict__ dtbias,
                                               const float* __restrict__ Dp,
                                               const unsigned short* __restrict__ gbf,
                                               const float* __restrict__ carry,
                                               unsigned short* __restrict__ yt) {
    const int t = blockIdx.x * 256 + threadIdx.x;
    const int e = t & (EE - 1);
    const int b = (t >> 9) & (BB - 1);
    const int ch = t >> 11;
    float A[16], h[16], wd[16];
#pragma unroll
    for (int q = 0; q < 4; ++q) {
        *(float4*)&A[q * 4]  = *(const float4*)&aexp[e * 16 + q * 4];
        *(float4*)&wd[q * 4] = *(const float4*)&Wdt[e * 16 + q * 4];
        *(float4*)&h[q * 4]  = *(const float4*)&carry[(size_t)t * 16 + q * 4];
    }
    const float be = dtbias[e];
    const float Dpe = Dp[e];
    const size_t base = ((size_t)(b * LL) + ch * CLEN) * EE + e;
    const unsigned short* up = ubf + base;
    const unsigned short* gp = gbf + base;
    unsigned short* yp = yt + base;
    const float* bc = bct + ((size_t)(b * LL) + ch * CLEN) * 48;
#pragma unroll 4
    for (int i = 0; i < CLEN; ++i) {
        float uv = bf2f(up[(size_t)i * EE]);
        float gv = bf2f(gp[(size_t)i * EE]);
        const float* bcl = bc + (size_t)i * 48;
        float Dv[16], Bv[16], Cv[16];
#pragma unroll
        for (int q = 0; q < 4; ++q) {
            *(float4*)&Dv[q * 4] = *(const float4*)(bcl + q * 4);
            *(float4*)&Bv[q * 4] = *(const float4*)(bcl + 16 + q * 4);
            *(float4*)&Cv[q * 4] = *(const float4*)(bcl + 32 + q * 4);
        }
        float d0 = be, d1 = 0.f, d2 = 0.f, d3 = 0.f;
#pragma unroll
        for (int r = 0; r < 4; ++r) {
            d0 = fmaf(wd[r], Dv[r], d0);
            d1 = fmaf(wd[r + 4], Dv[r + 4], d1);
            d2 = fmaf(wd[r + 8], Dv[r + 8], d2);
            d3 = fmaf(wd[r + 12], Dv[r + 12], d3);
        }
        float dv = softplus_fast((d0 + d1) + (d2 + d3));
        float du = dv * uv;
        float p0 = 0.f, p1 = 0.f, p2 = 0.f, p3 = 0.f;
#pragma unroll
        for (int n = 0; n < 4; ++n) {
            float dA = __expf(dv * A[n]);
            h[n] = fmaf(dA, h[n], du * Bv[n]);
            p0 = fmaf(h[n], Cv[n], p0);
        }
#pragma unroll
        for (int n = 4; n < 8; ++n) {
            float dA = __expf(dv * A[n]);
            h[n] = fmaf(dA, h[n], du * Bv[n]);
            p1 = fmaf(h[n], Cv[n], p1);
        }
#pragma unroll
        for (int n = 8; n < 12; ++n) {
            float dA = __expf(dv * A[n]);
            h[n] = fmaf(dA, h[n], du * Bv[n]);
            p2 = fmaf(h[n], Cv[n], p2);
        }
#pragma unroll
        for (int n = 12; n < 16; ++n) {
            float dA = __expf(dv * A[n]);
            h[n] = fmaf(dA, h[n], du * Bv[n]);
            p3 = fmaf(h[n], Cv[n], p3);
        }
        float p = (p0 + p1) + (p2 + p3) + uv * Dpe;
        yp[(size_t)i * EE] = bfbits(p * gv);
    }
}

// ---------------------------------------------------------------------------
extern "C" void kernel_launch(void* const* d_in, const int* in_sizes, int n_in,
                              void* d_out, int out_size, void* d_ws, size_t ws_size,
                              hipStream_t stream) {
    const float* x    = (const float*)d_in[0];
    const float* enc  = (const float*)d_in[1];
    const float* mask = (const float*)d_in[2];
    const float* ff_w = (const float*)d_in[3];
    const float* ff_b = (const float*)d_in[4];
    const float* sp[9];
    const float* cp[9];
    for (int i = 0; i < 9; ++i) {
        sp[i] = (const float*)d_in[5 + i];
        cp[i] = (const float*)d_in[14 + i];
    }

    // workspace carve-up
    float* ws = (float*)d_ws;
    auto fcarve = [&](size_t n) { float* p = ws; ws += (n + 3) & ~3ul; return p; };
    float* out0  = fcarve((size_t)BB * DD * LL);
    float* xz    = fcarve((size_t)BB * 2 * EE * LL);
    float* soutb = fcarve((size_t)BB * DD * LL);
    float* aprod = fcarve((size_t)NC * BB * EE * NN);   // doubles as carry
    float* hendb = fcarve((size_t)NC * BB * EE * NN);
    float* BCt   = fcarve((size_t)BB * LL * 48);
    float* aexp2 = fcarve((size_t)2 * EE * NN);
    auto scarve = [&](size_t n) { unsigned short* p = (unsigned short*)ws; ws += (n + 7) / 2 / 4 * 4 + 4; return p; };
    unsigned short* nrmp = scarve((size_t)BB * 32 * LL * 8);
    unsigned short* xbf  = scarve((size_t)BB * LL * EE);
    unsigned short* gbf  = scarve((size_t)BB * LL * EE);
    unsigned short* yt   = scarve((size_t)BB * LL * EE);
    unsigned short* xp   = scarve((size_t)BB * 32 * LPAD * 8);
    unsigned short* ffWp = scarve((size_t)KK * 32 * DD * 8);
    unsigned short* inWp[2]  = { scarve(32 * 1024 * 8), scarve(32 * 1024 * 8) };
    unsigned short* outWp[2] = { scarve(64 * 256 * 8),  scarve(64 * 256 * 8) };
    unsigned short* xWp[2]   = { scarve(64 * 64 * 8),   scarve(64 * 64 * 8) };

    // ---- fused packing (weights + aexp) + input packing ----
    k_pack_fused<<<dim3(224, 9), 256, 0, stream>>>(
        ff_w, ffWp, sp[0], inWp[0], cp[0], inWp[1], sp[8], outWp[0], cp[8], outWp[1],
        sp[3], xWp[0], cp[3], xWp[1],
        sp[6], aexp2, cp[6], aexp2 + EE * NN);
    k_pack_x<<<dim3((LPAD + 255) / 256, 32, BB), 256, 0, stream>>>(x, xp);

    // ---- conv_ff (MFMA, LDS-free direct fragments) ----
    k_conv_mfma<<<dim3(LL / 64, DD / 128, BB), 256, 0, stream>>>(ffWp, xp, ff_b, out0);

    auto mamba = [&](const float* src, const float* const* P, int s, int isFinal) {
        const float* aexp = aexp2 + s * EE * NN;
        k_instnorm<<<dim3(BB * DD), 256, 0, stream>>>(src, mask, nrmp);
        // in_proj: xz (B, 2E, L) fp32.  M=1024, Coct=32; 64m x 128l tiles
        k_mfma_gemm<2, 4, 1, 0, 0, 0><<<dim3(LL / 128, 1024 / 64, BB), 256, 0, stream>>>(
            inWp[s], nrmp, xz, nullptr, nullptr, nullptr, nullptr, nullptr, 1024, 32, 32);
        // dwconv + silu + transpose -> xbf (u), gbf (gate), bf16 [b][l][e]
        k_dwconv2<<<dim3(LL / 64, EE / 64, BB), 256, 0, stream>>>(
            xz, P[1], P[2], xbf, gbf);
        // x_proj: M=64 (48 live), Coct=64; B = xbf [b][l][E]; writes bct[b][l][48]
        k_mfma_gemm<2, 2, 0, 1, 1, 0><<<dim3(LL / 64, 1, BB), 256, 0, stream>>>(
            xWp[s], xbf, nullptr, BCt, nullptr, nullptr, nullptr, nullptr, 64, 64, EE);
        // selective scan (chunked linear recurrence), dt inline -> yt bf16
        k_scanA<<<dim3(NC * BB * EE / 256), 256, 0, stream>>>(
            xbf, BCt, aexp, P[4], P[5], aprod, hendb);
        k_scanB<<<dim3(BB * EE * NN / 256), 256, 0, stream>>>(aprod, hendb);
        k_scanC<<<dim3(NC * BB * EE / 256), 256, 0, stream>>>(
            xbf, BCt, aexp, P[4], P[5], P[7], gbf, aprod, yt);
        // out_proj: M=256, Coct=64; B = yt [b][l][E]
        if (!isFinal) {
            k_mfma_gemm<2, 2, 1, 0, 1, 0><<<dim3(LL / 64, DD / 64, BB), 256, 0, stream>>>(
                outWp[s], yt, soutb, nullptr, nullptr, nullptr, nullptr, nullptr, 256, 64, EE);
        } else {
            // fused final: out = (x + out0 + (sout + v)*mask)*mask -> d_out
            k_mfma_gemm<2, 2, 0, 0, 1, 1><<<dim3(LL / 64, DD / 64, BB), 256, 0, stream>>>(
                outWp[s], yt, (float*)d_out, nullptr, x, out0, soutb, mask, 256, 64, EE);
        }
    };

    mamba(out0, sp, 0, 0);   // self block -> soutb
    mamba(enc, cp, 1, 1);    // cross block, fused final -> d_out
}

// Round 10
// 456.995 us; speedup vs baseline: 3.1698x; 1.0453x over previous
//
#include <hip/hip_runtime.h>
#include <hip/hip_bf16.h>
#include <math.h>

// Problem constants
#define BB 4
#define DD 256
#define LL 2048
#define EE 512
#define NN 16
#define KK 7
#define RR 16
#define NC 128             // scan chunks
#define CLEN (LL / NC)     // 16 steps per chunk
#define LPAD 2064          // padded L for conv input (8 zeros each side)

typedef __attribute__((ext_vector_type(8))) short short8;   // 8 bf16 (4 VGPRs)
typedef __attribute__((ext_vector_type(4))) float floatx4;  // MFMA accumulator

static __device__ __forceinline__ unsigned short bfbits(float f) {
    __hip_bfloat16 h = __float2bfloat16(f);
    return *(unsigned short*)&h;
}

static __device__ __forceinline__ float bf2f(unsigned short u) {
    unsigned v = ((unsigned)u) << 16;
    float f;
    __builtin_memcpy(&f, &v, 4);
    return f;
}

static __device__ __forceinline__ float softplus_fast(float v) {
    return fmaxf(v, 0.f) + __logf(1.f + __expf(-fabsf(v)));
}

// ---------------------------------------------------------------------------
// Fused packing: all weights + aexp in ONE dispatch. grid (224, 9).
// ---------------------------------------------------------------------------
static __device__ __forceinline__ void pack_w_seg(const float* __restrict__ W,
                                                  unsigned short* __restrict__ Wp,
                                                  int M, int C, int Mp, int Coct,
                                                  int cell) {
    if (cell >= Coct * Mp) return;
    int co = cell / Mp, m = cell - co * Mp;
    unsigned short v[8];
#pragma unroll
    for (int j = 0; j < 8; ++j) {
        int c = co * 8 + j;
        float f = (m < M && c < C) ? W[(size_t)m * C + c] : 0.f;
        v[j] = bfbits(f);
    }
    *(uint4*)&Wp[(size_t)cell * 8] = *(uint4*)v;
}

__global__ __launch_bounds__(256) void k_pack_fused(
        const float* __restrict__ ffw, unsigned short* __restrict__ ffWp,
        const float* __restrict__ sW0, unsigned short* __restrict__ inW0,
        const float* __restrict__ cW0, unsigned short* __restrict__ inW1,
        const float* __restrict__ sW8, unsigned short* __restrict__ outW0,
        const float* __restrict__ cW8, unsigned short* __restrict__ outW1,
        const float* __restrict__ sW3, unsigned short* __restrict__ xW0,
        const float* __restrict__ cW3, unsigned short* __restrict__ xW1,
        const float* __restrict__ sAl, float* __restrict__ aexp0,
        const float* __restrict__ cAl, float* __restrict__ aexp1) {
    int cell = blockIdx.x * 256 + threadIdx.x;
    switch (blockIdx.y) {
    case 0: {  // ff_w (Do,Di,K) -> [k][co][do][8]
        if (cell >= KK * 32 * DD) return;
        int doo = cell % DD;
        int rest = cell / DD;
        int co = rest % 32, k = rest / 32;
        unsigned short v[8];
#pragma unroll
        for (int j = 0; j < 8; ++j)
            v[j] = bfbits(ffw[((size_t)doo * DD + co * 8 + j) * KK + k]);
        *(uint4*)&ffWp[(size_t)cell * 8] = *(uint4*)v;
    } break;
    case 1: pack_w_seg(sW0, inW0, 1024, 256, 1024, 32, cell); break;
    case 2: pack_w_seg(cW0, inW1, 1024, 256, 1024, 32, cell); break;
    case 3: pack_w_seg(sW8, outW0, 256, 512, 256, 64, cell); break;
    case 4: pack_w_seg(cW8, outW1, 256, 512, 256, 64, cell); break;
    case 5: pack_w_seg(sW3, xW0, 48, 512, 64, 64, cell); break;
    case 6: pack_w_seg(cW3, xW1, 48, 512, 64, 64, cell); break;
    case 7: if (cell < EE * NN) aexp0[cell] = -expf(sAl[cell]); break;
    case 8: if (cell < EE * NN) aexp1[cell] = -expf(cAl[cell]); break;
    }
}

// x (B, D, L) fp32 -> xp[b][co][l+8][8] bf16 with 8-column zero pad both sides
__global__ __launch_bounds__(256) void k_pack_x(const float* __restrict__ x,
                                                unsigned short* __restrict__ xp) {
    int l = blockIdx.x * 256 + threadIdx.x;
    int co = blockIdx.y, b = blockIdx.z;
    if (l >= LPAD) return;
    int sl = l - 8;
    unsigned short v[8];
#pragma unroll
    for (int j = 0; j < 8; ++j) {
        float f = (sl >= 0 && sl < LL) ? x[((size_t)(b * DD) + co * 8 + j) * LL + sl] : 0.f;
        v[j] = bfbits(f);
    }
    *(uint4*)&xp[(((size_t)(b * 32) + co) * LPAD + l) * 8] = *(uint4*)v;
}

// ---------------------------------------------------------------------------
// instance norm over L per (b,d), fused * mask, writes packed bf16 [b][d/8][l][8].
// ---------------------------------------------------------------------------
__global__ __launch_bounds__(256) void k_instnorm(const float* __restrict__ x,
                                                  const float* __restrict__ mask,
                                                  unsigned short* __restrict__ outp) {
    const int bd = blockIdx.x;
    const int b = bd >> 8, d = bd & 255;
    const int tid = threadIdx.x;
    const float* row = x + (size_t)bd * LL;
    float v[8];
    float s = 0.f, s2 = 0.f;
#pragma unroll
    for (int i = 0; i < 8; ++i) {
        v[i] = row[i * 256 + tid];
        s += v[i];
        s2 = fmaf(v[i], v[i], s2);
    }
#pragma unroll
    for (int off = 32; off > 0; off >>= 1) {
        s  += __shfl_down(s, off);
        s2 += __shfl_down(s2, off);
    }
    __shared__ float red[2][4];
    if ((tid & 63) == 0) { red[0][tid >> 6] = s; red[1][tid >> 6] = s2; }
    __syncthreads();
    s  = red[0][0] + red[0][1] + red[0][2] + red[0][3];
    s2 = red[1][0] + red[1][1] + red[1][2] + red[1][3];
    const float mu  = s * (1.f / LL);
    const float var = s2 * (1.f / LL) - mu * mu;
    const float inv = rsqrtf(var + 1e-5f);
    const float* mrow = mask + (size_t)b * LL;
    unsigned short* op = outp + ((size_t)(b * 32) + (d >> 3)) * LL * 8 + (d & 7);
#pragma unroll
    for (int i = 0; i < 8; ++i) {
        int l = i * 256 + tid;
        op[(size_t)l * 8] = bfbits((v[i] - mu) * inv * mrow[l]);
    }
}

// ---------------------------------------------------------------------------
// MFMA GEMM, double-buffered LDS, one barrier per K-chunk (BK=32).
// out[b][m][l] = sum_c A[m][c] * B[b][c][l]
// A packed [co][Ms][8] bf16.
// B layout: BLT=0 -> [b][co][L][8]; BLT=1 -> [b][l][E] (EphOrBoct = E).
// STOREOUT: write fp32 planar out.  BCT48: rows m<48 -> bct[b][l][48].
// FINAL: out = (fx + fo0 + (fs + v)*mask)*mask -> out (d_out).
// ---------------------------------------------------------------------------
template <int RM, int NLT, int STOREOUT, int BCT48, int BLT, int FINAL>
__global__ __launch_bounds__(256) void k_mfma_gemm(
        const unsigned short* __restrict__ Ap,
        const unsigned short* __restrict__ Bp,
        float* __restrict__ out,
        float* __restrict__ bct,
        const float* __restrict__ fx,
        const float* __restrict__ fo0,
        const float* __restrict__ fs,
        const float* __restrict__ fmask,
        int Ms, int Coct, int EphOrBoct) {
    constexpr int TM = RM * 32;
    constexpr int TL = NLT * 32;
    constexpr int APITCH = TM * 8 + 8;
    constexpr int BPITCH = TL * 8 + 8;
    constexpr int ACELLS = (4 * TM) / 256;
    constexpr int BCELLS = (4 * TL) / 256;
    __shared__ unsigned short As[2][4 * APITCH];
    __shared__ unsigned short Bs[2][4 * BPITCH];
    const int tid = threadIdx.x;
    const int w = tid >> 6, lane = tid & 63;
    const int quad = lane >> 4, t = lane & 15;
    const int wm = (w >> 1) * (RM * 16), wl = (w & 1) * (NLT * 16);
    const int l0 = blockIdx.x * TL;
    const int m0 = blockIdx.y * TM;
    const int b  = blockIdx.z;

    floatx4 acc[RM][NLT];
#pragma unroll
    for (int r = 0; r < RM; ++r)
#pragma unroll
        for (int j = 0; j < NLT; ++j) acc[r][j] = (floatx4){0.f, 0.f, 0.f, 0.f};

    uint4 areg[ACELLS], breg[BCELLS];
    auto loadRegs = [&](int c0) {
#pragma unroll
        for (int i = 0; i < ACELLS; ++i) {
            int cell = tid + i * 256;
            int q = cell / TM, mm = cell % TM;
            areg[i] = *(const uint4*)&Ap[((size_t)(c0 + q) * Ms + m0 + mm) * 8];
        }
#pragma unroll
        for (int i = 0; i < BCELLS; ++i) {
            int cell = tid + i * 256;
            if (BLT == 0) {
                int q = cell / TL, ll = cell % TL;
                breg[i] = *(const uint4*)&Bp[((size_t)b * EphOrBoct * LL +
                                              (size_t)(c0 + q) * LL + l0 + ll) * 8];
            } else {
                int ll = cell >> 2, q = cell & 3;
                breg[i] = *(const uint4*)&Bp[((size_t)b * LL + l0 + ll) * EphOrBoct +
                                             (size_t)(c0 + q) * 8];
            }
        }
    };
    auto storeRegs = [&](int p) {
#pragma unroll
        for (int i = 0; i < ACELLS; ++i) {
            int cell = tid + i * 256;
            int q = cell / TM, mm = cell % TM;
            *(uint4*)&As[p][q * APITCH + mm * 8] = areg[i];
        }
#pragma unroll
        for (int i = 0; i < BCELLS; ++i) {
            int cell = tid + i * 256;
            int q, ll;
            if (BLT == 0) { q = cell / TL; ll = cell % TL; }
            else          { ll = cell >> 2; q = cell & 3; }
            *(uint4*)&Bs[p][q * BPITCH + ll * 8] = breg[i];
        }
    };

    loadRegs(0);
    storeRegs(0);
    __syncthreads();
    int p = 0;
    for (int c0 = 4; c0 <= Coct; c0 += 4) {
        const bool has_next = (c0 < Coct);
        if (has_next) loadRegs(c0);
        short8 af[RM], bfv[NLT];
#pragma unroll
        for (int r = 0; r < RM; ++r)
            af[r] = *(short8*)&As[p][quad * APITCH + (wm + r * 16 + t) * 8];
#pragma unroll
        for (int j = 0; j < NLT; ++j)
            bfv[j] = *(short8*)&Bs[p][quad * BPITCH + (wl + j * 16 + t) * 8];
#pragma unroll
        for (int r = 0; r < RM; ++r)
#pragma unroll
            for (int j = 0; j < NLT; ++j)
                acc[r][j] = __builtin_amdgcn_mfma_f32_16x16x32_bf16(af[r], bfv[j], acc[r][j], 0, 0, 0);
        if (has_next) {
            storeRegs(p ^ 1);
            __syncthreads();
            p ^= 1;
        }
    }
    // epilogue: C/D layout col = lane&15 (l), row = quad*4 + reg (m)
#pragma unroll
    for (int r = 0; r < RM; ++r) {
        int mb = m0 + wm + r * 16 + quad * 4;
#pragma unroll
        for (int i = 0; i < 4; ++i) {
            int m = mb + i;
#pragma unroll
            for (int j = 0; j < NLT; ++j) {
                int l = l0 + wl + j * 16 + t;
                float v = acc[r][j][i];
                if (STOREOUT) out[((size_t)b * Ms + m) * LL + l] = v;
                if (BCT48) {
                    if (m < 48) bct[((size_t)b * LL + l) * 48 + m] = v;
                }
                if (FINAL) {
                    size_t idx = ((size_t)b * Ms + m) * LL + l;
                    float mk = fmask[(size_t)b * LL + l];
                    out[idx] = (fx[idx] + fo0[idx] + (fs[idx] + v) * mk) * mk;
                }
            }
        }
    }
}

// ---------------------------------------------------------------------------
// conv_ff: LDS-free, MFMA fragments loaded directly from global.
// ---------------------------------------------------------------------------
__global__ __launch_bounds__(256) void k_conv_mfma(
        const unsigned short* __restrict__ Wp,
        const unsigned short* __restrict__ Xp,
        const float* __restrict__ bias,
        float* __restrict__ out) {
    const int tid = threadIdx.x;
    const int w = tid >> 6, lane = tid & 63;
    const int quad = lane >> 4, t = lane & 15;
    const int wm = (w >> 1) * 64, wl = (w & 1) * 32;
    const int l0 = blockIdx.x * 64;
    const int m0 = blockIdx.y * 128;
    const int b  = blockIdx.z;

    floatx4 acc[4][2];
#pragma unroll
    for (int r = 0; r < 4; ++r)
#pragma unroll
        for (int j = 0; j < 2; ++j) acc[r][j] = (floatx4){0.f, 0.f, 0.f, 0.f};

    const unsigned short* wbase = Wp + ((size_t)quad * DD + m0 + wm + t) * 8;
    const unsigned short* xbase = Xp + (((size_t)(b * 32) + quad) * LPAD + l0 + wl + t + 5) * 8;

    for (int dc = 0; dc < 8; ++dc) {
#pragma unroll
        for (int k = 0; k < KK; ++k) {
            short8 af[4], bfv[2];
#pragma unroll
            for (int r = 0; r < 4; ++r)
                af[r] = *(const short8*)&wbase[((size_t)(k * 32 + dc * 4) * DD + r * 16) * 8];
#pragma unroll
            for (int j = 0; j < 2; ++j)
                bfv[j] = *(const short8*)&xbase[((size_t)(dc * 4) * LPAD + j * 16 + k) * 8];
#pragma unroll
            for (int r = 0; r < 4; ++r)
#pragma unroll
                for (int j = 0; j < 2; ++j)
                    acc[r][j] = __builtin_amdgcn_mfma_f32_16x16x32_bf16(af[r], bfv[j], acc[r][j], 0, 0, 0);
        }
    }
#pragma unroll
    for (int r = 0; r < 4; ++r) {
        int mb = m0 + wm + r * 16 + quad * 4;
#pragma unroll
        for (int i = 0; i < 4; ++i) {
            int m = mb + i;
            float bv = bias[m];
#pragma unroll
            for (int j = 0; j < 2; ++j) {
                int l = l0 + wl + j * 16 + t;
                float v = acc[r][j][i] + bv;
                out[((size_t)b * DD + m) * LL + l] = v > 0.f ? v : 0.f;
            }
        }
    }
}

// ---------------------------------------------------------------------------
// dwconv: tiled transpose. Writes ONLY bf16: xbf[b][l][e] = silu(conv(x)),
// gbf[b][l][e] = silu(z).  grid (L/64, E/64, B).
// ---------------------------------------------------------------------------
__global__ __launch_bounds__(256) void k_dwconv2(const float* __restrict__ xz,
                                                 const float* __restrict__ cw,
                                                 const float* __restrict__ cb,
                                                 unsigned short* __restrict__ xbf,
                                                 unsigned short* __restrict__ gbf) {
    __shared__ float xs[64][71];   // pitch 71: conflict-free
    __shared__ float zs[64][65];
    const int tid = threadIdx.x;
    const int l0 = blockIdx.x * 64;
    const int e0 = blockIdx.y * 64;
    const int b  = blockIdx.z;
    for (int idx = tid; idx < 64 * 70; idx += 256) {
        int r = idx / 70, c = idx - r * 70;
        int gl = l0 - 6 + c;
        xs[r][c] = (gl >= 0) ? xz[((size_t)(b * 2 * EE) + e0 + r) * LL + gl] : 0.f;
    }
    for (int idx = tid; idx < 64 * 64; idx += 256) {
        int r = idx >> 6, c = idx & 63;
        zs[r][c] = xz[((size_t)(b * 2 * EE) + EE + e0 + r) * LL + l0 + c];
    }
    __syncthreads();
    const int e = tid & 63, g = tid >> 6;
    float wv[KK];
#pragma unroll
    for (int k = 0; k < KK; ++k) wv[k] = cw[(e0 + e) * KK + k];
    const float cbe = cb[e0 + e];
#pragma unroll 4
    for (int i = 0; i < 16; ++i) {
        int li = g * 16 + i;
        float acc = cbe;
#pragma unroll
        for (int k = 0; k < KK; ++k) acc = fmaf(xs[e][li + k], wv[k], acc);
        float v = acc / (1.f + __expf(-acc));
        size_t o = ((size_t)(b * LL) + l0 + li) * EE + e0 + e;
        xbf[o] = bfbits(v);
        float zz = zs[e][li];
        gbf[o] = bfbits(zz / (1.f + __expf(-zz)));
    }
}

// ---------------------------------------------------------------------------
// Selective scan, PHASE-SPLIT: phase 1 computes dt for all CLEN steps
// (independent load->dot->softplus chains = full ILP on loads + trans pipe),
// phase 2 runs the recurrence (exp 16-way independent, shallow h-chain).
// t = ch*2048 + b*512 + e (lanes = consecutive e).
// ---------------------------------------------------------------------------
__global__ __launch_bounds__(256) void k_scanA(const unsigned short* __restrict__ ubf,
                                               const float* __restrict__ bct,
                                               const float* __restrict__ aexp,
                                               const float* __restrict__ Wdt,
                                               const float* __restrict__ dtbias,
                                               float* __restrict__ aprod,
                                               float* __restrict__ hend) {
    const int t = blockIdx.x * 256 + threadIdx.x;
    const int e = t & (EE - 1);
    const int b = (t >> 9) & (BB - 1);
    const int ch = t >> 11;
    float A[16], wd[16];
#pragma unroll
    for (int q = 0; q < 4; ++q) {
        *(float4*)&A[q * 4]  = *(const float4*)&aexp[e * 16 + q * 4];
        *(float4*)&wd[q * 4] = *(const float4*)&Wdt[e * 16 + q * 4];
    }
    const float be = dtbias[e];
    const float* bc = bct + ((size_t)(b * LL) + ch * CLEN) * 48;

    // phase 1: dt for all steps (independent chains)
    float dv[CLEN];
#pragma unroll
    for (int i = 0; i < CLEN; ++i) {
        const float* bcl = bc + (size_t)i * 48;
        float Dv[16];
#pragma unroll
        for (int q = 0; q < 4; ++q)
            *(float4*)&Dv[q * 4] = *(const float4*)(bcl + q * 4);
        float d0 = be, d1 = 0.f, d2 = 0.f, d3 = 0.f;
#pragma unroll
        for (int r = 0; r < 4; ++r) {
            d0 = fmaf(wd[r], Dv[r], d0);
            d1 = fmaf(wd[r + 4], Dv[r + 4], d1);
            d2 = fmaf(wd[r + 8], Dv[r + 8], d2);
            d3 = fmaf(wd[r + 12], Dv[r + 12], d3);
        }
        dv[i] = softplus_fast((d0 + d1) + (d2 + d3));
    }

    // phase 2: recurrence
    float h[16], ap[16];
#pragma unroll
    for (int n = 0; n < 16; ++n) { h[n] = 0.f; ap[n] = 1.f; }
    const unsigned short* up = ubf + ((size_t)(b * LL) + ch * CLEN) * EE + e;
#pragma unroll 4
    for (int i = 0; i < CLEN; ++i) {
        float uv = bf2f(up[(size_t)i * EE]);
        const float* bcl = bc + (size_t)i * 48 + 16;
        float Bv[16];
#pragma unroll
        for (int q = 0; q < 4; ++q)
            *(float4*)&Bv[q * 4] = *(const float4*)(bcl + q * 4);
        float du = dv[i] * uv;
#pragma unroll
        for (int n = 0; n < 16; ++n) {
            float dA = __expf(dv[i] * A[n]);
            h[n] = fmaf(dA, h[n], du * Bv[n]);
            ap[n] *= dA;
        }
    }
    float* app = aprod + (size_t)t * 16;
    float* hp  = hend + (size_t)t * 16;
#pragma unroll
    for (int q = 0; q < 4; ++q) {
        *(float4*)&app[q * 4] = *(float4*)&ap[q * 4];
        *(float4*)&hp[q * 4]  = *(float4*)&h[q * 4];
    }
}

// Pass B (in place): aprod[idx] <- carry into chunk ch for each (b,e,n).
__global__ __launch_bounds__(256) void k_scanB(float* __restrict__ aprod,
                                               const float* __restrict__ hend) {
    const int s = blockIdx.x * 256 + threadIdx.x;   // (b,e,n) = 32768
    float c = 0.f;
#pragma unroll 4
    for (int ch = 0; ch < NC; ++ch) {
        size_t idx = (size_t)ch * (BB * EE * NN) + s;
        float a = aprod[idx];
        float hh = hend[idx];
        aprod[idx] = c;
        c = fmaf(a, c, hh);
    }
}

// Pass C, phase-split; y = (sum_n h*C + u*Dp) * g -> yt[b][l][e] bf16.
__global__ __launch_bounds__(256) void k_scanC(const unsigned short* __restrict__ ubf,
                                               const float* __restrict__ bct,
                                               const float* __restrict__ aexp,
                                               const float* __restrict__ Wdt,
                                               const float* __restrict__ dtbias,
                                               const float* __restrict__ Dp,
                                               const unsigned short* __restrict__ gbf,
                                               const float* __restrict__ carry,
                                               unsigned short* __restrict__ yt) {
    const int t = blockIdx.x * 256 + threadIdx.x;
    const int e = t & (EE - 1);
    const int b = (t >> 9) & (BB - 1);
    const int ch = t >> 11;
    float A[16], wd[16];
#pragma unroll
    for (int q = 0; q < 4; ++q) {
        *(float4*)&A[q * 4]  = *(const float4*)&aexp[e * 16 + q * 4];
        *(float4*)&wd[q * 4] = *(const float4*)&Wdt[e * 16 + q * 4];
    }
    const float be = dtbias[e];
    const float Dpe = Dp[e];
    const float* bc = bct + ((size_t)(b * LL) + ch * CLEN) * 48;

    // phase 1: dt for all steps
    float dv[CLEN];
#pragma unroll
    for (int i = 0; i < CLEN; ++i) {
        const float* bcl = bc + (size_t)i * 48;
        float Dv[16];
#pragma unroll
        for (int q = 0; q < 4; ++q)
            *(float4*)&Dv[q * 4] = *(const float4*)(bcl + q * 4);
        float d0 = be, d1 = 0.f, d2 = 0.f, d3 = 0.f;
#pragma unroll
        for (int r = 0; r < 4; ++r) {
            d0 = fmaf(wd[r], Dv[r], d0);
            d1 = fmaf(wd[r + 4], Dv[r + 4], d1);
            d2 = fmaf(wd[r + 8], Dv[r + 8], d2);
            d3 = fmaf(wd[r + 12], Dv[r + 12], d3);
        }
        dv[i] = softplus_fast((d0 + d1) + (d2 + d3));
    }

    // phase 2: recurrence + output
    float h[16];
#pragma unroll
    for (int q = 0; q < 4; ++q)
        *(float4*)&h[q * 4] = *(const float4*)&carry[(size_t)t * 16 + q * 4];
    const size_t base = ((size_t)(b * LL) + ch * CLEN) * EE + e;
    const unsigned short* up = ubf + base;
    const unsigned short* gp = gbf + base;
    unsigned short* yp = yt + base;
#pragma unroll 4
    for (int i = 0; i < CLEN; ++i) {
        float uv = bf2f(up[(size_t)i * EE]);
        float gv = bf2f(gp[(size_t)i * EE]);
        const float* bcl = bc + (size_t)i * 48;
        float Bv[16], Cv[16];
#pragma unroll
        for (int q = 0; q < 4; ++q) {
            *(float4*)&Bv[q * 4] = *(const float4*)(bcl + 16 + q * 4);
            *(float4*)&Cv[q * 4] = *(const float4*)(bcl + 32 + q * 4);
        }
        float du = dv[i] * uv;
        float p0 = 0.f, p1 = 0.f, p2 = 0.f, p3 = 0.f;
#pragma unroll
        for (int n = 0; n < 4; ++n) {
            float dA = __expf(dv[i] * A[n]);
            h[n] = fmaf(dA, h[n], du * Bv[n]);
            p0 = fmaf(h[n], Cv[n], p0);
        }
#pragma unroll
        for (int n = 4; n < 8; ++n) {
            float dA = __expf(dv[i] * A[n]);
            h[n] = fmaf(dA, h[n], du * Bv[n]);
            p1 = fmaf(h[n], Cv[n], p1);
        }
#pragma unroll
        for (int n = 8; n < 12; ++n) {
            float dA = __expf(dv[i] * A[n]);
            h[n] = fmaf(dA, h[n], du * Bv[n]);
            p2 = fmaf(h[n], Cv[n], p2);
        }
#pragma unroll
        for (int n = 12; n < 16; ++n) {
            float dA = __expf(dv[i] * A[n]);
            h[n] = fmaf(dA, h[n], du * Bv[n]);
            p3 = fmaf(h[n], Cv[n], p3);
        }
        float p = (p0 + p1) + (p2 + p3) + uv * Dpe;
        yp[(size_t)i * EE] = bfbits(p * gv);
    }
}

// ---------------------------------------------------------------------------
extern "C" void kernel_launch(void* const* d_in, const int* in_sizes, int n_in,
                              void* d_out, int out_size, void* d_ws, size_t ws_size,
                              hipStream_t stream) {
    const float* x    = (const float*)d_in[0];
    const float* enc  = (const float*)d_in[1];
    const float* mask = (const float*)d_in[2];
    const float* ff_w = (const float*)d_in[3];
    const float* ff_b = (const float*)d_in[4];
    const float* sp[9];
    const float* cp[9];
    for (int i = 0; i < 9; ++i) {
        sp[i] = (const float*)d_in[5 + i];
        cp[i] = (const float*)d_in[14 + i];
    }

    // workspace carve-up
    float* ws = (float*)d_ws;
    auto fcarve = [&](size_t n) { float* p = ws; ws += (n + 3) & ~3ul; return p; };
    float* out0  = fcarve((size_t)BB * DD * LL);
    float* xz    = fcarve((size_t)BB * 2 * EE * LL);
    float* soutb = fcarve((size_t)BB * DD * LL);
    float* aprod = fcarve((size_t)NC * BB * EE * NN);   // doubles as carry
    float* hendb = fcarve((size_t)NC * BB * EE * NN);
    float* BCt   = fcarve((size_t)BB * LL * 48);
    float* aexp2 = fcarve((size_t)2 * EE * NN);
    auto scarve = [&](size_t n) { unsigned short* p = (unsigned short*)ws; ws += (n + 7) / 2 / 4 * 4 + 4; return p; };
    unsigned short* nrmp = scarve((size_t)BB * 32 * LL * 8);
    unsigned short* xbf  = scarve((size_t)BB * LL * EE);
    unsigned short* gbf  = scarve((size_t)BB * LL * EE);
    unsigned short* yt   = scarve((size_t)BB * LL * EE);
    unsigned short* xp   = scarve((size_t)BB * 32 * LPAD * 8);
    unsigned short* ffWp = scarve((size_t)KK * 32 * DD * 8);
    unsigned short* inWp[2]  = { scarve(32 * 1024 * 8), scarve(32 * 1024 * 8) };
    unsigned short* outWp[2] = { scarve(64 * 256 * 8),  scarve(64 * 256 * 8) };
    unsigned short* xWp[2]   = { scarve(64 * 64 * 8),   scarve(64 * 64 * 8) };

    // ---- fused packing (weights + aexp) + input packing ----
    k_pack_fused<<<dim3(224, 9), 256, 0, stream>>>(
        ff_w, ffWp, sp[0], inWp[0], cp[0], inWp[1], sp[8], outWp[0], cp[8], outWp[1],
        sp[3], xWp[0], cp[3], xWp[1],
        sp[6], aexp2, cp[6], aexp2 + EE * NN);
    k_pack_x<<<dim3((LPAD + 255) / 256, 32, BB), 256, 0, stream>>>(x, xp);

    // ---- conv_ff (MFMA, LDS-free direct fragments) ----
    k_conv_mfma<<<dim3(LL / 64, DD / 128, BB), 256, 0, stream>>>(ffWp, xp, ff_b, out0);

    auto mamba = [&](const float* src, const float* const* P, int s, int isFinal) {
        const float* aexp = aexp2 + s * EE * NN;
        k_instnorm<<<dim3(BB * DD), 256, 0, stream>>>(src, mask, nrmp);
        // in_proj: xz (B, 2E, L) fp32.  M=1024, Coct=32; 64m x 128l tiles
        k_mfma_gemm<2, 4, 1, 0, 0, 0><<<dim3(LL / 128, 1024 / 64, BB), 256, 0, stream>>>(
            inWp[s], nrmp, xz, nullptr, nullptr, nullptr, nullptr, nullptr, 1024, 32, 32);
        // dwconv + silu + transpose -> xbf (u), gbf (gate), bf16 [b][l][e]
        k_dwconv2<<<dim3(LL / 64, EE / 64, BB), 256, 0, stream>>>(
            xz, P[1], P[2], xbf, gbf);
        // x_proj: M=64 (48 live), Coct=64; B = xbf [b][l][E]; writes bct[b][l][48]
        k_mfma_gemm<2, 2, 0, 1, 1, 0><<<dim3(LL / 64, 1, BB), 256, 0, stream>>>(
            xWp[s], xbf, nullptr, BCt, nullptr, nullptr, nullptr, nullptr, 64, 64, EE);
        // selective scan (chunked linear recurrence), dt inline -> yt bf16
        k_scanA<<<dim3(NC * BB * EE / 256), 256, 0, stream>>>(
            xbf, BCt, aexp2 + s * EE * NN, P[4], P[5], aprod, hendb);
        k_scanB<<<dim3(BB * EE * NN / 256), 256, 0, stream>>>(aprod, hendb);
        k_scanC<<<dim3(NC * BB * EE / 256), 256, 0, stream>>>(
            xbf, BCt, aexp, P[4], P[5], P[7], gbf, aprod, yt);
        // out_proj: M=256, Coct=64; B = yt [b][l][E]
        if (!isFinal) {
            k_mfma_gemm<2, 2, 1, 0, 1, 0><<<dim3(LL / 64, DD / 64, BB), 256, 0, stream>>>(
                outWp[s], yt, soutb, nullptr, nullptr, nullptr, nullptr, nullptr, 256, 64, EE);
        } else {
            // fused final: out = (x + out0 + (sout + v)*mask)*mask -> d_out
            k_mfma_gemm<2, 2, 0, 0, 1, 1><<<dim3(LL / 64, DD / 64, BB), 256, 0, stream>>>(
                outWp[s], yt, (float*)d_out, nullptr, x, out0, soutb, mask, 256, 64, EE);
        }
    };

    mamba(out0, sp, 0, 0);   // self block -> soutb
    mamba(enc, cp, 1, 1);    // cross block, fused final -> d_out
}

// Round 11
// 450.592 us; speedup vs baseline: 3.2148x; 1.0142x over previous
//
#include <hip/hip_runtime.h>
#include <hip/hip_bf16.h>
#include <math.h>

// Problem constants
#define BB 4
#define DD 256
#define LL 2048
#define EE 512
#define NN 16
#define KK 7
#define RR 16
#define NC 128             // scan chunks
#define CLEN (LL / NC)     // 16 steps per chunk
#define LPAD 2064          // padded L for conv input (8 zeros each side)

// per-mamba-block scratch spans (elements)
#define ESPAN   ((size_t)BB * LL * EE)        // bf16 [b][l][e] buffers
#define XZSPAN  ((size_t)BB * 2 * EE * LL)    // fp32 xz
#define BCTSPAN ((size_t)BB * LL * 48)        // fp32 bct
#define APSPAN  ((size_t)NC * BB * EE * NN)   // fp32 aprod/hend
#define NRMPSPAN ((size_t)BB * 32 * LL * 8)   // bf16 nrmp

typedef __attribute__((ext_vector_type(8))) short short8;   // 8 bf16 (4 VGPRs)
typedef __attribute__((ext_vector_type(4))) float floatx4;  // MFMA accumulator

static __device__ __forceinline__ unsigned short bfbits(float f) {
    __hip_bfloat16 h = __float2bfloat16(f);
    return *(unsigned short*)&h;
}

static __device__ __forceinline__ float bf2f(unsigned short u) {
    unsigned v = ((unsigned)u) << 16;
    float f;
    __builtin_memcpy(&f, &v, 4);
    return f;
}

static __device__ __forceinline__ float softplus_fast(float v) {
    return fmaxf(v, 0.f) + __logf(1.f + __expf(-fabsf(v)));
}

// ---------------------------------------------------------------------------
// Fused packing: all weights + aexp in ONE dispatch. grid (224, 9).
// ---------------------------------------------------------------------------
static __device__ __forceinline__ void pack_w_seg(const float* __restrict__ W,
                                                  unsigned short* __restrict__ Wp,
                                                  int M, int C, int Mp, int Coct,
                                                  int cell) {
    if (cell >= Coct * Mp) return;
    int co = cell / Mp, m = cell - co * Mp;
    unsigned short v[8];
#pragma unroll
    for (int j = 0; j < 8; ++j) {
        int c = co * 8 + j;
        float f = (m < M && c < C) ? W[(size_t)m * C + c] : 0.f;
        v[j] = bfbits(f);
    }
    *(uint4*)&Wp[(size_t)cell * 8] = *(uint4*)v;
}

__global__ __launch_bounds__(256) void k_pack_fused(
        const float* __restrict__ ffw, unsigned short* __restrict__ ffWp,
        const float* __restrict__ sW0, unsigned short* __restrict__ inW0,
        const float* __restrict__ cW0, unsigned short* __restrict__ inW1,
        const float* __restrict__ sW8, unsigned short* __restrict__ outW0,
        const float* __restrict__ cW8, unsigned short* __restrict__ outW1,
        const float* __restrict__ sW3, unsigned short* __restrict__ xW0,
        const float* __restrict__ cW3, unsigned short* __restrict__ xW1,
        const float* __restrict__ sAl, float* __restrict__ aexp0,
        const float* __restrict__ cAl, float* __restrict__ aexp1) {
    int cell = blockIdx.x * 256 + threadIdx.x;
    switch (blockIdx.y) {
    case 0: {  // ff_w (Do,Di,K) -> [k][co][do][8]
        if (cell >= KK * 32 * DD) return;
        int doo = cell % DD;
        int rest = cell / DD;
        int co = rest % 32, k = rest / 32;
        unsigned short v[8];
#pragma unroll
        for (int j = 0; j < 8; ++j)
            v[j] = bfbits(ffw[((size_t)doo * DD + co * 8 + j) * KK + k]);
        *(uint4*)&ffWp[(size_t)cell * 8] = *(uint4*)v;
    } break;
    case 1: pack_w_seg(sW0, inW0, 1024, 256, 1024, 32, cell); break;
    case 2: pack_w_seg(cW0, inW1, 1024, 256, 1024, 32, cell); break;
    case 3: pack_w_seg(sW8, outW0, 256, 512, 256, 64, cell); break;
    case 4: pack_w_seg(cW8, outW1, 256, 512, 256, 64, cell); break;
    case 5: pack_w_seg(sW3, xW0, 48, 512, 64, 64, cell); break;
    case 6: pack_w_seg(cW3, xW1, 48, 512, 64, 64, cell); break;
    case 7: if (cell < EE * NN) aexp0[cell] = -expf(sAl[cell]); break;
    case 8: if (cell < EE * NN) aexp1[cell] = -expf(cAl[cell]); break;
    }
}

// x (B, D, L) fp32 -> xp[b][co][l+8][8] bf16 with 8-column zero pad both sides
__global__ __launch_bounds__(256) void k_pack_x(const float* __restrict__ x,
                                                unsigned short* __restrict__ xp) {
    int l = blockIdx.x * 256 + threadIdx.x;
    int co = blockIdx.y, b = blockIdx.z;
    if (l >= LPAD) return;
    int sl = l - 8;
    unsigned short v[8];
#pragma unroll
    for (int j = 0; j < 8; ++j) {
        float f = (sl >= 0 && sl < LL) ? x[((size_t)(b * DD) + co * 8 + j) * LL + sl] : 0.f;
        v[j] = bfbits(f);
    }
    *(uint4*)&xp[(((size_t)(b * 32) + co) * LPAD + l) * 8] = *(uint4*)v;
}

// ---------------------------------------------------------------------------
// instance norm, MERGED over both mamba blocks: blockIdx.x in [0, 2*B*D);
// s selects source (0: srcA=out0, 1: srcB=enc) and nrmp half.
// ---------------------------------------------------------------------------
__global__ __launch_bounds__(256) void k_instnorm_m(const float* __restrict__ srcA,
                                                    const float* __restrict__ srcB,
                                                    const float* __restrict__ mask,
                                                    unsigned short* __restrict__ outp) {
    const int s = blockIdx.x >> 10;
    const int bd = blockIdx.x & 1023;
    const int b = bd >> 8, d = bd & 255;
    const int tid = threadIdx.x;
    const float* row = (s ? srcB : srcA) + (size_t)bd * LL;
    float v[8];
    float ss = 0.f, s2 = 0.f;
#pragma unroll
    for (int i = 0; i < 8; ++i) {
        v[i] = row[i * 256 + tid];
        ss += v[i];
        s2 = fmaf(v[i], v[i], s2);
    }
#pragma unroll
    for (int off = 32; off > 0; off >>= 1) {
        ss += __shfl_down(ss, off);
        s2 += __shfl_down(s2, off);
    }
    __shared__ float red[2][4];
    if ((tid & 63) == 0) { red[0][tid >> 6] = ss; red[1][tid >> 6] = s2; }
    __syncthreads();
    ss = red[0][0] + red[0][1] + red[0][2] + red[0][3];
    s2 = red[1][0] + red[1][1] + red[1][2] + red[1][3];
    const float mu  = ss * (1.f / LL);
    const float var = s2 * (1.f / LL) - mu * mu;
    const float inv = rsqrtf(var + 1e-5f);
    const float* mrow = mask + (size_t)b * LL;
    unsigned short* op = outp + (size_t)s * NRMPSPAN
                       + ((size_t)(b * 32) + (d >> 3)) * LL * 8 + (d & 7);
#pragma unroll
    for (int i = 0; i < 8; ++i) {
        int l = i * 256 + tid;
        op[(size_t)l * 8] = bfbits((v[i] - mu) * inv * mrow[l]);
    }
}

// ---------------------------------------------------------------------------
// MFMA GEMM, double-buffered LDS, one barrier per K-chunk (BK=32).
// Merged-block support: blockIdx.z in [0, 4*S): b = z&3, s = z>>2.
// A = (s ? Ap1 : Ap0); Bp += s*BspanS; out += s*outSpanF; bct += s*bctSpanF.
// B layout: BLT=0 -> [b][co][L][8]; BLT=1 -> [b][l][E] (EphOrBoct = E).
// STOREOUT: fp32 planar out.  BCT48: rows m<48 -> bct[b][l][48].
// FINAL: out = (fx + fo0 + (fs + v)*mask)*mask.
// ---------------------------------------------------------------------------
template <int RM, int NLT, int STOREOUT, int BCT48, int BLT, int FINAL>
__global__ __launch_bounds__(256) void k_mfma_gemm(
        const unsigned short* __restrict__ Ap0,
        const unsigned short* __restrict__ Ap1,
        const unsigned short* __restrict__ Bp, size_t BspanS,
        float* __restrict__ out, size_t outSpanF,
        float* __restrict__ bct, size_t bctSpanF,
        const float* __restrict__ fx,
        const float* __restrict__ fo0,
        const float* __restrict__ fs,
        const float* __restrict__ fmask,
        int Ms, int Coct, int EphOrBoct) {
    constexpr int TM = RM * 32;
    constexpr int TL = NLT * 32;
    constexpr int APITCH = TM * 8 + 8;
    constexpr int BPITCH = TL * 8 + 8;
    constexpr int ACELLS = (4 * TM) / 256;
    constexpr int BCELLS = (4 * TL) / 256;
    __shared__ unsigned short As[2][4 * APITCH];
    __shared__ unsigned short Bs[2][4 * BPITCH];
    const int tid = threadIdx.x;
    const int w = tid >> 6, lane = tid & 63;
    const int quad = lane >> 4, t = lane & 15;
    const int wm = (w >> 1) * (RM * 16), wl = (w & 1) * (NLT * 16);
    const int l0 = blockIdx.x * TL;
    const int m0 = blockIdx.y * TM;
    const int z  = blockIdx.z;
    const int b  = z & 3, s = z >> 2;
    const unsigned short* Ap = s ? Ap1 : Ap0;
    Bp += (size_t)s * BspanS;
    if (STOREOUT) out += (size_t)s * outSpanF;
    if (BCT48) bct += (size_t)s * bctSpanF;

    floatx4 acc[RM][NLT];
#pragma unroll
    for (int r = 0; r < RM; ++r)
#pragma unroll
        for (int j = 0; j < NLT; ++j) acc[r][j] = (floatx4){0.f, 0.f, 0.f, 0.f};

    uint4 areg[ACELLS], breg[BCELLS];
    auto loadRegs = [&](int c0) {
#pragma unroll
        for (int i = 0; i < ACELLS; ++i) {
            int cell = tid + i * 256;
            int q = cell / TM, mm = cell % TM;
            areg[i] = *(const uint4*)&Ap[((size_t)(c0 + q) * Ms + m0 + mm) * 8];
        }
#pragma unroll
        for (int i = 0; i < BCELLS; ++i) {
            int cell = tid + i * 256;
            if (BLT == 0) {
                int q = cell / TL, ll = cell % TL;
                breg[i] = *(const uint4*)&Bp[((size_t)b * EphOrBoct * LL +
                                              (size_t)(c0 + q) * LL + l0 + ll) * 8];
            } else {
                int ll = cell >> 2, q = cell & 3;
                breg[i] = *(const uint4*)&Bp[((size_t)b * LL + l0 + ll) * EphOrBoct +
                                             (size_t)(c0 + q) * 8];
            }
        }
    };
    auto storeRegs = [&](int p) {
#pragma unroll
        for (int i = 0; i < ACELLS; ++i) {
            int cell = tid + i * 256;
            int q = cell / TM, mm = cell % TM;
            *(uint4*)&As[p][q * APITCH + mm * 8] = areg[i];
        }
#pragma unroll
        for (int i = 0; i < BCELLS; ++i) {
            int cell = tid + i * 256;
            int q, ll;
            if (BLT == 0) { q = cell / TL; ll = cell % TL; }
            else          { ll = cell >> 2; q = cell & 3; }
            *(uint4*)&Bs[p][q * BPITCH + ll * 8] = breg[i];
        }
    };

    loadRegs(0);
    storeRegs(0);
    __syncthreads();
    int p = 0;
    for (int c0 = 4; c0 <= Coct; c0 += 4) {
        const bool has_next = (c0 < Coct);
        if (has_next) loadRegs(c0);
        short8 af[RM], bfv[NLT];
#pragma unroll
        for (int r = 0; r < RM; ++r)
            af[r] = *(short8*)&As[p][quad * APITCH + (wm + r * 16 + t) * 8];
#pragma unroll
        for (int j = 0; j < NLT; ++j)
            bfv[j] = *(short8*)&Bs[p][quad * BPITCH + (wl + j * 16 + t) * 8];
#pragma unroll
        for (int r = 0; r < RM; ++r)
#pragma unroll
            for (int j = 0; j < NLT; ++j)
                acc[r][j] = __builtin_amdgcn_mfma_f32_16x16x32_bf16(af[r], bfv[j], acc[r][j], 0, 0, 0);
        if (has_next) {
            storeRegs(p ^ 1);
            __syncthreads();
            p ^= 1;
        }
    }
    // epilogue: C/D layout col = lane&15 (l), row = quad*4 + reg (m)
#pragma unroll
    for (int r = 0; r < RM; ++r) {
        int mb = m0 + wm + r * 16 + quad * 4;
#pragma unroll
        for (int i = 0; i < 4; ++i) {
            int m = mb + i;
#pragma unroll
            for (int j = 0; j < NLT; ++j) {
                int l = l0 + wl + j * 16 + t;
                float v = acc[r][j][i];
                if (STOREOUT) out[((size_t)b * Ms + m) * LL + l] = v;
                if (BCT48) {
                    if (m < 48) bct[((size_t)b * LL + l) * 48 + m] = v;
                }
                if (FINAL) {
                    size_t idx = ((size_t)b * Ms + m) * LL + l;
                    float mk = fmask[(size_t)b * LL + l];
                    out[idx] = (fx[idx] + fo0[idx] + (fs[idx] + v) * mk) * mk;
                }
            }
        }
    }
}

// ---------------------------------------------------------------------------
// conv_ff: LDS-free, MFMA fragments loaded directly from global.
// ---------------------------------------------------------------------------
__global__ __launch_bounds__(256) void k_conv_mfma(
        const unsigned short* __restrict__ Wp,
        const unsigned short* __restrict__ Xp,
        const float* __restrict__ bias,
        float* __restrict__ out) {
    const int tid = threadIdx.x;
    const int w = tid >> 6, lane = tid & 63;
    const int quad = lane >> 4, t = lane & 15;
    const int wm = (w >> 1) * 64, wl = (w & 1) * 32;
    const int l0 = blockIdx.x * 64;
    const int m0 = blockIdx.y * 128;
    const int b  = blockIdx.z;

    floatx4 acc[4][2];
#pragma unroll
    for (int r = 0; r < 4; ++r)
#pragma unroll
        for (int j = 0; j < 2; ++j) acc[r][j] = (floatx4){0.f, 0.f, 0.f, 0.f};

    const unsigned short* wbase = Wp + ((size_t)quad * DD + m0 + wm + t) * 8;
    const unsigned short* xbase = Xp + (((size_t)(b * 32) + quad) * LPAD + l0 + wl + t + 5) * 8;

    for (int dc = 0; dc < 8; ++dc) {
#pragma unroll
        for (int k = 0; k < KK; ++k) {
            short8 af[4], bfv[2];
#pragma unroll
            for (int r = 0; r < 4; ++r)
                af[r] = *(const short8*)&wbase[((size_t)(k * 32 + dc * 4) * DD + r * 16) * 8];
#pragma unroll
            for (int j = 0; j < 2; ++j)
                bfv[j] = *(const short8*)&xbase[((size_t)(dc * 4) * LPAD + j * 16 + k) * 8];
#pragma unroll
            for (int r = 0; r < 4; ++r)
#pragma unroll
                for (int j = 0; j < 2; ++j)
                    acc[r][j] = __builtin_amdgcn_mfma_f32_16x16x32_bf16(af[r], bfv[j], acc[r][j], 0, 0, 0);
        }
    }
#pragma unroll
    for (int r = 0; r < 4; ++r) {
        int mb = m0 + wm + r * 16 + quad * 4;
#pragma unroll
        for (int i = 0; i < 4; ++i) {
            int m = mb + i;
            float bv = bias[m];
#pragma unroll
            for (int j = 0; j < 2; ++j) {
                int l = l0 + wl + j * 16 + t;
                float v = acc[r][j][i] + bv;
                out[((size_t)b * DD + m) * LL + l] = v > 0.f ? v : 0.f;
            }
        }
    }
}

// ---------------------------------------------------------------------------
// dwconv, MERGED: grid (L/64, E/64, 2*B): b = z&3, s = z>>2.
// Writes bf16 xbf[b][l][e] = silu(conv(x)), gbf[b][l][e] = silu(z).
// ---------------------------------------------------------------------------
__global__ __launch_bounds__(256) void k_dwconv2(const float* __restrict__ xz,
                                                 const float* __restrict__ cw0,
                                                 const float* __restrict__ cw1,
                                                 const float* __restrict__ cb0,
                                                 const float* __restrict__ cb1,
                                                 unsigned short* __restrict__ xbf,
                                                 unsigned short* __restrict__ gbf) {
    __shared__ float xs[64][71];   // pitch 71: conflict-free
    __shared__ float zs[64][65];
    const int tid = threadIdx.x;
    const int l0 = blockIdx.x * 64;
    const int e0 = blockIdx.y * 64;
    const int z  = blockIdx.z;
    const int b  = z & 3, s = z >> 2;
    xz  += (size_t)s * XZSPAN;
    xbf += (size_t)s * ESPAN;
    gbf += (size_t)s * ESPAN;
    const float* cw = s ? cw1 : cw0;
    const float* cb = s ? cb1 : cb0;
    for (int idx = tid; idx < 64 * 70; idx += 256) {
        int r = idx / 70, c = idx - r * 70;
        int gl = l0 - 6 + c;
        xs[r][c] = (gl >= 0) ? xz[((size_t)(b * 2 * EE) + e0 + r) * LL + gl] : 0.f;
    }
    for (int idx = tid; idx < 64 * 64; idx += 256) {
        int r = idx >> 6, c = idx & 63;
        zs[r][c] = xz[((size_t)(b * 2 * EE) + EE + e0 + r) * LL + l0 + c];
    }
    __syncthreads();
    const int e = tid & 63, g = tid >> 6;
    float wv[KK];
#pragma unroll
    for (int k = 0; k < KK; ++k) wv[k] = cw[(e0 + e) * KK + k];
    const float cbe = cb[e0 + e];
#pragma unroll 4
    for (int i = 0; i < 16; ++i) {
        int li = g * 16 + i;
        float acc = cbe;
#pragma unroll
        for (int k = 0; k < KK; ++k) acc = fmaf(xs[e][li + k], wv[k], acc);
        float v = acc / (1.f + __expf(-acc));
        size_t o = ((size_t)(b * LL) + l0 + li) * EE + e0 + e;
        xbf[o] = bfbits(v);
        float zz = zs[e][li];
        gbf[o] = bfbits(zz / (1.f + __expf(-zz)));
    }
}

// ---------------------------------------------------------------------------
// Selective scan, MERGED + phase-split (fully unrolled so dv[] stays in regs).
// blockIdx.x in [0, 2*NC*B*E/256): s = blockIdx.x >> 10.
// t = within-s thread id; e = t&511, b = (t>>9)&3, ch = t>>11.
// aprod shortcut: prod(exp(dv_i*A)) == exp(A * sum(dv_i)).
// ---------------------------------------------------------------------------
__global__ __launch_bounds__(256) void k_scanA(const unsigned short* __restrict__ ubf,
                                               const float* __restrict__ bct,
                                               const float* __restrict__ aexp2,
                                               const float* __restrict__ Wdt0,
                                               const float* __restrict__ Wdt1,
                                               const float* __restrict__ db0,
                                               const float* __restrict__ db1,
                                               float* __restrict__ aprod,
                                               float* __restrict__ hend) {
    const int s = blockIdx.x >> 10;
    const int t = ((blockIdx.x & 1023) << 8) + threadIdx.x;
    const int e = t & (EE - 1);
    const int b = (t >> 9) & (BB - 1);
    const int ch = t >> 11;
    ubf   += (size_t)s * ESPAN;
    bct   += (size_t)s * BCTSPAN;
    aprod += (size_t)s * APSPAN;
    hend  += (size_t)s * APSPAN;
    const float* aexp = aexp2 + (size_t)s * (EE * NN);
    const float* Wdt  = s ? Wdt1 : Wdt0;
    const float be    = (s ? db1 : db0)[e];
    float A[16], wd[16];
#pragma unroll
    for (int q = 0; q < 4; ++q) {
        *(float4*)&A[q * 4]  = *(const float4*)&aexp[e * 16 + q * 4];
        *(float4*)&wd[q * 4] = *(const float4*)&Wdt[e * 16 + q * 4];
    }
    const float* bc = bct + ((size_t)(b * LL) + ch * CLEN) * 48;

    // phase 1: dt for all steps (independent chains)
    float dv[CLEN];
    float S = 0.f;
#pragma unroll
    for (int i = 0; i < CLEN; ++i) {
        const float* bcl = bc + (size_t)i * 48;
        float Dv[16];
#pragma unroll
        for (int q = 0; q < 4; ++q)
            *(float4*)&Dv[q * 4] = *(const float4*)(bcl + q * 4);
        float d0 = be, d1 = 0.f, d2 = 0.f, d3 = 0.f;
#pragma unroll
        for (int r = 0; r < 4; ++r) {
            d0 = fmaf(wd[r], Dv[r], d0);
            d1 = fmaf(wd[r + 4], Dv[r + 4], d1);
            d2 = fmaf(wd[r + 8], Dv[r + 8], d2);
            d3 = fmaf(wd[r + 12], Dv[r + 12], d3);
        }
        dv[i] = softplus_fast((d0 + d1) + (d2 + d3));
        S += dv[i];
    }

    // phase 2: recurrence (h only; aprod computed from S at the end)
    float h[16];
#pragma unroll
    for (int n = 0; n < 16; ++n) h[n] = 0.f;
    const unsigned short* up = ubf + ((size_t)(b * LL) + ch * CLEN) * EE + e;
#pragma unroll
    for (int i = 0; i < CLEN; ++i) {
        float uv = bf2f(up[(size_t)i * EE]);
        const float* bcl = bc + (size_t)i * 48 + 16;
        float Bv[16];
#pragma unroll
        for (int q = 0; q < 4; ++q)
            *(float4*)&Bv[q * 4] = *(const float4*)(bcl + q * 4);
        float du = dv[i] * uv;
#pragma unroll
        for (int n = 0; n < 16; ++n) {
            float dA = __expf(dv[i] * A[n]);
            h[n] = fmaf(dA, h[n], du * Bv[n]);
        }
    }
    float ap[16];
#pragma unroll
    for (int n = 0; n < 16; ++n) ap[n] = __expf(S * A[n]);
    float* app = aprod + (size_t)t * 16;
    float* hp  = hend + (size_t)t * 16;
#pragma unroll
    for (int q = 0; q < 4; ++q) {
        *(float4*)&app[q * 4] = *(float4*)&ap[q * 4];
        *(float4*)&hp[q * 4]  = *(float4*)&h[q * 4];
    }
}

// Pass B (in place, merged): blockIdx.x in [0, 2*B*E*N/256): s = x >> 7.
__global__ __launch_bounds__(256) void k_scanB(float* __restrict__ aprod,
                                               const float* __restrict__ hend) {
    const int s = blockIdx.x >> 7;
    const int ss = ((blockIdx.x & 127) << 8) + threadIdx.x;
    aprod += (size_t)s * APSPAN;
    hend  += (size_t)s * APSPAN;
    float c = 0.f;
#pragma unroll 4
    for (int ch = 0; ch < NC; ++ch) {
        size_t idx = (size_t)ch * (BB * EE * NN) + ss;
        float a = aprod[idx];
        float hh = hend[idx];
        aprod[idx] = c;
        c = fmaf(a, c, hh);
    }
}

// Pass C, merged + phase-split; y = (sum_n h*C + u*Dp) * g -> yt[b][l][e] bf16.
__global__ __launch_bounds__(256) void k_scanC(const unsigned short* __restrict__ ubf,
                                               const float* __restrict__ bct,
                                               const float* __restrict__ aexp2,
                                               const float* __restrict__ Wdt0,
                                               const float* __restrict__ Wdt1,
                                               const float* __restrict__ db0,
                                               const float* __restrict__ db1,
                                               const float* __restrict__ Dp0,
                                               const float* __restrict__ Dp1,
                                               const unsigned short* __restrict__ gbf,
                                               const float* __restrict__ carry,
                                               unsigned short* __restrict__ yt) {
    const int s = blockIdx.x >> 10;
    const int t = ((blockIdx.x & 1023) << 8) + threadIdx.x;
    const int e = t & (EE - 1);
    const int b = (t >> 9) & (BB - 1);
    const int ch = t >> 11;
    ubf   += (size_t)s * ESPAN;
    gbf   += (size_t)s * ESPAN;
    yt    += (size_t)s * ESPAN;
    bct   += (size_t)s * BCTSPAN;
    carry += (size_t)s * APSPAN;
    const float* aexp = aexp2 + (size_t)s * (EE * NN);
    const float* Wdt  = s ? Wdt1 : Wdt0;
    const float be    = (s ? db1 : db0)[e];
    const float Dpe   = (s ? Dp1 : Dp0)[e];
    float A[16], wd[16];
#pragma unroll
    for (int q = 0; q < 4; ++q) {
        *(float4*)&A[q * 4]  = *(const float4*)&aexp[e * 16 + q * 4];
        *(float4*)&wd[q * 4] = *(const float4*)&Wdt[e * 16 + q * 4];
    }
    const float* bc = bct + ((size_t)(b * LL) + ch * CLEN) * 48;

    // phase 1: dt for all steps
    float dv[CLEN];
#pragma unroll
    for (int i = 0; i < CLEN; ++i) {
        const float* bcl = bc + (size_t)i * 48;
        float Dv[16];
#pragma unroll
        for (int q = 0; q < 4; ++q)
            *(float4*)&Dv[q * 4] = *(const float4*)(bcl + q * 4);
        float d0 = be, d1 = 0.f, d2 = 0.f, d3 = 0.f;
#pragma unroll
        for (int r = 0; r < 4; ++r) {
            d0 = fmaf(wd[r], Dv[r], d0);
            d1 = fmaf(wd[r + 4], Dv[r + 4], d1);
            d2 = fmaf(wd[r + 8], Dv[r + 8], d2);
            d3 = fmaf(wd[r + 12], Dv[r + 12], d3);
        }
        dv[i] = softplus_fast((d0 + d1) + (d2 + d3));
    }

    // phase 2: recurrence + output
    float h[16];
#pragma unroll
    for (int q = 0; q < 4; ++q)
        *(float4*)&h[q * 4] = *(const float4*)&carry[(size_t)t * 16 + q * 4];
    const size_t base = ((size_t)(b * LL) + ch * CLEN) * EE + e;
    const unsigned short* up = ubf + base;
    const unsigned short* gp = gbf + base;
    unsigned short* yp = yt + base;
#pragma unroll
    for (int i = 0; i < CLEN; ++i) {
        float uv = bf2f(up[(size_t)i * EE]);
        float gv = bf2f(gp[(size_t)i * EE]);
        const float* bcl = bc + (size_t)i * 48;
        float Bv[16], Cv[16];
#pragma unroll
        for (int q = 0; q < 4; ++q) {
            *(float4*)&Bv[q * 4] = *(const float4*)(bcl + 16 + q * 4);
            *(float4*)&Cv[q * 4] = *(const float4*)(bcl + 32 + q * 4);
        }
        float du = dv[i] * uv;
        float p0 = 0.f, p1 = 0.f, p2 = 0.f, p3 = 0.f;
#pragma unroll
        for (int n = 0; n < 4; ++n) {
            float dA = __expf(dv[i] * A[n]);
            h[n] = fmaf(dA, h[n], du * Bv[n]);
            p0 = fmaf(h[n], Cv[n], p0);
        }
#pragma unroll
        for (int n = 4; n < 8; ++n) {
            float dA = __expf(dv[i] * A[n]);
            h[n] = fmaf(dA, h[n], du * Bv[n]);
            p1 = fmaf(h[n], Cv[n], p1);
        }
#pragma unroll
        for (int n = 8; n < 12; ++n) {
            float dA = __expf(dv[i] * A[n]);
            h[n] = fmaf(dA, h[n], du * Bv[n]);
            p2 = fmaf(h[n], Cv[n], p2);
        }
#pragma unroll
        for (int n = 12; n < 16; ++n) {
            float dA = __expf(dv[i] * A[n]);
            h[n] = fmaf(dA, h[n], du * Bv[n]);
            p3 = fmaf(h[n], Cv[n], p3);
        }
        float p = (p0 + p1) + (p2 + p3) + uv * Dpe;
        yp[(size_t)i * EE] = bfbits(p * gv);
    }
}

// ---------------------------------------------------------------------------
extern "C" void kernel_launch(void* const* d_in, const int* in_sizes, int n_in,
                              void* d_out, int out_size, void* d_ws, size_t ws_size,
                              hipStream_t stream) {
    const float* x    = (const float*)d_in[0];
    const float* enc  = (const float*)d_in[1];
    const float* mask = (const float*)d_in[2];
    const float* ff_w = (const float*)d_in[3];
    const float* ff_b = (const float*)d_in[4];
    const float* sp[9];
    const float* cp[9];
    for (int i = 0; i < 9; ++i) {
        sp[i] = (const float*)d_in[5 + i];
        cp[i] = (const float*)d_in[14 + i];
    }

    // workspace carve-up (duplicated per-mamba-block scratch: [s=0 | s=1])
    float* ws = (float*)d_ws;
    auto fcarve = [&](size_t n) { float* p = ws; ws += (n + 3) & ~3ul; return p; };
    float* out0  = fcarve((size_t)BB * DD * LL);
    float* xz    = fcarve(2 * XZSPAN);
    float* soutb = fcarve((size_t)BB * DD * LL);
    float* aprod = fcarve(2 * APSPAN);   // doubles as carry
    float* hendb = fcarve(2 * APSPAN);
    float* BCt   = fcarve(2 * BCTSPAN);
    float* aexp2 = fcarve((size_t)2 * EE * NN);
    auto scarve = [&](size_t n) { unsigned short* p = (unsigned short*)ws; ws += (n + 7) / 2 / 4 * 4 + 4; return p; };
    unsigned short* nrmp = scarve(2 * NRMPSPAN);
    unsigned short* xbf  = scarve(2 * ESPAN);
    unsigned short* gbf  = scarve(2 * ESPAN);
    unsigned short* yt   = scarve(2 * ESPAN);
    unsigned short* xp   = scarve((size_t)BB * 32 * LPAD * 8);
    unsigned short* ffWp = scarve((size_t)KK * 32 * DD * 8);
    unsigned short* inWp[2]  = { scarve(32 * 1024 * 8), scarve(32 * 1024 * 8) };
    unsigned short* outWp[2] = { scarve(64 * 256 * 8),  scarve(64 * 256 * 8) };
    unsigned short* xWp[2]   = { scarve(64 * 64 * 8),   scarve(64 * 64 * 8) };

    // ---- packing (weights + aexp) + input packing ----
    k_pack_fused<<<dim3(224, 9), 256, 0, stream>>>(
        ff_w, ffWp, sp[0], inWp[0], cp[0], inWp[1], sp[8], outWp[0], cp[8], outWp[1],
        sp[3], xWp[0], cp[3], xWp[1],
        sp[6], aexp2, cp[6], aexp2 + EE * NN);
    k_pack_x<<<dim3((LPAD + 255) / 256, 32, BB), 256, 0, stream>>>(x, xp);

    // ---- conv_ff (MFMA, LDS-free direct fragments) ----
    k_conv_mfma<<<dim3(LL / 64, DD / 128, BB), 256, 0, stream>>>(ffWp, xp, ff_b, out0);

    // ---- merged mamba pipeline (s=0: self on out0, s=1: cross on enc) ----
    k_instnorm_m<<<dim3(2 * BB * DD), 256, 0, stream>>>(out0, enc, mask, nrmp);
    // in_proj: xz[s] (B, 2E, L) fp32.  M=1024, Coct=32
    k_mfma_gemm<2, 4, 1, 0, 0, 0><<<dim3(LL / 128, 1024 / 64, 2 * BB), 256, 0, stream>>>(
        inWp[0], inWp[1], nrmp, NRMPSPAN, xz, XZSPAN, nullptr, 0,
        nullptr, nullptr, nullptr, nullptr, 1024, 32, 32);
    // dwconv + silu + transpose -> xbf/gbf bf16 [b][l][e]
    k_dwconv2<<<dim3(LL / 64, EE / 64, 2 * BB), 256, 0, stream>>>(
        xz, sp[1], cp[1], sp[2], cp[2], xbf, gbf);
    // x_proj: M=64 (48 live), Coct=64; B = xbf [b][l][E]; writes bct[b][l][48]
    k_mfma_gemm<2, 2, 0, 1, 1, 0><<<dim3(LL / 64, 1, 2 * BB), 256, 0, stream>>>(
        xWp[0], xWp[1], xbf, ESPAN, nullptr, 0, BCt, BCTSPAN,
        nullptr, nullptr, nullptr, nullptr, 64, 64, EE);
    // selective scan (chunked linear recurrence), dt inline -> yt bf16
    k_scanA<<<dim3(2 * NC * BB * EE / 256), 256, 0, stream>>>(
        xbf, BCt, aexp2, sp[4], cp[4], sp[5], cp[5], aprod, hendb);
    k_scanB<<<dim3(2 * BB * EE * NN / 256), 256, 0, stream>>>(aprod, hendb);
    k_scanC<<<dim3(2 * NC * BB * EE / 256), 256, 0, stream>>>(
        xbf, BCt, aexp2, sp[4], cp[4], sp[5], cp[5], sp[7], cp[7], gbf, aprod, yt);
    // out_proj self: soutb = W_out . yt[0]
    k_mfma_gemm<2, 2, 1, 0, 1, 0><<<dim3(LL / 64, DD / 64, BB), 256, 0, stream>>>(
        outWp[0], outWp[0], yt, 0, soutb, 0, nullptr, 0,
        nullptr, nullptr, nullptr, nullptr, 256, 64, EE);
    // out_proj cross + fused final: d_out = (x + out0 + (soutb + v)*mask)*mask
    k_mfma_gemm<2, 2, 0, 0, 1, 1><<<dim3(LL / 64, DD / 64, BB), 256, 0, stream>>>(
        outWp[1], outWp[1], yt + ESPAN, 0, (float*)d_out, 0, nullptr, 0,
        x, out0, soutb, mask, 256, 64, EE);
}

// Round 12
// 382.400 us; speedup vs baseline: 3.7881x; 1.1783x over previous
//
#include <hip/hip_runtime.h>
#include <hip/hip_bf16.h>
#include <math.h>

// Problem constants
#define BB 4
#define DD 256
#define LL 2048
#define EE 512
#define NN 16
#define KK 7
#define RR 16
#define NC 128             // scan chunks
#define CLEN (LL / NC)     // 16 steps per chunk
#define LPAD 2064          // padded L for conv input (8 zeros each side)

// per-mamba-block scratch spans (elements)
#define ESPAN   ((size_t)BB * LL * EE)        // bf16 [b][l][e] buffers
#define XZSPAN  ((size_t)BB * 2 * EE * LL)    // fp32 xz
#define BCTSPAN ((size_t)BB * LL * 48)        // fp32 bct
#define APSPAN  ((size_t)NC * BB * EE * NN)   // fp32 aprod/hend
#define NRMPSPAN ((size_t)BB * 32 * LL * 8)   // bf16 nrmp

typedef __attribute__((ext_vector_type(8))) short short8;   // 8 bf16 (4 VGPRs)
typedef __attribute__((ext_vector_type(4))) float floatx4;  // MFMA accumulator

static __device__ __forceinline__ unsigned short bfbits(float f) {
    __hip_bfloat16 h = __float2bfloat16(f);
    return *(unsigned short*)&h;
}

static __device__ __forceinline__ float bf2f(unsigned short u) {
    unsigned v = ((unsigned)u) << 16;
    float f;
    __builtin_memcpy(&f, &v, 4);
    return f;
}

static __device__ __forceinline__ float softplus_fast(float v) {
    return fmaxf(v, 0.f) + __logf(1.f + __expf(-fabsf(v)));
}

// ---------------------------------------------------------------------------
// Fused packing: all weights + aexp in ONE dispatch. grid (224, 9).
// ---------------------------------------------------------------------------
static __device__ __forceinline__ void pack_w_seg(const float* __restrict__ W,
                                                  unsigned short* __restrict__ Wp,
                                                  int M, int C, int Mp, int Coct,
                                                  int cell) {
    if (cell >= Coct * Mp) return;
    int co = cell / Mp, m = cell - co * Mp;
    unsigned short v[8];
#pragma unroll
    for (int j = 0; j < 8; ++j) {
        int c = co * 8 + j;
        float f = (m < M && c < C) ? W[(size_t)m * C + c] : 0.f;
        v[j] = bfbits(f);
    }
    *(uint4*)&Wp[(size_t)cell * 8] = *(uint4*)v;
}

__global__ __launch_bounds__(256) void k_pack_fused(
        const float* __restrict__ ffw, unsigned short* __restrict__ ffWp,
        const float* __restrict__ sW0, unsigned short* __restrict__ inW0,
        const float* __restrict__ cW0, unsigned short* __restrict__ inW1,
        const float* __restrict__ sW8, unsigned short* __restrict__ outW0,
        const float* __restrict__ cW8, unsigned short* __restrict__ outW1,
        const float* __restrict__ sW3, unsigned short* __restrict__ xW0,
        const float* __restrict__ cW3, unsigned short* __restrict__ xW1,
        const float* __restrict__ sAl, float* __restrict__ aexp0,
        const float* __restrict__ cAl, float* __restrict__ aexp1) {
    int cell = blockIdx.x * 256 + threadIdx.x;
    switch (blockIdx.y) {
    case 0: {  // ff_w (Do,Di,K) -> [k][co][do][8]
        if (cell >= KK * 32 * DD) return;
        int doo = cell % DD;
        int rest = cell / DD;
        int co = rest % 32, k = rest / 32;
        unsigned short v[8];
#pragma unroll
        for (int j = 0; j < 8; ++j)
            v[j] = bfbits(ffw[((size_t)doo * DD + co * 8 + j) * KK + k]);
        *(uint4*)&ffWp[(size_t)cell * 8] = *(uint4*)v;
    } break;
    case 1: pack_w_seg(sW0, inW0, 1024, 256, 1024, 32, cell); break;
    case 2: pack_w_seg(cW0, inW1, 1024, 256, 1024, 32, cell); break;
    case 3: pack_w_seg(sW8, outW0, 256, 512, 256, 64, cell); break;
    case 4: pack_w_seg(cW8, outW1, 256, 512, 256, 64, cell); break;
    case 5: pack_w_seg(sW3, xW0, 48, 512, 64, 64, cell); break;
    case 6: pack_w_seg(cW3, xW1, 48, 512, 64, 64, cell); break;
    case 7: if (cell < EE * NN) aexp0[cell] = -expf(sAl[cell]); break;
    case 8: if (cell < EE * NN) aexp1[cell] = -expf(cAl[cell]); break;
    }
}

// x (B, D, L) fp32 -> xp[b][co][l+8][8] bf16 with 8-column zero pad both sides
__global__ __launch_bounds__(256) void k_pack_x(const float* __restrict__ x,
                                                unsigned short* __restrict__ xp) {
    int l = blockIdx.x * 256 + threadIdx.x;
    int co = blockIdx.y, b = blockIdx.z;
    if (l >= LPAD) return;
    int sl = l - 8;
    unsigned short v[8];
#pragma unroll
    for (int j = 0; j < 8; ++j) {
        float f = (sl >= 0 && sl < LL) ? x[((size_t)(b * DD) + co * 8 + j) * LL + sl] : 0.f;
        v[j] = bfbits(f);
    }
    *(uint4*)&xp[(((size_t)(b * 32) + co) * LPAD + l) * 8] = *(uint4*)v;
}

// ---------------------------------------------------------------------------
// instance norm, MERGED over both mamba blocks: blockIdx.x in [0, 2*B*D);
// ---------------------------------------------------------------------------
__global__ __launch_bounds__(256) void k_instnorm_m(const float* __restrict__ srcA,
                                                    const float* __restrict__ srcB,
                                                    const float* __restrict__ mask,
                                                    unsigned short* __restrict__ outp) {
    const int s = blockIdx.x >> 10;
    const int bd = blockIdx.x & 1023;
    const int b = bd >> 8, d = bd & 255;
    const int tid = threadIdx.x;
    const float* row = (s ? srcB : srcA) + (size_t)bd * LL;
    float v[8];
    float ss = 0.f, s2 = 0.f;
#pragma unroll
    for (int i = 0; i < 8; ++i) {
        v[i] = row[i * 256 + tid];
        ss += v[i];
        s2 = fmaf(v[i], v[i], s2);
    }
#pragma unroll
    for (int off = 32; off > 0; off >>= 1) {
        ss += __shfl_down(ss, off);
        s2 += __shfl_down(s2, off);
    }
    __shared__ float red[2][4];
    if ((tid & 63) == 0) { red[0][tid >> 6] = ss; red[1][tid >> 6] = s2; }
    __syncthreads();
    ss = red[0][0] + red[0][1] + red[0][2] + red[0][3];
    s2 = red[1][0] + red[1][1] + red[1][2] + red[1][3];
    const float mu  = ss * (1.f / LL);
    const float var = s2 * (1.f / LL) - mu * mu;
    const float inv = rsqrtf(var + 1e-5f);
    const float* mrow = mask + (size_t)b * LL;
    unsigned short* op = outp + (size_t)s * NRMPSPAN
                       + ((size_t)(b * 32) + (d >> 3)) * LL * 8 + (d & 7);
#pragma unroll
    for (int i = 0; i < 8; ++i) {
        int l = i * 256 + tid;
        op[(size_t)l * 8] = bfbits((v[i] - mu) * inv * mrow[l]);
    }
}

// ---------------------------------------------------------------------------
// MFMA GEMM, double-buffered LDS, one barrier per K-chunk (BK=32).
// Merged-block support: blockIdx.z in [0, 4*S): b = z&3, s = z>>2.
// ---------------------------------------------------------------------------
template <int RM, int NLT, int STOREOUT, int BCT48, int BLT, int FINAL>
__global__ __launch_bounds__(256) void k_mfma_gemm(
        const unsigned short* __restrict__ Ap0,
        const unsigned short* __restrict__ Ap1,
        const unsigned short* __restrict__ Bp, size_t BspanS,
        float* __restrict__ out, size_t outSpanF,
        float* __restrict__ bct, size_t bctSpanF,
        const float* __restrict__ fx,
        const float* __restrict__ fo0,
        const float* __restrict__ fs,
        const float* __restrict__ fmask,
        int Ms, int Coct, int EphOrBoct) {
    constexpr int TM = RM * 32;
    constexpr int TL = NLT * 32;
    constexpr int APITCH = TM * 8 + 8;
    constexpr int BPITCH = TL * 8 + 8;
    constexpr int ACELLS = (4 * TM) / 256;
    constexpr int BCELLS = (4 * TL) / 256;
    __shared__ unsigned short As[2][4 * APITCH];
    __shared__ unsigned short Bs[2][4 * BPITCH];
    const int tid = threadIdx.x;
    const int w = tid >> 6, lane = tid & 63;
    const int quad = lane >> 4, t = lane & 15;
    const int wm = (w >> 1) * (RM * 16), wl = (w & 1) * (NLT * 16);
    const int l0 = blockIdx.x * TL;
    const int m0 = blockIdx.y * TM;
    const int z  = blockIdx.z;
    const int b  = z & 3, s = z >> 2;
    const unsigned short* Ap = s ? Ap1 : Ap0;
    Bp += (size_t)s * BspanS;
    if (STOREOUT) out += (size_t)s * outSpanF;
    if (BCT48) bct += (size_t)s * bctSpanF;

    floatx4 acc[RM][NLT];
#pragma unroll
    for (int r = 0; r < RM; ++r)
#pragma unroll
        for (int j = 0; j < NLT; ++j) acc[r][j] = (floatx4){0.f, 0.f, 0.f, 0.f};

    uint4 areg[ACELLS], breg[BCELLS];
    auto loadRegs = [&](int c0) {
#pragma unroll
        for (int i = 0; i < ACELLS; ++i) {
            int cell = tid + i * 256;
            int q = cell / TM, mm = cell % TM;
            areg[i] = *(const uint4*)&Ap[((size_t)(c0 + q) * Ms + m0 + mm) * 8];
        }
#pragma unroll
        for (int i = 0; i < BCELLS; ++i) {
            int cell = tid + i * 256;
            if (BLT == 0) {
                int q = cell / TL, ll = cell % TL;
                breg[i] = *(const uint4*)&Bp[((size_t)b * EphOrBoct * LL +
                                              (size_t)(c0 + q) * LL + l0 + ll) * 8];
            } else {
                int ll = cell >> 2, q = cell & 3;
                breg[i] = *(const uint4*)&Bp[((size_t)b * LL + l0 + ll) * EphOrBoct +
                                             (size_t)(c0 + q) * 8];
            }
        }
    };
    auto storeRegs = [&](int p) {
#pragma unroll
        for (int i = 0; i < ACELLS; ++i) {
            int cell = tid + i * 256;
            int q = cell / TM, mm = cell % TM;
            *(uint4*)&As[p][q * APITCH + mm * 8] = areg[i];
        }
#pragma unroll
        for (int i = 0; i < BCELLS; ++i) {
            int cell = tid + i * 256;
            int q, ll;
            if (BLT == 0) { q = cell / TL; ll = cell % TL; }
            else          { ll = cell >> 2; q = cell & 3; }
            *(uint4*)&Bs[p][q * BPITCH + ll * 8] = breg[i];
        }
    };

    loadRegs(0);
    storeRegs(0);
    __syncthreads();
    int p = 0;
    for (int c0 = 4; c0 <= Coct; c0 += 4) {
        const bool has_next = (c0 < Coct);
        if (has_next) loadRegs(c0);
        short8 af[RM], bfv[NLT];
#pragma unroll
        for (int r = 0; r < RM; ++r)
            af[r] = *(short8*)&As[p][quad * APITCH + (wm + r * 16 + t) * 8];
#pragma unroll
        for (int j = 0; j < NLT; ++j)
            bfv[j] = *(short8*)&Bs[p][quad * BPITCH + (wl + j * 16 + t) * 8];
#pragma unroll
        for (int r = 0; r < RM; ++r)
#pragma unroll
            for (int j = 0; j < NLT; ++j)
                acc[r][j] = __builtin_amdgcn_mfma_f32_16x16x32_bf16(af[r], bfv[j], acc[r][j], 0, 0, 0);
        if (has_next) {
            storeRegs(p ^ 1);
            __syncthreads();
            p ^= 1;
        }
    }
    // epilogue: C/D layout col = lane&15 (l), row = quad*4 + reg (m)
#pragma unroll
    for (int r = 0; r < RM; ++r) {
        int mb = m0 + wm + r * 16 + quad * 4;
#pragma unroll
        for (int i = 0; i < 4; ++i) {
            int m = mb + i;
#pragma unroll
            for (int j = 0; j < NLT; ++j) {
                int l = l0 + wl + j * 16 + t;
                float v = acc[r][j][i];
                if (STOREOUT) out[((size_t)b * Ms + m) * LL + l] = v;
                if (BCT48) {
                    if (m < 48) bct[((size_t)b * LL + l) * 48 + m] = v;
                }
                if (FINAL) {
                    size_t idx = ((size_t)b * Ms + m) * LL + l;
                    float mk = fmask[(size_t)b * LL + l];
                    out[idx] = (fx[idx] + fo0[idx] + (fs[idx] + v) * mk) * mk;
                }
            }
        }
    }
}

// ---------------------------------------------------------------------------
// conv_ff: LDS-free, MFMA fragments loaded directly from global.
// ---------------------------------------------------------------------------
__global__ __launch_bounds__(256) void k_conv_mfma(
        const unsigned short* __restrict__ Wp,
        const unsigned short* __restrict__ Xp,
        const float* __restrict__ bias,
        float* __restrict__ out) {
    const int tid = threadIdx.x;
    const int w = tid >> 6, lane = tid & 63;
    const int quad = lane >> 4, t = lane & 15;
    const int wm = (w >> 1) * 64, wl = (w & 1) * 32;
    const int l0 = blockIdx.x * 64;
    const int m0 = blockIdx.y * 128;
    const int b  = blockIdx.z;

    floatx4 acc[4][2];
#pragma unroll
    for (int r = 0; r < 4; ++r)
#pragma unroll
        for (int j = 0; j < 2; ++j) acc[r][j] = (floatx4){0.f, 0.f, 0.f, 0.f};

    const unsigned short* wbase = Wp + ((size_t)quad * DD + m0 + wm + t) * 8;
    const unsigned short* xbase = Xp + (((size_t)(b * 32) + quad) * LPAD + l0 + wl + t + 5) * 8;

    for (int dc = 0; dc < 8; ++dc) {
#pragma unroll
        for (int k = 0; k < KK; ++k) {
            short8 af[4], bfv[2];
#pragma unroll
            for (int r = 0; r < 4; ++r)
                af[r] = *(const short8*)&wbase[((size_t)(k * 32 + dc * 4) * DD + r * 16) * 8];
#pragma unroll
            for (int j = 0; j < 2; ++j)
                bfv[j] = *(const short8*)&xbase[((size_t)(dc * 4) * LPAD + j * 16 + k) * 8];
#pragma unroll
            for (int r = 0; r < 4; ++r)
#pragma unroll
                for (int j = 0; j < 2; ++j)
                    acc[r][j] = __builtin_amdgcn_mfma_f32_16x16x32_bf16(af[r], bfv[j], acc[r][j], 0, 0, 0);
        }
    }
#pragma unroll
    for (int r = 0; r < 4; ++r) {
        int mb = m0 + wm + r * 16 + quad * 4;
#pragma unroll
        for (int i = 0; i < 4; ++i) {
            int m = mb + i;
            float bv = bias[m];
#pragma unroll
            for (int j = 0; j < 2; ++j) {
                int l = l0 + wl + j * 16 + t;
                float v = acc[r][j][i] + bv;
                out[((size_t)b * DD + m) * LL + l] = v > 0.f ? v : 0.f;
            }
        }
    }
}

// ---------------------------------------------------------------------------
// dwconv, MERGED: grid (L/64, E/64, 2*B): b = z&3, s = z>>2.
// Writes bf16 xbf[b][l][e] = silu(conv(x)), gbf[b][l][e] = silu(z).
// ---------------------------------------------------------------------------
__global__ __launch_bounds__(256) void k_dwconv2(const float* __restrict__ xz,
                                                 const float* __restrict__ cw0,
                                                 const float* __restrict__ cw1,
                                                 const float* __restrict__ cb0,
                                                 const float* __restrict__ cb1,
                                                 unsigned short* __restrict__ xbf,
                                                 unsigned short* __restrict__ gbf) {
    __shared__ float xs[64][71];   // pitch 71: conflict-free
    __shared__ float zs[64][65];
    const int tid = threadIdx.x;
    const int l0 = blockIdx.x * 64;
    const int e0 = blockIdx.y * 64;
    const int z  = blockIdx.z;
    const int b  = z & 3, s = z >> 2;
    xz  += (size_t)s * XZSPAN;
    xbf += (size_t)s * ESPAN;
    gbf += (size_t)s * ESPAN;
    const float* cw = s ? cw1 : cw0;
    const float* cb = s ? cb1 : cb0;
    for (int idx = tid; idx < 64 * 70; idx += 256) {
        int r = idx / 70, c = idx - r * 70;
        int gl = l0 - 6 + c;
        xs[r][c] = (gl >= 0) ? xz[((size_t)(b * 2 * EE) + e0 + r) * LL + gl] : 0.f;
    }
    for (int idx = tid; idx < 64 * 64; idx += 256) {
        int r = idx >> 6, c = idx & 63;
        zs[r][c] = xz[((size_t)(b * 2 * EE) + EE + e0 + r) * LL + l0 + c];
    }
    __syncthreads();
    const int e = tid & 63, g = tid >> 6;
    float wv[KK];
#pragma unroll
    for (int k = 0; k < KK; ++k) wv[k] = cw[(e0 + e) * KK + k];
    const float cbe = cb[e0 + e];
#pragma unroll 4
    for (int i = 0; i < 16; ++i) {
        int li = g * 16 + i;
        float acc = cbe;
#pragma unroll
        for (int k = 0; k < KK; ++k) acc = fmaf(xs[e][li + k], wv[k], acc);
        float v = acc / (1.f + __expf(-acc));
        size_t o = ((size_t)(b * LL) + l0 + li) * EE + e0 + e;
        xbf[o] = bfbits(v);
        float zz = zs[e][li];
        gbf[o] = bfbits(zz / (1.f + __expf(-zz)));
    }
}

// ---------------------------------------------------------------------------
// Selective scan, MERGED + phase-split + LDS-staged bct.
// grid: 2048 blocks; blk = (s<<10) | (ch<<3) | (b<<1) | eh; e = eh*256+tid.
// (s,ch,b block-uniform -> chunk pointers in SGPRs; bct chunk (3 KB) staged
// in LDS once, all Dv/Bv/Cv reads are wave-uniform ds_read broadcasts.)
// ---------------------------------------------------------------------------
__global__ __launch_bounds__(256) void k_scanA(const unsigned short* __restrict__ ubf,
                                               const float* __restrict__ bct,
                                               const float* __restrict__ aexp2,
                                               const float* __restrict__ Wdt0,
                                               const float* __restrict__ Wdt1,
                                               const float* __restrict__ db0,
                                               const float* __restrict__ db1,
                                               float* __restrict__ aprod,
                                               float* __restrict__ hend) {
    __shared__ float bcs[CLEN * 48];   // 3 KB
    const int tid = threadIdx.x;
    const int blk = blockIdx.x;
    const int s  = blk >> 10;
    const int ch = (blk >> 3) & 127;
    const int b  = (blk >> 1) & 3;
    const int eh = blk & 1;
    const int e  = (eh << 8) + tid;
    const int t  = ch * 2048 + b * 512 + e;
    ubf   += (size_t)s * ESPAN;
    bct   += (size_t)s * BCTSPAN;
    aprod += (size_t)s * APSPAN;
    hend  += (size_t)s * APSPAN;
    const float* aexp = aexp2 + (size_t)s * (EE * NN);
    const float* Wdt  = s ? Wdt1 : Wdt0;
    const float be    = (s ? db1 : db0)[e];

    // stage bct chunk (contiguous CLEN*48 floats) into LDS
    const float* bc = bct + ((size_t)(b * LL) + ch * CLEN) * 48;
    for (int i = tid; i < CLEN * 48 / 4; i += 256)
        ((float4*)bcs)[i] = ((const float4*)bc)[i];

    float A[16], wd[16];
#pragma unroll
    for (int q = 0; q < 4; ++q) {
        *(float4*)&A[q * 4]  = *(const float4*)&aexp[e * 16 + q * 4];
        *(float4*)&wd[q * 4] = *(const float4*)&Wdt[e * 16 + q * 4];
    }
    __syncthreads();

    // phase 1: dt for all steps (independent chains)
    float dv[CLEN];
    float S = 0.f;
#pragma unroll
    for (int i = 0; i < CLEN; ++i) {
        const float* bcl = &bcs[i * 48];
        float Dv[16];
#pragma unroll
        for (int q = 0; q < 4; ++q)
            *(float4*)&Dv[q * 4] = *(const float4*)(bcl + q * 4);
        float d0 = be, d1 = 0.f, d2 = 0.f, d3 = 0.f;
#pragma unroll
        for (int r = 0; r < 4; ++r) {
            d0 = fmaf(wd[r], Dv[r], d0);
            d1 = fmaf(wd[r + 4], Dv[r + 4], d1);
            d2 = fmaf(wd[r + 8], Dv[r + 8], d2);
            d3 = fmaf(wd[r + 12], Dv[r + 12], d3);
        }
        dv[i] = softplus_fast((d0 + d1) + (d2 + d3));
        S += dv[i];
    }

    // phase 2: recurrence (h only; aprod from S at the end)
    float h[16];
#pragma unroll
    for (int n = 0; n < 16; ++n) h[n] = 0.f;
    const unsigned short* up = ubf + ((size_t)(b * LL) + ch * CLEN) * EE + e;
#pragma unroll
    for (int i = 0; i < CLEN; ++i) {
        float uv = bf2f(up[(size_t)i * EE]);
        const float* bcl = &bcs[i * 48 + 16];
        float Bv[16];
#pragma unroll
        for (int q = 0; q < 4; ++q)
            *(float4*)&Bv[q * 4] = *(const float4*)(bcl + q * 4);
        float du = dv[i] * uv;
#pragma unroll
        for (int n = 0; n < 16; ++n) {
            float dA = __expf(dv[i] * A[n]);
            h[n] = fmaf(dA, h[n], du * Bv[n]);
        }
    }
    float ap[16];
#pragma unroll
    for (int n = 0; n < 16; ++n) ap[n] = __expf(S * A[n]);
    float* app = aprod + (size_t)t * 16;
    float* hp  = hend + (size_t)t * 16;
#pragma unroll
    for (int q = 0; q < 4; ++q) {
        *(float4*)&app[q * 4] = *(float4*)&ap[q * 4];
        *(float4*)&hp[q * 4]  = *(float4*)&h[q * 4];
    }
}

// Pass B (in place, merged): blockIdx.x in [0, 2*B*E*N/256): s = x >> 7.
__global__ __launch_bounds__(256) void k_scanB(float* __restrict__ aprod,
                                               const float* __restrict__ hend) {
    const int s = blockIdx.x >> 7;
    const int ss = ((blockIdx.x & 127) << 8) + threadIdx.x;
    aprod += (size_t)s * APSPAN;
    hend  += (size_t)s * APSPAN;
    float c = 0.f;
#pragma unroll 4
    for (int ch = 0; ch < NC; ++ch) {
        size_t idx = (size_t)ch * (BB * EE * NN) + ss;
        float a = aprod[idx];
        float hh = hend[idx];
        aprod[idx] = c;
        c = fmaf(a, c, hh);
    }
}

// Pass C, merged + phase-split + LDS-staged bct.
__global__ __launch_bounds__(256) void k_scanC(const unsigned short* __restrict__ ubf,
                                               const float* __restrict__ bct,
                                               const float* __restrict__ aexp2,
                                               const float* __restrict__ Wdt0,
                                               const float* __restrict__ Wdt1,
                                               const float* __restrict__ db0,
                                               const float* __restrict__ db1,
                                               const float* __restrict__ Dp0,
                                               const float* __restrict__ Dp1,
                                               const unsigned short* __restrict__ gbf,
                                               const float* __restrict__ carry,
                                               unsigned short* __restrict__ yt) {
    __shared__ float bcs[CLEN * 48];   // 3 KB
    const int tid = threadIdx.x;
    const int blk = blockIdx.x;
    const int s  = blk >> 10;
    const int ch = (blk >> 3) & 127;
    const int b  = (blk >> 1) & 3;
    const int eh = blk & 1;
    const int e  = (eh << 8) + tid;
    const int t  = ch * 2048 + b * 512 + e;
    ubf   += (size_t)s * ESPAN;
    gbf   += (size_t)s * ESPAN;
    yt    += (size_t)s * ESPAN;
    bct   += (size_t)s * BCTSPAN;
    carry += (size_t)s * APSPAN;
    const float* aexp = aexp2 + (size_t)s * (EE * NN);
    const float* Wdt  = s ? Wdt1 : Wdt0;
    const float be    = (s ? db1 : db0)[e];
    const float Dpe   = (s ? Dp1 : Dp0)[e];

    // stage bct chunk into LDS
    const float* bc = bct + ((size_t)(b * LL) + ch * CLEN) * 48;
    for (int i = tid; i < CLEN * 48 / 4; i += 256)
        ((float4*)bcs)[i] = ((const float4*)bc)[i];

    float A[16], wd[16];
#pragma unroll
    for (int q = 0; q < 4; ++q) {
        *(float4*)&A[q * 4]  = *(const float4*)&aexp[e * 16 + q * 4];
        *(float4*)&wd[q * 4] = *(const float4*)&Wdt[e * 16 + q * 4];
    }
    __syncthreads();

    // phase 1: dt for all steps
    float dv[CLEN];
#pragma unroll
    for (int i = 0; i < CLEN; ++i) {
        const float* bcl = &bcs[i * 48];
        float Dv[16];
#pragma unroll
        for (int q = 0; q < 4; ++q)
            *(float4*)&Dv[q * 4] = *(const float4*)(bcl + q * 4);
        float d0 = be, d1 = 0.f, d2 = 0.f, d3 = 0.f;
#pragma unroll
        for (int r = 0; r < 4; ++r) {
            d0 = fmaf(wd[r], Dv[r], d0);
            d1 = fmaf(wd[r + 4], Dv[r + 4], d1);
            d2 = fmaf(wd[r + 8], Dv[r + 8], d2);
            d3 = fmaf(wd[r + 12], Dv[r + 12], d3);
        }
        dv[i] = softplus_fast((d0 + d1) + (d2 + d3));
    }

    // phase 2: recurrence + output
    float h[16];
#pragma unroll
    for (int q = 0; q < 4; ++q)
        *(float4*)&h[q * 4] = *(const float4*)&carry[(size_t)t * 16 + q * 4];
    const size_t base = ((size_t)(b * LL) + ch * CLEN) * EE + e;
    const unsigned short* up = ubf + base;
    const unsigned short* gp = gbf + base;
    unsigned short* yp = yt + base;
#pragma unroll
    for (int i = 0; i < CLEN; ++i) {
        float uv = bf2f(up[(size_t)i * EE]);
        float gv = bf2f(gp[(size_t)i * EE]);
        const float* bcl = &bcs[i * 48];
        float Bv[16], Cv[16];
#pragma unroll
        for (int q = 0; q < 4; ++q) {
            *(float4*)&Bv[q * 4] = *(const float4*)(bcl + 16 + q * 4);
            *(float4*)&Cv[q * 4] = *(const float4*)(bcl + 32 + q * 4);
        }
        float du = dv[i] * uv;
        float p0 = 0.f, p1 = 0.f, p2 = 0.f, p3 = 0.f;
#pragma unroll
        for (int n = 0; n < 4; ++n) {
            float dA = __expf(dv[i] * A[n]);
            h[n] = fmaf(dA, h[n], du * Bv[n]);
            p0 = fmaf(h[n], Cv[n], p0);
        }
#pragma unroll
        for (int n = 4; n < 8; ++n) {
            float dA = __expf(dv[i] * A[n]);
            h[n] = fmaf(dA, h[n], du * Bv[n]);
            p1 = fmaf(h[n], Cv[n], p1);
        }
#pragma unroll
        for (int n = 8; n < 12; ++n) {
            float dA = __expf(dv[i] * A[n]);
            h[n] = fmaf(dA, h[n], du * Bv[n]);
            p2 = fmaf(h[n], Cv[n], p2);
        }
#pragma unroll
        for (int n = 12; n < 16; ++n) {
            float dA = __expf(dv[i] * A[n]);
            h[n] = fmaf(dA, h[n], du * Bv[n]);
            p3 = fmaf(h[n], Cv[n], p3);
        }
        float p = (p0 + p1) + (p2 + p3) + uv * Dpe;
        yp[(size_t)i * EE] = bfbits(p * gv);
    }
}

// ---------------------------------------------------------------------------
extern "C" void kernel_launch(void* const* d_in, const int* in_sizes, int n_in,
                              void* d_out, int out_size, void* d_ws, size_t ws_size,
                              hipStream_t stream) {
    const float* x    = (const float*)d_in[0];
    const float* enc  = (const float*)d_in[1];
    const float* mask = (const float*)d_in[2];
    const float* ff_w = (const float*)d_in[3];
    const float* ff_b = (const float*)d_in[4];
    const float* sp[9];
    const float* cp[9];
    for (int i = 0; i < 9; ++i) {
        sp[i] = (const float*)d_in[5 + i];
        cp[i] = (const float*)d_in[14 + i];
    }

    // workspace carve-up (duplicated per-mamba-block scratch: [s=0 | s=1])
    float* ws = (float*)d_ws;
    auto fcarve = [&](size_t n) { float* p = ws; ws += (n + 3) & ~3ul; return p; };
    float* out0  = fcarve((size_t)BB * DD * LL);
    float* xz    = fcarve(2 * XZSPAN);
    float* soutb = fcarve((size_t)BB * DD * LL);
    float* aprod = fcarve(2 * APSPAN);   // doubles as carry
    float* hendb = fcarve(2 * APSPAN);
    float* BCt   = fcarve(2 * BCTSPAN);
    float* aexp2 = fcarve((size_t)2 * EE * NN);
    auto scarve = [&](size_t n) { unsigned short* p = (unsigned short*)ws; ws += (n + 7) / 2 / 4 * 4 + 4; return p; };
    unsigned short* nrmp = scarve(2 * NRMPSPAN);
    unsigned short* xbf  = scarve(2 * ESPAN);
    unsigned short* gbf  = scarve(2 * ESPAN);
    unsigned short* yt   = scarve(2 * ESPAN);
    unsigned short* xp   = scarve((size_t)BB * 32 * LPAD * 8);
    unsigned short* ffWp = scarve((size_t)KK * 32 * DD * 8);
    unsigned short* inWp[2]  = { scarve(32 * 1024 * 8), scarve(32 * 1024 * 8) };
    unsigned short* outWp[2] = { scarve(64 * 256 * 8),  scarve(64 * 256 * 8) };
    unsigned short* xWp[2]   = { scarve(64 * 64 * 8),   scarve(64 * 64 * 8) };

    // ---- packing (weights + aexp) + input packing ----
    k_pack_fused<<<dim3(224, 9), 256, 0, stream>>>(
        ff_w, ffWp, sp[0], inWp[0], cp[0], inWp[1], sp[8], outWp[0], cp[8], outWp[1],
        sp[3], xWp[0], cp[3], xWp[1],
        sp[6], aexp2, cp[6], aexp2 + EE * NN);
    k_pack_x<<<dim3((LPAD + 255) / 256, 32, BB), 256, 0, stream>>>(x, xp);

    // ---- conv_ff (MFMA, LDS-free direct fragments) ----
    k_conv_mfma<<<dim3(LL / 64, DD / 128, BB), 256, 0, stream>>>(ffWp, xp, ff_b, out0);

    // ---- merged mamba pipeline (s=0: self on out0, s=1: cross on enc) ----
    k_instnorm_m<<<dim3(2 * BB * DD), 256, 0, stream>>>(out0, enc, mask, nrmp);
    // in_proj: xz[s] (B, 2E, L) fp32.  M=1024, Coct=32
    k_mfma_gemm<2, 4, 1, 0, 0, 0><<<dim3(LL / 128, 1024 / 64, 2 * BB), 256, 0, stream>>>(
        inWp[0], inWp[1], nrmp, NRMPSPAN, xz, XZSPAN, nullptr, 0,
        nullptr, nullptr, nullptr, nullptr, 1024, 32, 32);
    // dwconv + silu + transpose -> xbf/gbf bf16 [b][l][e]
    k_dwconv2<<<dim3(LL / 64, EE / 64, 2 * BB), 256, 0, stream>>>(
        xz, sp[1], cp[1], sp[2], cp[2], xbf, gbf);
    // x_proj: M=64 (48 live), Coct=64; B = xbf [b][l][E]; writes bct[b][l][48]
    k_mfma_gemm<2, 2, 0, 1, 1, 0><<<dim3(LL / 64, 1, 2 * BB), 256, 0, stream>>>(
        xWp[0], xWp[1], xbf, ESPAN, nullptr, 0, BCt, BCTSPAN,
        nullptr, nullptr, nullptr, nullptr, 64, 64, EE);
    // selective scan (chunked linear recurrence), dt inline -> yt bf16
    k_scanA<<<dim3(2 * NC * BB * 2), 256, 0, stream>>>(
        xbf, BCt, aexp2, sp[4], cp[4], sp[5], cp[5], aprod, hendb);
    k_scanB<<<dim3(2 * BB * EE * NN / 256), 256, 0, stream>>>(aprod, hendb);
    k_scanC<<<dim3(2 * NC * BB * 2), 256, 0, stream>>>(
        xbf, BCt, aexp2, sp[4], cp[4], sp[5], cp[5], sp[7], cp[7], gbf, aprod, yt);
    // out_proj self: soutb = W_out . yt[0]
    k_mfma_gemm<2, 2, 1, 0, 1, 0><<<dim3(LL / 64, DD / 64, BB), 256, 0, stream>>>(
        outWp[0], outWp[0], yt, 0, soutb, 0, nullptr, 0,
        nullptr, nullptr, nullptr, nullptr, 256, 64, EE);
    // out_proj cross + fused final: d_out = (x + out0 + (soutb + v)*mask)*mask
    k_mfma_gemm<2, 2, 0, 0, 1, 1><<<dim3(LL / 64, DD / 64, BB), 256, 0, stream>>>(
        outWp[1], outWp[1], yt + ESPAN, 0, (float*)d_out, 0, nullptr, 0,
        x, out0, soutb, mask, 256, 64, EE);
}